// Round 3
// baseline (1063.704 us; speedup 1.0000x reference)
//
#include <hip/hip_runtime.h>
#include <hip/hip_bf16.h>

// GCN: h1 = relu(GCNConv(x, W1, b1)); out = scatter_mean(GCNConv(h1, W2, b2), user_idx)
// N=100000 nodes, E=1600000 edges, dims 128 -> 64 -> 64.
// Dtypes per harness contract: float32 tensors -> const float*, int -> const int*,
// output float32 -> float*.  (R1 NaN forensics: fp32 read as bf16 => NaN; bf16 read
// as fp32 => finite garbage. We saw NaN => inputs are fp32.)
// Buffers: B/agg/scatter accumulator = d_out itself (fp32 N*64, exact fit; final
// divide is elementwise in-place so aliasing is safe). Workspace: [dis][cnt][A].
// A is fp32 if ws allows (26.4 MB), else bf16 (13.6 MB).

#define FEAT 64
#define INDIM 128

__device__ __forceinline__ float ldf(const float* p, long i) { return p[i]; }
__device__ __forceinline__ float ldf(const __hip_bfloat16* p, long i) { return __bfloat162float(p[i]); }
__device__ __forceinline__ void stf(float* p, long i, float v) { p[i] = v; }
__device__ __forceinline__ void stf(__hip_bfloat16* p, long i, float v) { p[i] = __float2bfloat16(v); }

// ---- degree: deg[i] = #(dst==i). buffer pre-zeroed. ----
__global__ __launch_bounds__(256) void k_deg(const int* __restrict__ dst,
                                             float* __restrict__ deg, int E, int N) {
    int e = blockIdx.x * 256 + threadIdx.x;
    if (e < E) {
        int d = dst[e];
        if ((unsigned)d < (unsigned)N) atomicAdd(&deg[d], 1.0f);
    }
}

// in-place: deg -> dis = rsqrt(deg + 1)   (+1 = self loop)
__global__ __launch_bounds__(256) void k_dis(float* __restrict__ deg, int N) {
    int i = blockIdx.x * 256 + threadIdx.x;
    if (i < N) deg[i] = rsqrtf(deg[i] + 1.0f);
}

// ---- GEMM1: [N,128] f32 @ [128,64] f32 -> [N,64] (AT). 16 rows/block. ----
template <typename AT>
__global__ __launch_bounds__(256) void k_gemm1(const float* __restrict__ x,
                                               const float* __restrict__ W,
                                               AT* __restrict__ out, int N) {
    __shared__ float ws[INDIM * FEAT];   // 32 KB
    __shared__ float xs[16 * INDIM];     // 8 KB
    const int tid = threadIdx.x;
    for (int i = tid; i < INDIM * FEAT; i += 256) ws[i] = W[i];
    const int row0 = blockIdx.x * 16;
    for (int i = tid; i < 16 * INDIM; i += 256) {
        int r = i >> 7, k = i & (INDIM - 1);
        int gr = row0 + r;
        xs[i] = (gr < N) ? x[(long)gr * INDIM + k] : 0.0f;
    }
    __syncthreads();
    const int rb = tid >> 6;   // wave id 0..3 -> row subgroup
    const int c  = tid & 63;
    float acc0 = 0.f, acc1 = 0.f, acc2 = 0.f, acc3 = 0.f;
    #pragma unroll 4
    for (int k = 0; k < INDIM; ++k) {
        float w = ws[k * FEAT + c];              // stride-1: 2-way alias, free
        acc0 += xs[(rb     ) * INDIM + k] * w;   // wave-uniform addr: LDS broadcast
        acc1 += xs[(rb +  4) * INDIM + k] * w;
        acc2 += xs[(rb +  8) * INDIM + k] * w;
        acc3 += xs[(rb + 12) * INDIM + k] * w;
    }
    float acc[4] = {acc0, acc1, acc2, acc3};
    for (int j = 0; j < 4; ++j) {
        int gr = row0 + rb + j * 4;
        if (gr < N) stf(out, (long)gr * FEAT + c, acc[j]);
    }
}

// ---- GEMM2: [N,64] f32 @ [64,64] f32 -> [N,64] (AT). ----
template <typename AT>
__global__ __launch_bounds__(256) void k_gemm2(const float* __restrict__ h,
                                               const float* __restrict__ W,
                                               AT* __restrict__ out, int N) {
    __shared__ float ws[FEAT * FEAT];    // 16 KB
    __shared__ float xs[16 * FEAT];      // 4 KB
    const int tid = threadIdx.x;
    for (int i = tid; i < FEAT * FEAT; i += 256) ws[i] = W[i];
    const int row0 = blockIdx.x * 16;
    for (int i = tid; i < 16 * FEAT; i += 256) {
        int r = i >> 6, k = i & 63;
        int gr = row0 + r;
        xs[i] = (gr < N) ? h[(long)gr * FEAT + k] : 0.0f;
    }
    __syncthreads();
    const int rb = tid >> 6;
    const int c  = tid & 63;
    float acc0 = 0.f, acc1 = 0.f, acc2 = 0.f, acc3 = 0.f;
    #pragma unroll 4
    for (int k = 0; k < FEAT; ++k) {
        float w = ws[k * FEAT + c];
        acc0 += xs[(rb     ) * FEAT + k] * w;
        acc1 += xs[(rb +  4) * FEAT + k] * w;
        acc2 += xs[(rb +  8) * FEAT + k] * w;
        acc3 += xs[(rb + 12) * FEAT + k] * w;
    }
    float acc[4] = {acc0, acc1, acc2, acc3};
    for (int j = 0; j < 4; ++j) {
        int gr = row0 + rb + j * 4;
        if (gr < N) stf(out, (long)gr * FEAT + c, acc[j]);
    }
}

// ---- edge aggregation: agg[dst] += h[src] * dis[src]*dis[dst], 64 thr/edge ----
template <typename AT>
__global__ __launch_bounds__(256) void k_agg(const AT* __restrict__ h,
                                             const int* __restrict__ src,
                                             const int* __restrict__ dst,
                                             const float* __restrict__ dis,
                                             float* __restrict__ agg, int E, int N) {
    int e = blockIdx.x * 4 + (threadIdx.x >> 6);
    if (e >= E) return;
    int f = threadIdx.x & 63;
    int s = src[e], d = dst[e];
    if ((unsigned)s >= (unsigned)N || (unsigned)d >= (unsigned)N) return;
    float nrm = dis[s] * dis[d];
    atomicAdd(&agg[(long)d * FEAT + f], ldf(h, (long)s * FEAT + f) * nrm);
}

// ---- epi1: B = relu(B + A*dis^2 + b1)   (self-loop + bias + relu, B fp32) ----
template <typename AT>
__global__ __launch_bounds__(256) void k_epi1(float* __restrict__ B,
                                              const AT* __restrict__ A,
                                              const float* __restrict__ dis,
                                              const float* __restrict__ b1, int N) {
    long idx = (long)blockIdx.x * 256 + threadIdx.x;
    if (idx >= (long)N * FEAT) return;
    int i = (int)(idx >> 6), f = (int)(idx & 63);
    float di = dis[i];
    float v = B[idx] + ldf(A, idx) * di * di + b1[f];
    B[idx] = v > 0.f ? v : 0.f;
}

// ---- epi2: A = B + A*dis^2 + b2   (in place on A; B holds agg2) ----
template <typename AT>
__global__ __launch_bounds__(256) void k_epi2(AT* __restrict__ A,
                                              const float* __restrict__ B,
                                              const float* __restrict__ dis,
                                              const float* __restrict__ b2, int N) {
    long idx = (long)blockIdx.x * 256 + threadIdx.x;
    if (idx >= (long)N * FEAT) return;
    int i = (int)(idx >> 6), f = (int)(idx & 63);
    float di = dis[i];
    float v = B[idx] + ldf(A, idx) * di * di + b2[f];
    stf(A, idx, v);
}

// ---- scatter-mean accumulate: S[u] += A[i], cnt[u] += 1 ----
template <typename AT>
__global__ __launch_bounds__(256) void k_scatter(const AT* __restrict__ A,
                                                 const int* __restrict__ uidx,
                                                 float* __restrict__ S,
                                                 float* __restrict__ cnt, int N) {
    int i = blockIdx.x * 4 + (threadIdx.x >> 6);
    if (i >= N) return;
    int f = threadIdx.x & 63;
    int u = uidx[i];
    if ((unsigned)u >= (unsigned)N) return;
    atomicAdd(&S[(long)u * FEAT + f], ldf(A, (long)i * FEAT + f));
    if (f == 0) atomicAdd(&cnt[u], 1.0f);
}

// ---- final: out = cnt>0 ? S/cnt : 0 (in place, S aliases out) ----
__global__ __launch_bounds__(256) void k_final(float* __restrict__ S,
                                               const float* __restrict__ cnt, int N) {
    long idx = (long)blockIdx.x * 256 + threadIdx.x;
    if (idx >= (long)N * FEAT) return;
    int i = (int)(idx >> 6);
    float c = cnt[i];
    S[idx] = (c > 0.f) ? S[idx] / c : 0.f;
}

template <typename AT>
static void run_pipeline(const float* x, const int* src, const int* dst,
                         const int* uidx, const float* W1, const float* b1,
                         const float* W2, const float* b2,
                         float* out, float* dis, float* cnt, AT* A,
                         int N, int E, hipStream_t stream) {
    const size_t fbuf = (size_t)N * FEAT * sizeof(float);
    const long NF = (long)N * FEAT;
    const int gNF = (int)((NF + 255) / 256);
    float* B = out;   // d_out doubles as agg/scatter accumulator (fp32 N*FEAT)

    // degrees -> dis
    hipMemsetAsync(dis, 0, (size_t)N * sizeof(float), stream);
    k_deg<<<(E + 255) / 256, 256, 0, stream>>>(dst, dis, E, N);
    k_dis<<<(N + 255) / 256, 256, 0, stream>>>(dis, N);

    // layer 1: A = x@W1; B = agg(A); B = relu(B + A*dis^2 + b1)
    k_gemm1<AT><<<(N + 15) / 16, 256, 0, stream>>>(x, W1, A, N);
    hipMemsetAsync(B, 0, fbuf, stream);
    k_agg<AT><<<(E + 3) / 4, 256, 0, stream>>>(A, src, dst, dis, B, E, N);
    k_epi1<AT><<<gNF, 256, 0, stream>>>(B, A, dis, b1, N);

    // layer 2: A = B@W2; B = agg(A); A = B + A*dis^2 + b2
    k_gemm2<AT><<<(N + 15) / 16, 256, 0, stream>>>(B, W2, A, N);
    hipMemsetAsync(B, 0, fbuf, stream);
    k_agg<AT><<<(E + 3) / 4, 256, 0, stream>>>(A, src, dst, dis, B, E, N);
    k_epi2<AT><<<gNF, 256, 0, stream>>>(A, B, dis, b2, N);

    // scatter-mean into B (=out, contents of B consumed by epi2), then divide
    hipMemsetAsync(B, 0, fbuf, stream);
    hipMemsetAsync(cnt, 0, (size_t)N * sizeof(float), stream);
    k_scatter<AT><<<(N + 3) / 4, 256, 0, stream>>>(A, uidx, B, cnt, N);
    k_final<<<gNF, 256, 0, stream>>>(B, cnt, N);
}

extern "C" void kernel_launch(void* const* d_in, const int* in_sizes, int n_in,
                              void* d_out, int out_size, void* d_ws, size_t ws_size,
                              hipStream_t stream) {
    const float* x   = (const float*)d_in[0];
    const int* edge  = (const int*)d_in[1];
    const int* uidx  = (const int*)d_in[2];
    const float* W1  = (const float*)d_in[3];
    const float* b1  = (const float*)d_in[4];
    const float* W2  = (const float*)d_in[5];
    const float* b2  = (const float*)d_in[6];
    float* out       = (float*)d_out;

    const int N = in_sizes[2];       // 100000
    const int E = in_sizes[1] / 2;   // 1600000
    const int* src = edge;           // edge_index[0]
    const int* dst = edge + E;       // edge_index[1]

    // Workspace: [dis N*4][cnt N*4][pad to 256][A]
    size_t off = ((size_t)2 * N * sizeof(float) + 255) & ~(size_t)255;
    char* w = (char*)d_ws;
    float* dis = (float*)w;
    float* cnt = (float*)(w + (size_t)N * sizeof(float));
    char*  Ap  = w + off;

    const size_t need_f32 = off + (size_t)N * FEAT * sizeof(float);   // ~26.4 MB
    if (ws_size >= need_f32) {
        run_pipeline<float>(x, src, dst, uidx, W1, b1, W2, b2, out,
                            dis, cnt, (float*)Ap, N, E, stream);
    } else {
        run_pipeline<__hip_bfloat16>(x, src, dst, uidx, W1, b1, W2, b2, out,
                                     dis, cnt, (__hip_bfloat16*)Ap, N, E, stream);
    }
}

// Round 4
// 665.369 us; speedup vs baseline: 1.5987x; 1.5987x over previous
//
#include <hip/hip_runtime.h>
#include <hip/hip_bf16.h>

// GCN: h1 = relu(GCNConv(x, W1, b1)); out = scatter_mean(GCNConv(h1, W2, b2), user_idx)
// N=100000, E=1600000, dims 128 -> 64 -> 64. fp32 I/O, int32 indices.
//
// R3: pull-based aggregation over per-launch CSR. R2 profile showed push-atomic
// agg = 2x348us with WRITE_SIZE == E*64*4 B exactly: every fp32 atomic is a
// discrete EA write (non-coherent XCD L2s can't absorb device-scope atomics).
// CSR build uses only int atomics (rank counters); agg writes each row once.
// Fusions: self-loop+bias+relu in pull kernel; layer-2 pull scatters straight
// into d_out. Fallback to push-atomic path if ws too small.

#define FEAT 64
#define INDIM 128

// ==================== CSR build ====================

__global__ __launch_bounds__(256) void k_hist(const int* __restrict__ dst,
                                              int* __restrict__ cntE, int E, int N) {
    int e = blockIdx.x * 256 + threadIdx.x;
    if (e < E) {
        int d = dst[e];
        if ((unsigned)d < (unsigned)N) atomicAdd(&cntE[d], 1);
    }
}

// dis[i] = rsqrt(deg_in[i] + 1)   (+1 = self loop)
__global__ __launch_bounds__(256) void k_dis(const int* __restrict__ cntE,
                                             float* __restrict__ dis, int N) {
    int i = blockIdx.x * 256 + threadIdx.x;
    if (i < N) dis[i] = rsqrtf((float)cntE[i] + 1.0f);
}

// exclusive scan of cntE[0..N) -> rowptr[0..N], single block of 1024.
__global__ __launch_bounds__(1024) void k_scan(const int* __restrict__ c,
                                               int* __restrict__ rp, int N) {
    __shared__ int part[1024];
    const int tid = threadIdx.x;
    const int chunk = (N + 1023) >> 10;
    const int b = tid * chunk;
    const int e = min(b + chunk, N);
    int s = 0;
    for (int j = b; j < e; ++j) s += c[j];
    part[tid] = s;
    __syncthreads();
    for (int d = 1; d < 1024; d <<= 1) {       // Hillis-Steele inclusive
        int v = (tid >= d) ? part[tid - d] : 0;
        __syncthreads();
        part[tid] += v;
        __syncthreads();
    }
    int off = (tid == 0) ? 0 : part[tid - 1];
    for (int j = b; j < e; ++j) { rp[j] = off; off += c[j]; }
    if (tid == 1023) rp[N] = part[1023];
}

// scatter edges into CSR slots; tmp is zeroed rank counter (int atomics only)
__global__ __launch_bounds__(256) void k_fill(const int* __restrict__ src,
                                              const int* __restrict__ dst,
                                              const float* __restrict__ dis,
                                              const int* __restrict__ rp,
                                              int* __restrict__ tmp,
                                              int* __restrict__ col,
                                              float* __restrict__ wgt, int E, int N) {
    int e = blockIdx.x * 256 + threadIdx.x;
    if (e >= E) return;
    int s = src[e], d = dst[e];
    if ((unsigned)s >= (unsigned)N || (unsigned)d >= (unsigned)N) return;
    int r = atomicAdd(&tmp[d], 1);
    int p = rp[d] + r;
    col[p] = s;
    wgt[p] = dis[s] * dis[d];
}

// user-count histogram for scatter-mean denominator
__global__ __launch_bounds__(256) void k_ucnt(const int* __restrict__ uidx,
                                              float* __restrict__ cntf, int N) {
    int i = blockIdx.x * 256 + threadIdx.x;
    if (i < N) {
        int u = uidx[i];
        if ((unsigned)u < (unsigned)N) atomicAdd(&cntf[u], 1.0f);
    }
}

// ==================== GEMMs (LDS-staged, scalar FMA) ====================

__global__ __launch_bounds__(256) void k_gemm1(const float* __restrict__ x,
                                               const float* __restrict__ W,
                                               float* __restrict__ out, int N) {
    __shared__ float ws[INDIM * FEAT];   // 32 KB
    __shared__ float xs[16 * INDIM];     // 8 KB
    const int tid = threadIdx.x;
    for (int i = tid; i < INDIM * FEAT; i += 256) ws[i] = W[i];
    const int row0 = blockIdx.x * 16;
    for (int i = tid; i < 16 * INDIM; i += 256) {
        int r = i >> 7, k = i & (INDIM - 1);
        int gr = row0 + r;
        xs[i] = (gr < N) ? x[(long)gr * INDIM + k] : 0.0f;
    }
    __syncthreads();
    const int rb = tid >> 6;
    const int c  = tid & 63;
    float a0 = 0.f, a1 = 0.f, a2 = 0.f, a3 = 0.f;
    #pragma unroll 4
    for (int k = 0; k < INDIM; ++k) {
        float w = ws[k * FEAT + c];
        a0 += xs[(rb     ) * INDIM + k] * w;
        a1 += xs[(rb +  4) * INDIM + k] * w;
        a2 += xs[(rb +  8) * INDIM + k] * w;
        a3 += xs[(rb + 12) * INDIM + k] * w;
    }
    float acc[4] = {a0, a1, a2, a3};
    for (int j = 0; j < 4; ++j) {
        int gr = row0 + rb + j * 4;
        if (gr < N) out[(long)gr * FEAT + c] = acc[j];
    }
}

__global__ __launch_bounds__(256) void k_gemm2(const float* __restrict__ h,
                                               const float* __restrict__ W,
                                               float* __restrict__ out, int N) {
    __shared__ float ws[FEAT * FEAT];    // 16 KB
    __shared__ float xs[16 * FEAT];      // 4 KB
    const int tid = threadIdx.x;
    for (int i = tid; i < FEAT * FEAT; i += 256) ws[i] = W[i];
    const int row0 = blockIdx.x * 16;
    for (int i = tid; i < 16 * FEAT; i += 256) {
        int r = i >> 6, k = i & 63;
        int gr = row0 + r;
        xs[i] = (gr < N) ? h[(long)gr * FEAT + k] : 0.0f;
    }
    __syncthreads();
    const int rb = tid >> 6;
    const int c  = tid & 63;
    float a0 = 0.f, a1 = 0.f, a2 = 0.f, a3 = 0.f;
    #pragma unroll 4
    for (int k = 0; k < FEAT; ++k) {
        float w = ws[k * FEAT + c];
        a0 += xs[(rb     ) * FEAT + k] * w;
        a1 += xs[(rb +  4) * FEAT + k] * w;
        a2 += xs[(rb +  8) * FEAT + k] * w;
        a3 += xs[(rb + 12) * FEAT + k] * w;
    }
    float acc[4] = {a0, a1, a2, a3};
    for (int j = 0; j < 4; ++j) {
        int gr = row0 + rb + j * 4;
        if (gr < N) out[(long)gr * FEAT + c] = acc[j];
    }
}

// ==================== pull aggregation (atomic-free) ====================
// one wave per node: acc[f] = sum_j wgt[j]*A[col[j]][f]; + self + bias (+relu)

__global__ __launch_bounds__(256) void k_agg1(const float* __restrict__ A,
                                              const int* __restrict__ rp,
                                              const int* __restrict__ col,
                                              const float* __restrict__ wgt,
                                              const float* __restrict__ dis,
                                              const float* __restrict__ bias,
                                              float* __restrict__ H, int N) {
    int i = blockIdx.x * 4 + (threadIdx.x >> 6);
    if (i >= N) return;
    int f = threadIdx.x & 63;
    int jb = rp[i], je = rp[i + 1];
    float acc = 0.f;
    int j = jb;
    for (; j + 3 < je; j += 4) {
        int   c0 = col[j], c1 = col[j+1], c2 = col[j+2], c3 = col[j+3];
        float w0 = wgt[j], w1 = wgt[j+1], w2 = wgt[j+2], w3 = wgt[j+3];
        acc += w0 * A[(long)c0 * FEAT + f];
        acc += w1 * A[(long)c1 * FEAT + f];
        acc += w2 * A[(long)c2 * FEAT + f];
        acc += w3 * A[(long)c3 * FEAT + f];
    }
    for (; j < je; ++j) acc += wgt[j] * A[(long)col[j] * FEAT + f];
    float di = dis[i];
    float v = acc + A[(long)i * FEAT + f] * di * di + bias[f];
    H[(long)i * FEAT + f] = fmaxf(v, 0.f);              // relu
}

// layer-2 pull + fused scatter-mean accumulate into S (=d_out, zeroed)
__global__ __launch_bounds__(256) void k_agg2s(const float* __restrict__ A,
                                               const int* __restrict__ rp,
                                               const int* __restrict__ col,
                                               const float* __restrict__ wgt,
                                               const float* __restrict__ dis,
                                               const float* __restrict__ bias,
                                               const int* __restrict__ uidx,
                                               float* __restrict__ S, int N) {
    int i = blockIdx.x * 4 + (threadIdx.x >> 6);
    if (i >= N) return;
    int f = threadIdx.x & 63;
    int jb = rp[i], je = rp[i + 1];
    float acc = 0.f;
    int j = jb;
    for (; j + 3 < je; j += 4) {
        int   c0 = col[j], c1 = col[j+1], c2 = col[j+2], c3 = col[j+3];
        float w0 = wgt[j], w1 = wgt[j+1], w2 = wgt[j+2], w3 = wgt[j+3];
        acc += w0 * A[(long)c0 * FEAT + f];
        acc += w1 * A[(long)c1 * FEAT + f];
        acc += w2 * A[(long)c2 * FEAT + f];
        acc += w3 * A[(long)c3 * FEAT + f];
    }
    for (; j < je; ++j) acc += wgt[j] * A[(long)col[j] * FEAT + f];
    float di = dis[i];
    float v = acc + A[(long)i * FEAT + f] * di * di + bias[f];
    int u = uidx[i];
    if ((unsigned)u < (unsigned)N) atomicAdd(&S[(long)u * FEAT + f], v);
}

// final: out = cnt>0 ? out/cnt : 0 (in place)
__global__ __launch_bounds__(256) void k_final(float* __restrict__ S,
                                               const float* __restrict__ cnt, int N) {
    long idx = (long)blockIdx.x * 256 + threadIdx.x;
    if (idx >= (long)N * FEAT) return;
    int i = (int)(idx >> 6);
    float c = cnt[i];
    S[idx] = (c > 0.f) ? S[idx] / c : 0.f;
}

// ==================== fallback (R2 push-atomic path) ====================

__global__ __launch_bounds__(256) void k_degf(const int* __restrict__ dst,
                                              float* __restrict__ deg, int E, int N) {
    int e = blockIdx.x * 256 + threadIdx.x;
    if (e < E) {
        int d = dst[e];
        if ((unsigned)d < (unsigned)N) atomicAdd(&deg[d], 1.0f);
    }
}
__global__ __launch_bounds__(256) void k_disf(float* __restrict__ deg, int N) {
    int i = blockIdx.x * 256 + threadIdx.x;
    if (i < N) deg[i] = rsqrtf(deg[i] + 1.0f);
}
__global__ __launch_bounds__(256) void k_aggp(const float* __restrict__ h,
                                              const int* __restrict__ src,
                                              const int* __restrict__ dst,
                                              const float* __restrict__ dis,
                                              float* __restrict__ agg, int E, int N) {
    int e = blockIdx.x * 4 + (threadIdx.x >> 6);
    if (e >= E) return;
    int f = threadIdx.x & 63;
    int s = src[e], d = dst[e];
    if ((unsigned)s >= (unsigned)N || (unsigned)d >= (unsigned)N) return;
    float nrm = dis[s] * dis[d];
    atomicAdd(&agg[(long)d * FEAT + f], h[(long)s * FEAT + f] * nrm);
}
__global__ __launch_bounds__(256) void k_epi1(float* __restrict__ B, const float* __restrict__ A,
                                              const float* __restrict__ dis,
                                              const float* __restrict__ b1, int N) {
    long idx = (long)blockIdx.x * 256 + threadIdx.x;
    if (idx >= (long)N * FEAT) return;
    int i = (int)(idx >> 6), f = (int)(idx & 63);
    float di = dis[i];
    float v = B[idx] + A[idx] * di * di + b1[f];
    B[idx] = v > 0.f ? v : 0.f;
}
__global__ __launch_bounds__(256) void k_epi2(float* __restrict__ A, const float* __restrict__ B,
                                              const float* __restrict__ dis,
                                              const float* __restrict__ b2, int N) {
    long idx = (long)blockIdx.x * 256 + threadIdx.x;
    if (idx >= (long)N * FEAT) return;
    int i = (int)(idx >> 6), f = (int)(idx & 63);
    float di = dis[i];
    A[idx] = B[idx] + A[idx] * di * di + b2[f];
}
__global__ __launch_bounds__(256) void k_scat(const float* __restrict__ A,
                                              const int* __restrict__ uidx,
                                              float* __restrict__ S, float* __restrict__ cnt, int N) {
    int i = blockIdx.x * 4 + (threadIdx.x >> 6);
    if (i >= N) return;
    int f = threadIdx.x & 63;
    int u = uidx[i];
    if ((unsigned)u >= (unsigned)N) return;
    atomicAdd(&S[(long)u * FEAT + f], A[(long)i * FEAT + f]);
    if (f == 0) atomicAdd(&cnt[u], 1.0f);
}

extern "C" void kernel_launch(void* const* d_in, const int* in_sizes, int n_in,
                              void* d_out, int out_size, void* d_ws, size_t ws_size,
                              hipStream_t stream) {
    const float* x   = (const float*)d_in[0];
    const int* edge  = (const int*)d_in[1];
    const int* uidx  = (const int*)d_in[2];
    const float* W1  = (const float*)d_in[3];
    const float* b1  = (const float*)d_in[4];
    const float* W2  = (const float*)d_in[5];
    const float* b2  = (const float*)d_in[6];
    float* out       = (float*)d_out;

    const int N = in_sizes[2];       // 100000
    const int E = in_sizes[1] / 2;   // 1600000
    const int* src = edge;
    const int* dst = edge + E;

    const size_t fbuf = (size_t)N * FEAT * sizeof(float);   // 25.6 MB
    const long NF = (long)N * FEAT;
    const int gNF = (int)((NF + 255) / 256);
    const int gE  = (E + 255) / 256;
    const int gN  = (N + 255) / 256;
    const int gN4 = (N + 3) / 4;

    auto align256 = [](size_t v) { return (v + 255) & ~(size_t)255; };

    // CSR-path layout: dis, cntf, rowptr, cntE, col, wgt, A
    char* w = (char*)d_ws;
    size_t o = 0;
    float* dis  = (float*)(w + o); o = align256(o + (size_t)N * 4);
    float* cntf = (float*)(w + o); o = align256(o + (size_t)N * 4);
    int*   rp   = (int*)  (w + o); o = align256(o + (size_t)(N + 1) * 4);
    int*   cntE = (int*)  (w + o); o = align256(o + (size_t)N * 4);
    int*   col  = (int*)  (w + o); o = align256(o + (size_t)E * 4);
    float* wgt  = (float*)(w + o); o = align256(o + (size_t)E * 4);
    float* A    = (float*)(w + o); o = align256(o + fbuf);
    const size_t need_csr = o;   // ~40.1 MB

    if (ws_size >= need_csr) {
        // --- CSR build ---
        hipMemsetAsync(cntE, 0, (size_t)N * 4, stream);
        k_hist<<<gE, 256, 0, stream>>>(dst, cntE, E, N);
        k_dis <<<gN, 256, 0, stream>>>(cntE, dis, N);
        k_scan<<<1, 1024, 0, stream>>>(cntE, rp, N);
        hipMemsetAsync(cntE, 0, (size_t)N * 4, stream);
        k_fill<<<gE, 256, 0, stream>>>(src, dst, dis, rp, cntE, col, wgt, E, N);
        hipMemsetAsync(cntf, 0, (size_t)N * 4, stream);
        k_ucnt<<<gN, 256, 0, stream>>>(uidx, cntf, N);

        // --- layer 1: A = x@W1; H(=out) = relu(agg + self + b1) ---
        k_gemm1<<<(N + 15) / 16, 256, 0, stream>>>(x, W1, A, N);
        k_agg1 <<<gN4, 256, 0, stream>>>(A, rp, col, wgt, dis, b1, out, N);

        // --- layer 2: A = H@W2; scatter(agg + self + b2) into out ---
        k_gemm2<<<(N + 15) / 16, 256, 0, stream>>>(out, W2, A, N);
        hipMemsetAsync(out, 0, fbuf, stream);
        k_agg2s<<<gN4, 256, 0, stream>>>(A, rp, col, wgt, dis, b2, uidx, out, N);
        k_final<<<gNF, 256, 0, stream>>>(out, cntf, N);
    } else {
        // --- fallback: push-atomic path (R2, proven) ---
        char* w2p = (char*)d_ws;
        float* disF = (float*)w2p;
        float* cntF = (float*)(w2p + (size_t)N * 4);
        float* Af   = (float*)(w2p + align256((size_t)2 * N * 4));
        float* B = out;

        hipMemsetAsync(disF, 0, (size_t)N * 4, stream);
        k_degf<<<gE, 256, 0, stream>>>(dst, disF, E, N);
        k_disf<<<gN, 256, 0, stream>>>(disF, N);

        k_gemm1<<<(N + 15) / 16, 256, 0, stream>>>(x, W1, Af, N);
        hipMemsetAsync(B, 0, fbuf, stream);
        k_aggp<<<(E + 3) / 4, 256, 0, stream>>>(Af, src, dst, disF, B, E, N);
        k_epi1<<<gNF, 256, 0, stream>>>(B, Af, disF, b1, N);

        k_gemm2<<<(N + 15) / 16, 256, 0, stream>>>(B, W2, Af, N);
        hipMemsetAsync(B, 0, fbuf, stream);
        k_aggp<<<(E + 3) / 4, 256, 0, stream>>>(Af, src, dst, disF, B, E, N);
        k_epi2<<<gNF, 256, 0, stream>>>(Af, B, disF, b2, N);

        hipMemsetAsync(B, 0, fbuf, stream);
        hipMemsetAsync(cntF, 0, (size_t)N * 4, stream);
        k_scat<<<gN4, 256, 0, stream>>>(Af, uidx, B, cntF, N);
        k_final<<<gNF, 256, 0, stream>>>(B, cntF, N);
    }
}

// Round 5
// 549.315 us; speedup vs baseline: 1.9364x; 1.2113x over previous
//
#include <hip/hip_runtime.h>
#include <hip/hip_bf16.h>

// GCN: h1 = relu(GCNConv(x, W1, b1)); out = scatter_mean(GCNConv(h1, W2, b2), user_idx)
// N=100000, E=1600000, dims 128 -> 64 -> 64. fp32 I/O, int32 indices.
//
// R4: R3's pull-CSR design kept; single-block scan (164us, 1 CU, latency-bound)
// replaced with 3-phase multi-block scan (~10us). Everything else unchanged so
// the next profile cleanly attributes agg/gemm costs.

#define FEAT 64
#define INDIM 128

#define SCAN_BS 256
#define SCAN_ELEMS 8
#define SCAN_CHUNK (SCAN_BS * SCAN_ELEMS)   // 2048 elems/block

// ==================== CSR build ====================

__global__ __launch_bounds__(256) void k_hist(const int* __restrict__ dst,
                                              int* __restrict__ cntE, int E, int N) {
    int e = blockIdx.x * 256 + threadIdx.x;
    if (e < E) {
        int d = dst[e];
        if ((unsigned)d < (unsigned)N) atomicAdd(&cntE[d], 1);
    }
}

// dis[i] = rsqrt(deg_in[i] + 1)   (+1 = self loop)
__global__ __launch_bounds__(256) void k_dis(const int* __restrict__ cntE,
                                             float* __restrict__ dis, int N) {
    int i = blockIdx.x * 256 + threadIdx.x;
    if (i < N) dis[i] = rsqrtf((float)cntE[i] + 1.0f);
}

// --- 3-phase exclusive scan of cntE[0..N) -> rp[0..N] ---
// phase 1: per-block chunk scan + block totals
__global__ __launch_bounds__(SCAN_BS) void k_scan1(const int* __restrict__ c,
                                                   int* __restrict__ rp,
                                                   int* __restrict__ ptot, int N) {
    __shared__ int lds[SCAN_BS];
    const int base = blockIdx.x * SCAN_CHUNK;
    const int tb = base + threadIdx.x * SCAN_ELEMS;
    int vals[SCAN_ELEMS];
    int s = 0;
    #pragma unroll
    for (int k = 0; k < SCAN_ELEMS; ++k) {
        int idx = tb + k;
        int v = (idx < N) ? c[idx] : 0;
        vals[k] = s;           // exclusive within thread
        s += v;
    }
    lds[threadIdx.x] = s;
    __syncthreads();
    for (int d = 1; d < SCAN_BS; d <<= 1) {   // Hillis-Steele inclusive
        int v = (threadIdx.x >= d) ? lds[threadIdx.x - d] : 0;
        __syncthreads();
        lds[threadIdx.x] += v;
        __syncthreads();
    }
    int toff = (threadIdx.x == 0) ? 0 : lds[threadIdx.x - 1];
    #pragma unroll
    for (int k = 0; k < SCAN_ELEMS; ++k) {
        int idx = tb + k;
        if (idx < N) rp[idx] = toff + vals[k];
    }
    if (threadIdx.x == SCAN_BS - 1) ptot[blockIdx.x] = lds[SCAN_BS - 1];
}

// phase 2: one block exclusive-scans block totals (nb <= 1024)
__global__ __launch_bounds__(1024) void k_scan2(int* __restrict__ ptot,
                                                int* __restrict__ poff,
                                                int* __restrict__ rpN, int nb) {
    __shared__ int lds[1024];
    int tid = threadIdx.x;
    lds[tid] = (tid < nb) ? ptot[tid] : 0;
    __syncthreads();
    for (int d = 1; d < 1024; d <<= 1) {
        int v = (tid >= d) ? lds[tid - d] : 0;
        __syncthreads();
        lds[tid] += v;
        __syncthreads();
    }
    if (tid < nb) poff[tid] = (tid == 0) ? 0 : lds[tid - 1];
    if (tid == nb - 1) *rpN = lds[tid];     // total edges -> rp[N]
}

// phase 3: add block offsets
__global__ __launch_bounds__(SCAN_BS) void k_scan3(int* __restrict__ rp,
                                                   const int* __restrict__ poff, int N) {
    int off = poff[blockIdx.x];
    const int tb = blockIdx.x * SCAN_CHUNK + threadIdx.x * SCAN_ELEMS;
    #pragma unroll
    for (int k = 0; k < SCAN_ELEMS; ++k) {
        int idx = tb + k;
        if (idx < N) rp[idx] += off;
    }
}

// scatter edges into CSR slots; tmp is zeroed rank counter (int atomics only)
__global__ __launch_bounds__(256) void k_fill(const int* __restrict__ src,
                                              const int* __restrict__ dst,
                                              const float* __restrict__ dis,
                                              const int* __restrict__ rp,
                                              int* __restrict__ tmp,
                                              int* __restrict__ col,
                                              float* __restrict__ wgt, int E, int N) {
    int e = blockIdx.x * 256 + threadIdx.x;
    if (e >= E) return;
    int s = src[e], d = dst[e];
    if ((unsigned)s >= (unsigned)N || (unsigned)d >= (unsigned)N) return;
    int r = atomicAdd(&tmp[d], 1);
    int p = rp[d] + r;
    col[p] = s;
    wgt[p] = dis[s] * dis[d];
}

// user-count histogram for scatter-mean denominator
__global__ __launch_bounds__(256) void k_ucnt(const int* __restrict__ uidx,
                                              float* __restrict__ cntf, int N) {
    int i = blockIdx.x * 256 + threadIdx.x;
    if (i < N) {
        int u = uidx[i];
        if ((unsigned)u < (unsigned)N) atomicAdd(&cntf[u], 1.0f);
    }
}

// ==================== GEMMs (LDS-staged, scalar FMA) ====================

__global__ __launch_bounds__(256) void k_gemm1(const float* __restrict__ x,
                                               const float* __restrict__ W,
                                               float* __restrict__ out, int N) {
    __shared__ float ws[INDIM * FEAT];   // 32 KB
    __shared__ float xs[16 * INDIM];     // 8 KB
    const int tid = threadIdx.x;
    for (int i = tid; i < INDIM * FEAT; i += 256) ws[i] = W[i];
    const int row0 = blockIdx.x * 16;
    for (int i = tid; i < 16 * INDIM; i += 256) {
        int r = i >> 7, k = i & (INDIM - 1);
        int gr = row0 + r;
        xs[i] = (gr < N) ? x[(long)gr * INDIM + k] : 0.0f;
    }
    __syncthreads();
    const int rb = tid >> 6;
    const int c  = tid & 63;
    float a0 = 0.f, a1 = 0.f, a2 = 0.f, a3 = 0.f;
    #pragma unroll 4
    for (int k = 0; k < INDIM; ++k) {
        float w = ws[k * FEAT + c];
        a0 += xs[(rb     ) * INDIM + k] * w;
        a1 += xs[(rb +  4) * INDIM + k] * w;
        a2 += xs[(rb +  8) * INDIM + k] * w;
        a3 += xs[(rb + 12) * INDIM + k] * w;
    }
    float acc[4] = {a0, a1, a2, a3};
    for (int j = 0; j < 4; ++j) {
        int gr = row0 + rb + j * 4;
        if (gr < N) out[(long)gr * FEAT + c] = acc[j];
    }
}

__global__ __launch_bounds__(256) void k_gemm2(const float* __restrict__ h,
                                               const float* __restrict__ W,
                                               float* __restrict__ out, int N) {
    __shared__ float ws[FEAT * FEAT];    // 16 KB
    __shared__ float xs[16 * FEAT];      // 4 KB
    const int tid = threadIdx.x;
    for (int i = tid; i < FEAT * FEAT; i += 256) ws[i] = W[i];
    const int row0 = blockIdx.x * 16;
    for (int i = tid; i < 16 * FEAT; i += 256) {
        int r = i >> 6, k = i & 63;
        int gr = row0 + r;
        xs[i] = (gr < N) ? h[(long)gr * FEAT + k] : 0.0f;
    }
    __syncthreads();
    const int rb = tid >> 6;
    const int c  = tid & 63;
    float a0 = 0.f, a1 = 0.f, a2 = 0.f, a3 = 0.f;
    #pragma unroll 4
    for (int k = 0; k < FEAT; ++k) {
        float w = ws[k * FEAT + c];
        a0 += xs[(rb     ) * FEAT + k] * w;
        a1 += xs[(rb +  4) * FEAT + k] * w;
        a2 += xs[(rb +  8) * FEAT + k] * w;
        a3 += xs[(rb + 12) * FEAT + k] * w;
    }
    float acc[4] = {a0, a1, a2, a3};
    for (int j = 0; j < 4; ++j) {
        int gr = row0 + rb + j * 4;
        if (gr < N) out[(long)gr * FEAT + c] = acc[j];
    }
}

// ==================== pull aggregation (atomic-free) ====================

__global__ __launch_bounds__(256) void k_agg1(const float* __restrict__ A,
                                              const int* __restrict__ rp,
                                              const int* __restrict__ col,
                                              const float* __restrict__ wgt,
                                              const float* __restrict__ dis,
                                              const float* __restrict__ bias,
                                              float* __restrict__ H, int N) {
    int i = blockIdx.x * 4 + (threadIdx.x >> 6);
    if (i >= N) return;
    int f = threadIdx.x & 63;
    int jb = rp[i], je = rp[i + 1];
    float acc = 0.f;
    int j = jb;
    for (; j + 3 < je; j += 4) {
        int   c0 = col[j], c1 = col[j+1], c2 = col[j+2], c3 = col[j+3];
        float w0 = wgt[j], w1 = wgt[j+1], w2 = wgt[j+2], w3 = wgt[j+3];
        acc += w0 * A[(long)c0 * FEAT + f];
        acc += w1 * A[(long)c1 * FEAT + f];
        acc += w2 * A[(long)c2 * FEAT + f];
        acc += w3 * A[(long)c3 * FEAT + f];
    }
    for (; j < je; ++j) acc += wgt[j] * A[(long)col[j] * FEAT + f];
    float di = dis[i];
    float v = acc + A[(long)i * FEAT + f] * di * di + bias[f];
    H[(long)i * FEAT + f] = fmaxf(v, 0.f);              // relu
}

// layer-2 pull + fused scatter-mean accumulate into S (=d_out, zeroed)
__global__ __launch_bounds__(256) void k_agg2s(const float* __restrict__ A,
                                               const int* __restrict__ rp,
                                               const int* __restrict__ col,
                                               const float* __restrict__ wgt,
                                               const float* __restrict__ dis,
                                               const float* __restrict__ bias,
                                               const int* __restrict__ uidx,
                                               float* __restrict__ S, int N) {
    int i = blockIdx.x * 4 + (threadIdx.x >> 6);
    if (i >= N) return;
    int f = threadIdx.x & 63;
    int jb = rp[i], je = rp[i + 1];
    float acc = 0.f;
    int j = jb;
    for (; j + 3 < je; j += 4) {
        int   c0 = col[j], c1 = col[j+1], c2 = col[j+2], c3 = col[j+3];
        float w0 = wgt[j], w1 = wgt[j+1], w2 = wgt[j+2], w3 = wgt[j+3];
        acc += w0 * A[(long)c0 * FEAT + f];
        acc += w1 * A[(long)c1 * FEAT + f];
        acc += w2 * A[(long)c2 * FEAT + f];
        acc += w3 * A[(long)c3 * FEAT + f];
    }
    for (; j < je; ++j) acc += wgt[j] * A[(long)col[j] * FEAT + f];
    float di = dis[i];
    float v = acc + A[(long)i * FEAT + f] * di * di + bias[f];
    int u = uidx[i];
    if ((unsigned)u < (unsigned)N) atomicAdd(&S[(long)u * FEAT + f], v);
}

// final: out = cnt>0 ? out/cnt : 0 (in place)
__global__ __launch_bounds__(256) void k_final(float* __restrict__ S,
                                               const float* __restrict__ cnt, int N) {
    long idx = (long)blockIdx.x * 256 + threadIdx.x;
    if (idx >= (long)N * FEAT) return;
    int i = (int)(idx >> 6);
    float c = cnt[i];
    S[idx] = (c > 0.f) ? S[idx] / c : 0.f;
}

// ==================== fallback (push-atomic path) ====================

__global__ __launch_bounds__(256) void k_degf(const int* __restrict__ dst,
                                              float* __restrict__ deg, int E, int N) {
    int e = blockIdx.x * 256 + threadIdx.x;
    if (e < E) {
        int d = dst[e];
        if ((unsigned)d < (unsigned)N) atomicAdd(&deg[d], 1.0f);
    }
}
__global__ __launch_bounds__(256) void k_disf(float* __restrict__ deg, int N) {
    int i = blockIdx.x * 256 + threadIdx.x;
    if (i < N) deg[i] = rsqrtf(deg[i] + 1.0f);
}
__global__ __launch_bounds__(256) void k_aggp(const float* __restrict__ h,
                                              const int* __restrict__ src,
                                              const int* __restrict__ dst,
                                              const float* __restrict__ dis,
                                              float* __restrict__ agg, int E, int N) {
    int e = blockIdx.x * 4 + (threadIdx.x >> 6);
    if (e >= E) return;
    int f = threadIdx.x & 63;
    int s = src[e], d = dst[e];
    if ((unsigned)s >= (unsigned)N || (unsigned)d >= (unsigned)N) return;
    float nrm = dis[s] * dis[d];
    atomicAdd(&agg[(long)d * FEAT + f], h[(long)s * FEAT + f] * nrm);
}
__global__ __launch_bounds__(256) void k_epi1(float* __restrict__ B, const float* __restrict__ A,
                                              const float* __restrict__ dis,
                                              const float* __restrict__ b1, int N) {
    long idx = (long)blockIdx.x * 256 + threadIdx.x;
    if (idx >= (long)N * FEAT) return;
    int i = (int)(idx >> 6), f = (int)(idx & 63);
    float di = dis[i];
    float v = B[idx] + A[idx] * di * di + b1[f];
    B[idx] = v > 0.f ? v : 0.f;
}
__global__ __launch_bounds__(256) void k_epi2(float* __restrict__ A, const float* __restrict__ B,
                                              const float* __restrict__ dis,
                                              const float* __restrict__ b2, int N) {
    long idx = (long)blockIdx.x * 256 + threadIdx.x;
    if (idx >= (long)N * FEAT) return;
    int i = (int)(idx >> 6), f = (int)(idx & 63);
    float di = dis[i];
    A[idx] = B[idx] + A[idx] * di * di + b2[f];
}
__global__ __launch_bounds__(256) void k_scat(const float* __restrict__ A,
                                              const int* __restrict__ uidx,
                                              float* __restrict__ S, float* __restrict__ cnt, int N) {
    int i = blockIdx.x * 4 + (threadIdx.x >> 6);
    if (i >= N) return;
    int f = threadIdx.x & 63;
    int u = uidx[i];
    if ((unsigned)u >= (unsigned)N) return;
    atomicAdd(&S[(long)u * FEAT + f], A[(long)i * FEAT + f]);
    if (f == 0) atomicAdd(&cnt[u], 1.0f);
}

extern "C" void kernel_launch(void* const* d_in, const int* in_sizes, int n_in,
                              void* d_out, int out_size, void* d_ws, size_t ws_size,
                              hipStream_t stream) {
    const float* x   = (const float*)d_in[0];
    const int* edge  = (const int*)d_in[1];
    const int* uidx  = (const int*)d_in[2];
    const float* W1  = (const float*)d_in[3];
    const float* b1  = (const float*)d_in[4];
    const float* W2  = (const float*)d_in[5];
    const float* b2  = (const float*)d_in[6];
    float* out       = (float*)d_out;

    const int N = in_sizes[2];       // 100000
    const int E = in_sizes[1] / 2;   // 1600000
    const int* src = edge;
    const int* dst = edge + E;

    const size_t fbuf = (size_t)N * FEAT * sizeof(float);   // 25.6 MB
    const long NF = (long)N * FEAT;
    const int gNF = (int)((NF + 255) / 256);
    const int gE  = (E + 255) / 256;
    const int gN  = (N + 255) / 256;
    const int gN4 = (N + 3) / 4;
    const int nbScan = (N + SCAN_CHUNK - 1) / SCAN_CHUNK;   // 49 for N=100000

    auto align256 = [](size_t v) { return (v + 255) & ~(size_t)255; };

    // CSR-path layout: dis, cntf, rowptr, cntE, ptot, poff, col, wgt, A
    char* w = (char*)d_ws;
    size_t o = 0;
    float* dis  = (float*)(w + o); o = align256(o + (size_t)N * 4);
    float* cntf = (float*)(w + o); o = align256(o + (size_t)N * 4);
    int*   rp   = (int*)  (w + o); o = align256(o + (size_t)(N + 1) * 4);
    int*   cntE = (int*)  (w + o); o = align256(o + (size_t)N * 4);
    int*   ptot = (int*)  (w + o); o = align256(o + (size_t)1024 * 4);
    int*   poff = (int*)  (w + o); o = align256(o + (size_t)1024 * 4);
    int*   col  = (int*)  (w + o); o = align256(o + (size_t)E * 4);
    float* wgt  = (float*)(w + o); o = align256(o + (size_t)E * 4);
    float* A    = (float*)(w + o); o = align256(o + fbuf);
    const size_t need_csr = o;   // ~40.1 MB

    if (ws_size >= need_csr && nbScan <= 1024) {
        // --- CSR build ---
        hipMemsetAsync(cntE, 0, (size_t)N * 4, stream);
        k_hist <<<gE, 256, 0, stream>>>(dst, cntE, E, N);
        k_dis  <<<gN, 256, 0, stream>>>(cntE, dis, N);
        k_scan1<<<nbScan, SCAN_BS, 0, stream>>>(cntE, rp, ptot, N);
        k_scan2<<<1, 1024, 0, stream>>>(ptot, poff, rp + N, nbScan);
        k_scan3<<<nbScan, SCAN_BS, 0, stream>>>(rp, poff, N);
        hipMemsetAsync(cntE, 0, (size_t)N * 4, stream);
        k_fill <<<gE, 256, 0, stream>>>(src, dst, dis, rp, cntE, col, wgt, E, N);
        hipMemsetAsync(cntf, 0, (size_t)N * 4, stream);
        k_ucnt <<<gN, 256, 0, stream>>>(uidx, cntf, N);

        // --- layer 1: A = x@W1; H(=out) = relu(agg + self + b1) ---
        k_gemm1<<<(N + 15) / 16, 256, 0, stream>>>(x, W1, A, N);
        k_agg1 <<<gN4, 256, 0, stream>>>(A, rp, col, wgt, dis, b1, out, N);

        // --- layer 2: A = H@W2; scatter(agg + self + b2) into out ---
        k_gemm2<<<(N + 15) / 16, 256, 0, stream>>>(out, W2, A, N);
        hipMemsetAsync(out, 0, fbuf, stream);
        k_agg2s<<<gN4, 256, 0, stream>>>(A, rp, col, wgt, dis, b2, uidx, out, N);
        k_final<<<gNF, 256, 0, stream>>>(out, cntf, N);
    } else {
        // --- fallback: push-atomic path (proven) ---
        char* w2p = (char*)d_ws;
        float* disF = (float*)w2p;
        float* cntF = (float*)(w2p + (size_t)N * 4);
        float* Af   = (float*)(w2p + align256((size_t)2 * N * 4));
        float* B = out;

        hipMemsetAsync(disF, 0, (size_t)N * 4, stream);
        k_degf<<<gE, 256, 0, stream>>>(dst, disF, E, N);
        k_disf<<<gN, 256, 0, stream>>>(disF, N);

        k_gemm1<<<(N + 15) / 16, 256, 0, stream>>>(x, W1, Af, N);
        hipMemsetAsync(B, 0, fbuf, stream);
        k_aggp<<<(E + 3) / 4, 256, 0, stream>>>(Af, src, dst, disF, B, E, N);
        k_epi1<<<gNF, 256, 0, stream>>>(B, Af, disF, b1, N);

        k_gemm2<<<(N + 15) / 16, 256, 0, stream>>>(B, W2, Af, N);
        hipMemsetAsync(B, 0, fbuf, stream);
        k_aggp<<<(E + 3) / 4, 256, 0, stream>>>(Af, src, dst, disF, B, E, N);
        k_epi2<<<gNF, 256, 0, stream>>>(Af, B, disF, b2, N);

        hipMemsetAsync(B, 0, fbuf, stream);
        hipMemsetAsync(cntF, 0, (size_t)N * 4, stream);
        k_scat<<<gN4, 256, 0, stream>>>(Af, uidx, B, cntF, N);
        k_final<<<gNF, 256, 0, stream>>>(B, cntF, N);
    }
}

// Round 6
// 544.523 us; speedup vs baseline: 1.9535x; 1.0088x over previous
//
#include <hip/hip_runtime.h>
#include <hip/hip_bf16.h>

// GCN: h1 = relu(GCNConv(x, W1, b1)); out = scatter_mean(GCNConv(h1, W2, b2), user_idx)
// N=100000, E=1600000, dims 128 -> 64 -> 64. fp32 I/O, int32 indices.
//
// R5 profile: k_fill 112us, WRITE_SIZE=156MB (payload 12.8MB) — two random 4B
// stores/edge (col+wgt) dirty 2 random 64B lines each, write-amplified ~12x.
// R6: weight is separable (msg = h[s]*dis[s]*dis[d]), so pre-scale rows in the
// GEMM epilogue (A[r] = (x@W)[r]*dis[r]) and scale by dis[i] in the agg
// epilogue. wgt array GONE; k_fill writes only col (1 random 4B store/edge).

#define FEAT 64
#define INDIM 128

#define SCAN_BS 256
#define SCAN_ELEMS 8
#define SCAN_CHUNK (SCAN_BS * SCAN_ELEMS)   // 2048 elems/block

// ==================== CSR build ====================

__global__ __launch_bounds__(256) void k_hist(const int* __restrict__ dst,
                                              int* __restrict__ cntE, int E, int N) {
    int e = blockIdx.x * 256 + threadIdx.x;
    if (e < E) {
        int d = dst[e];
        if ((unsigned)d < (unsigned)N) atomicAdd(&cntE[d], 1);
    }
}

// dis[i] = rsqrt(deg_in[i] + 1)   (+1 = self loop)
__global__ __launch_bounds__(256) void k_dis(const int* __restrict__ cntE,
                                             float* __restrict__ dis, int N) {
    int i = blockIdx.x * 256 + threadIdx.x;
    if (i < N) dis[i] = rsqrtf((float)cntE[i] + 1.0f);
}

// --- 3-phase exclusive scan of cntE[0..N) -> rp[0..N] ---
__global__ __launch_bounds__(SCAN_BS) void k_scan1(const int* __restrict__ c,
                                                   int* __restrict__ rp,
                                                   int* __restrict__ ptot, int N) {
    __shared__ int lds[SCAN_BS];
    const int base = blockIdx.x * SCAN_CHUNK;
    const int tb = base + threadIdx.x * SCAN_ELEMS;
    int vals[SCAN_ELEMS];
    int s = 0;
    #pragma unroll
    for (int k = 0; k < SCAN_ELEMS; ++k) {
        int idx = tb + k;
        int v = (idx < N) ? c[idx] : 0;
        vals[k] = s;           // exclusive within thread
        s += v;
    }
    lds[threadIdx.x] = s;
    __syncthreads();
    for (int d = 1; d < SCAN_BS; d <<= 1) {   // Hillis-Steele inclusive
        int v = (threadIdx.x >= d) ? lds[threadIdx.x - d] : 0;
        __syncthreads();
        lds[threadIdx.x] += v;
        __syncthreads();
    }
    int toff = (threadIdx.x == 0) ? 0 : lds[threadIdx.x - 1];
    #pragma unroll
    for (int k = 0; k < SCAN_ELEMS; ++k) {
        int idx = tb + k;
        if (idx < N) rp[idx] = toff + vals[k];
    }
    if (threadIdx.x == SCAN_BS - 1) ptot[blockIdx.x] = lds[SCAN_BS - 1];
}

__global__ __launch_bounds__(1024) void k_scan2(int* __restrict__ ptot,
                                                int* __restrict__ poff,
                                                int* __restrict__ rpN, int nb) {
    __shared__ int lds[1024];
    int tid = threadIdx.x;
    lds[tid] = (tid < nb) ? ptot[tid] : 0;
    __syncthreads();
    for (int d = 1; d < 1024; d <<= 1) {
        int v = (tid >= d) ? lds[tid - d] : 0;
        __syncthreads();
        lds[tid] += v;
        __syncthreads();
    }
    if (tid < nb) poff[tid] = (tid == 0) ? 0 : lds[tid - 1];
    if (tid == nb - 1) *rpN = lds[tid];     // total edges -> rp[N]
}

__global__ __launch_bounds__(SCAN_BS) void k_scan3(int* __restrict__ rp,
                                                   const int* __restrict__ poff, int N) {
    int off = poff[blockIdx.x];
    const int tb = blockIdx.x * SCAN_CHUNK + threadIdx.x * SCAN_ELEMS;
    #pragma unroll
    for (int k = 0; k < SCAN_ELEMS; ++k) {
        int idx = tb + k;
        if (idx < N) rp[idx] += off;
    }
}

// scatter edges into CSR slots: ONLY col (weights folded into row scaling)
__global__ __launch_bounds__(256) void k_fill(const int* __restrict__ src,
                                              const int* __restrict__ dst,
                                              const int* __restrict__ rp,
                                              int* __restrict__ tmp,
                                              int* __restrict__ col, int E, int N) {
    int e = blockIdx.x * 256 + threadIdx.x;
    if (e >= E) return;
    int s = src[e], d = dst[e];
    if ((unsigned)s >= (unsigned)N || (unsigned)d >= (unsigned)N) return;
    int r = atomicAdd(&tmp[d], 1);
    col[rp[d] + r] = s;
}

// user-count histogram for scatter-mean denominator
__global__ __launch_bounds__(256) void k_ucnt(const int* __restrict__ uidx,
                                              float* __restrict__ cntf, int N) {
    int i = blockIdx.x * 256 + threadIdx.x;
    if (i < N) {
        int u = uidx[i];
        if ((unsigned)u < (unsigned)N) atomicAdd(&cntf[u], 1.0f);
    }
}

// ==================== GEMMs (LDS-staged, scalar FMA) ====================
// Optional epilogue row-scale by scale[row] (nullptr = no scale).

__global__ __launch_bounds__(256) void k_gemm1(const float* __restrict__ x,
                                               const float* __restrict__ W,
                                               const float* __restrict__ scale,
                                               float* __restrict__ out, int N) {
    __shared__ float ws[INDIM * FEAT];   // 32 KB
    __shared__ float xs[16 * INDIM];     // 8 KB
    const int tid = threadIdx.x;
    for (int i = tid; i < INDIM * FEAT; i += 256) ws[i] = W[i];
    const int row0 = blockIdx.x * 16;
    for (int i = tid; i < 16 * INDIM; i += 256) {
        int r = i >> 7, k = i & (INDIM - 1);
        int gr = row0 + r;
        xs[i] = (gr < N) ? x[(long)gr * INDIM + k] : 0.0f;
    }
    __syncthreads();
    const int rb = tid >> 6;
    const int c  = tid & 63;
    float a0 = 0.f, a1 = 0.f, a2 = 0.f, a3 = 0.f;
    #pragma unroll 4
    for (int k = 0; k < INDIM; ++k) {
        float w = ws[k * FEAT + c];
        a0 += xs[(rb     ) * INDIM + k] * w;
        a1 += xs[(rb +  4) * INDIM + k] * w;
        a2 += xs[(rb +  8) * INDIM + k] * w;
        a3 += xs[(rb + 12) * INDIM + k] * w;
    }
    float acc[4] = {a0, a1, a2, a3};
    for (int j = 0; j < 4; ++j) {
        int gr = row0 + rb + j * 4;
        if (gr < N) {
            float sc = scale ? scale[gr] : 1.0f;
            out[(long)gr * FEAT + c] = acc[j] * sc;
        }
    }
}

__global__ __launch_bounds__(256) void k_gemm2(const float* __restrict__ h,
                                               const float* __restrict__ W,
                                               const float* __restrict__ scale,
                                               float* __restrict__ out, int N) {
    __shared__ float ws[FEAT * FEAT];    // 16 KB
    __shared__ float xs[16 * FEAT];      // 4 KB
    const int tid = threadIdx.x;
    for (int i = tid; i < FEAT * FEAT; i += 256) ws[i] = W[i];
    const int row0 = blockIdx.x * 16;
    for (int i = tid; i < 16 * FEAT; i += 256) {
        int r = i >> 6, k = i & 63;
        int gr = row0 + r;
        xs[i] = (gr < N) ? h[(long)gr * FEAT + k] : 0.0f;
    }
    __syncthreads();
    const int rb = tid >> 6;
    const int c  = tid & 63;
    float a0 = 0.f, a1 = 0.f, a2 = 0.f, a3 = 0.f;
    #pragma unroll 4
    for (int k = 0; k < FEAT; ++k) {
        float w = ws[k * FEAT + c];
        a0 += xs[(rb     ) * FEAT + k] * w;
        a1 += xs[(rb +  4) * FEAT + k] * w;
        a2 += xs[(rb +  8) * FEAT + k] * w;
        a3 += xs[(rb + 12) * FEAT + k] * w;
    }
    float acc[4] = {a0, a1, a2, a3};
    for (int j = 0; j < 4; ++j) {
        int gr = row0 + rb + j * 4;
        if (gr < N) {
            float sc = scale ? scale[gr] : 1.0f;
            out[(long)gr * FEAT + c] = acc[j] * sc;
        }
    }
}

// ==================== pull aggregation (atomic-free, col-only CSR) ====================
// A rows are pre-scaled by dis[src]. agg[i] = dis[i]*(sum_j A[col_j] + A[i]) + bias

__global__ __launch_bounds__(256) void k_agg1(const float* __restrict__ A,
                                              const int* __restrict__ rp,
                                              const int* __restrict__ col,
                                              const float* __restrict__ dis,
                                              const float* __restrict__ bias,
                                              float* __restrict__ H, int N) {
    int i = blockIdx.x * 4 + (threadIdx.x >> 6);
    if (i >= N) return;
    int f = threadIdx.x & 63;
    int jb = rp[i], je = rp[i + 1];
    float acc = 0.f;
    int j = jb;
    for (; j + 3 < je; j += 4) {
        int c0 = col[j], c1 = col[j+1], c2 = col[j+2], c3 = col[j+3];
        acc += A[(long)c0 * FEAT + f];
        acc += A[(long)c1 * FEAT + f];
        acc += A[(long)c2 * FEAT + f];
        acc += A[(long)c3 * FEAT + f];
    }
    for (; j < je; ++j) acc += A[(long)col[j] * FEAT + f];
    float v = dis[i] * (acc + A[(long)i * FEAT + f]) + bias[f];
    H[(long)i * FEAT + f] = fmaxf(v, 0.f);              // relu
}

// layer-2 pull + fused scatter-mean accumulate into S (=d_out, zeroed)
__global__ __launch_bounds__(256) void k_agg2s(const float* __restrict__ A,
                                               const int* __restrict__ rp,
                                               const int* __restrict__ col,
                                               const float* __restrict__ dis,
                                               const float* __restrict__ bias,
                                               const int* __restrict__ uidx,
                                               float* __restrict__ S, int N) {
    int i = blockIdx.x * 4 + (threadIdx.x >> 6);
    if (i >= N) return;
    int f = threadIdx.x & 63;
    int jb = rp[i], je = rp[i + 1];
    float acc = 0.f;
    int j = jb;
    for (; j + 3 < je; j += 4) {
        int c0 = col[j], c1 = col[j+1], c2 = col[j+2], c3 = col[j+3];
        acc += A[(long)c0 * FEAT + f];
        acc += A[(long)c1 * FEAT + f];
        acc += A[(long)c2 * FEAT + f];
        acc += A[(long)c3 * FEAT + f];
    }
    for (; j < je; ++j) acc += A[(long)col[j] * FEAT + f];
    float v = dis[i] * (acc + A[(long)i * FEAT + f]) + bias[f];
    int u = uidx[i];
    if ((unsigned)u < (unsigned)N) atomicAdd(&S[(long)u * FEAT + f], v);
}

// final: out = cnt>0 ? out/cnt : 0 (in place)
__global__ __launch_bounds__(256) void k_final(float* __restrict__ S,
                                               const float* __restrict__ cnt, int N) {
    long idx = (long)blockIdx.x * 256 + threadIdx.x;
    if (idx >= (long)N * FEAT) return;
    int i = (int)(idx >> 6);
    float c = cnt[i];
    S[idx] = (c > 0.f) ? S[idx] / c : 0.f;
}

// ==================== fallback (push-atomic path, unscaled GEMM) ====================

__global__ __launch_bounds__(256) void k_degf(const int* __restrict__ dst,
                                              float* __restrict__ deg, int E, int N) {
    int e = blockIdx.x * 256 + threadIdx.x;
    if (e < E) {
        int d = dst[e];
        if ((unsigned)d < (unsigned)N) atomicAdd(&deg[d], 1.0f);
    }
}
__global__ __launch_bounds__(256) void k_disf(float* __restrict__ deg, int N) {
    int i = blockIdx.x * 256 + threadIdx.x;
    if (i < N) deg[i] = rsqrtf(deg[i] + 1.0f);
}
__global__ __launch_bounds__(256) void k_aggp(const float* __restrict__ h,
                                              const int* __restrict__ src,
                                              const int* __restrict__ dst,
                                              const float* __restrict__ dis,
                                              float* __restrict__ agg, int E, int N) {
    int e = blockIdx.x * 4 + (threadIdx.x >> 6);
    if (e >= E) return;
    int f = threadIdx.x & 63;
    int s = src[e], d = dst[e];
    if ((unsigned)s >= (unsigned)N || (unsigned)d >= (unsigned)N) return;
    float nrm = dis[s] * dis[d];
    atomicAdd(&agg[(long)d * FEAT + f], h[(long)s * FEAT + f] * nrm);
}
__global__ __launch_bounds__(256) void k_epi1(float* __restrict__ B, const float* __restrict__ A,
                                              const float* __restrict__ dis,
                                              const float* __restrict__ b1, int N) {
    long idx = (long)blockIdx.x * 256 + threadIdx.x;
    if (idx >= (long)N * FEAT) return;
    int i = (int)(idx >> 6), f = (int)(idx & 63);
    float di = dis[i];
    float v = B[idx] + A[idx] * di * di + b1[f];
    B[idx] = v > 0.f ? v : 0.f;
}
__global__ __launch_bounds__(256) void k_epi2(float* __restrict__ A, const float* __restrict__ B,
                                              const float* __restrict__ dis,
                                              const float* __restrict__ b2, int N) {
    long idx = (long)blockIdx.x * 256 + threadIdx.x;
    if (idx >= (long)N * FEAT) return;
    int i = (int)(idx >> 6), f = (int)(idx & 63);
    float di = dis[i];
    A[idx] = B[idx] + A[idx] * di * di + b2[f];
}
__global__ __launch_bounds__(256) void k_scat(const float* __restrict__ A,
                                              const int* __restrict__ uidx,
                                              float* __restrict__ S, float* __restrict__ cnt, int N) {
    int i = blockIdx.x * 4 + (threadIdx.x >> 6);
    if (i >= N) return;
    int f = threadIdx.x & 63;
    int u = uidx[i];
    if ((unsigned)u >= (unsigned)N) return;
    atomicAdd(&S[(long)u * FEAT + f], A[(long)i * FEAT + f]);
    if (f == 0) atomicAdd(&cnt[u], 1.0f);
}

extern "C" void kernel_launch(void* const* d_in, const int* in_sizes, int n_in,
                              void* d_out, int out_size, void* d_ws, size_t ws_size,
                              hipStream_t stream) {
    const float* x   = (const float*)d_in[0];
    const int* edge  = (const int*)d_in[1];
    const int* uidx  = (const int*)d_in[2];
    const float* W1  = (const float*)d_in[3];
    const float* b1  = (const float*)d_in[4];
    const float* W2  = (const float*)d_in[5];
    const float* b2  = (const float*)d_in[6];
    float* out       = (float*)d_out;

    const int N = in_sizes[2];       // 100000
    const int E = in_sizes[1] / 2;   // 1600000
    const int* src = edge;
    const int* dst = edge + E;

    const size_t fbuf = (size_t)N * FEAT * sizeof(float);   // 25.6 MB
    const long NF = (long)N * FEAT;
    const int gNF = (int)((NF + 255) / 256);
    const int gE  = (E + 255) / 256;
    const int gN  = (N + 255) / 256;
    const int gN4 = (N + 3) / 4;
    const int nbScan = (N + SCAN_CHUNK - 1) / SCAN_CHUNK;   // 49 for N=100000

    auto align256 = [](size_t v) { return (v + 255) & ~(size_t)255; };

    // CSR-path layout: dis, cntf, rowptr, cntE, ptot, poff, col, A
    char* w = (char*)d_ws;
    size_t o = 0;
    float* dis  = (float*)(w + o); o = align256(o + (size_t)N * 4);
    float* cntf = (float*)(w + o); o = align256(o + (size_t)N * 4);
    int*   rp   = (int*)  (w + o); o = align256(o + (size_t)(N + 1) * 4);
    int*   cntE = (int*)  (w + o); o = align256(o + (size_t)N * 4);
    int*   ptot = (int*)  (w + o); o = align256(o + (size_t)1024 * 4);
    int*   poff = (int*)  (w + o); o = align256(o + (size_t)1024 * 4);
    int*   col  = (int*)  (w + o); o = align256(o + (size_t)E * 4);
    float* A    = (float*)(w + o); o = align256(o + fbuf);
    const size_t need_csr = o;   // ~33.7 MB

    if (ws_size >= need_csr && nbScan <= 1024) {
        // --- CSR build ---
        hipMemsetAsync(cntE, 0, (size_t)N * 4, stream);
        k_hist <<<gE, 256, 0, stream>>>(dst, cntE, E, N);
        k_dis  <<<gN, 256, 0, stream>>>(cntE, dis, N);
        k_scan1<<<nbScan, SCAN_BS, 0, stream>>>(cntE, rp, ptot, N);
        k_scan2<<<1, 1024, 0, stream>>>(ptot, poff, rp + N, nbScan);
        k_scan3<<<nbScan, SCAN_BS, 0, stream>>>(rp, poff, N);
        hipMemsetAsync(cntE, 0, (size_t)N * 4, stream);
        k_fill <<<gE, 256, 0, stream>>>(src, dst, rp, cntE, col, E, N);
        hipMemsetAsync(cntf, 0, (size_t)N * 4, stream);
        k_ucnt <<<gN, 256, 0, stream>>>(uidx, cntf, N);

        // --- layer 1: A = (x@W1)*dis[row]; H(=out) = relu(dis*(agg+self) + b1) ---
        k_gemm1<<<(N + 15) / 16, 256, 0, stream>>>(x, W1, dis, A, N);
        k_agg1 <<<gN4, 256, 0, stream>>>(A, rp, col, dis, b1, out, N);

        // --- layer 2: A = (H@W2)*dis[row]; scatter(dis*(agg+self) + b2) into out ---
        k_gemm2<<<(N + 15) / 16, 256, 0, stream>>>(out, W2, dis, A, N);
        hipMemsetAsync(out, 0, fbuf, stream);
        k_agg2s<<<gN4, 256, 0, stream>>>(A, rp, col, dis, b2, uidx, out, N);
        k_final<<<gNF, 256, 0, stream>>>(out, cntf, N);
    } else {
        // --- fallback: push-atomic path (proven) ---
        char* w2p = (char*)d_ws;
        float* disF = (float*)w2p;
        float* cntF = (float*)(w2p + (size_t)N * 4);
        float* Af   = (float*)(w2p + align256((size_t)2 * N * 4));
        float* B = out;

        hipMemsetAsync(disF, 0, (size_t)N * 4, stream);
        k_degf<<<gE, 256, 0, stream>>>(dst, disF, E, N);
        k_disf<<<gN, 256, 0, stream>>>(disF, N);

        k_gemm1<<<(N + 15) / 16, 256, 0, stream>>>(x, W1, nullptr, Af, N);
        hipMemsetAsync(B, 0, fbuf, stream);
        k_aggp<<<(E + 3) / 4, 256, 0, stream>>>(Af, src, dst, disF, B, E, N);
        k_epi1<<<gNF, 256, 0, stream>>>(B, Af, disF, b1, N);

        k_gemm2<<<(N + 15) / 16, 256, 0, stream>>>(B, W2, nullptr, Af, N);
        hipMemsetAsync(B, 0, fbuf, stream);
        k_aggp<<<(E + 3) / 4, 256, 0, stream>>>(Af, src, dst, disF, B, E, N);
        k_epi2<<<gNF, 256, 0, stream>>>(Af, B, disF, b2, N);

        hipMemsetAsync(B, 0, fbuf, stream);
        hipMemsetAsync(cntF, 0, (size_t)N * 4, stream);
        k_scat<<<gN4, 256, 0, stream>>>(Af, uidx, B, cntF, N);
        k_final<<<gNF, 256, 0, stream>>>(B, cntF, N);
    }
}

// Round 7
// 484.560 us; speedup vs baseline: 2.1952x; 1.1237x over previous
//
#include <hip/hip_runtime.h>
#include <hip/hip_bf16.h>

// GCN: h1 = relu(GCNConv(x, W1, b1)); out = scatter_mean(GCNConv(h1, W2, b2), user_idx)
// N=100000, E=1600000, dims 128 -> 64 -> 64. fp32 I/O, int32 indices.
//
// R6 profile: k_fill 103us, WRITE_SIZE=107MB ~= E*64B -- every random 4B col
// store writes back a full line (random dst => lines never fill densely).
// R7: two-phase binned scatter. Phase A tile-reorders edges in LDS and flushes
// per-bucket runs as coalesced bursts into a bucket-ordered pairs buffer
// (bucket = dst>>9; region offsets = rp sampled at bucket boundaries; pairs
// aliases A which is dead until gemm1). Phase B: one WG per bucket, LDS rank
// cursors, col writes dense within a 25KB region on one CU/XCD.

#define FEAT 64
#define INDIM 128

#define SCAN_BS 256
#define SCAN_ELEMS 8
#define SCAN_CHUNK (SCAN_BS * SCAN_ELEMS)   // 2048 elems/block

#define BIN_SHIFT 9
#define BIN_R 512                 // nodes per bucket
#define BIN_TILE 4096             // edges per k_binA block (16/thread)

// ==================== CSR build ====================

__global__ __launch_bounds__(256) void k_hist(const int* __restrict__ dst,
                                              int* __restrict__ cntE, int E, int N) {
    int e = blockIdx.x * 256 + threadIdx.x;
    if (e < E) {
        int d = dst[e];
        if ((unsigned)d < (unsigned)N) atomicAdd(&cntE[d], 1);
    }
}

// dis[i] = rsqrt(deg_in[i] + 1)   (+1 = self loop)
__global__ __launch_bounds__(256) void k_dis(const int* __restrict__ cntE,
                                             float* __restrict__ dis, int N) {
    int i = blockIdx.x * 256 + threadIdx.x;
    if (i < N) dis[i] = rsqrtf((float)cntE[i] + 1.0f);
}

// --- 3-phase exclusive scan of cntE[0..N) -> rp[0..N] ---
__global__ __launch_bounds__(SCAN_BS) void k_scan1(const int* __restrict__ c,
                                                   int* __restrict__ rp,
                                                   int* __restrict__ ptot, int N) {
    __shared__ int lds[SCAN_BS];
    const int base = blockIdx.x * SCAN_CHUNK;
    const int tb = base + threadIdx.x * SCAN_ELEMS;
    int vals[SCAN_ELEMS];
    int s = 0;
    #pragma unroll
    for (int k = 0; k < SCAN_ELEMS; ++k) {
        int idx = tb + k;
        int v = (idx < N) ? c[idx] : 0;
        vals[k] = s;
        s += v;
    }
    lds[threadIdx.x] = s;
    __syncthreads();
    for (int d = 1; d < SCAN_BS; d <<= 1) {
        int v = (threadIdx.x >= d) ? lds[threadIdx.x - d] : 0;
        __syncthreads();
        lds[threadIdx.x] += v;
        __syncthreads();
    }
    int toff = (threadIdx.x == 0) ? 0 : lds[threadIdx.x - 1];
    #pragma unroll
    for (int k = 0; k < SCAN_ELEMS; ++k) {
        int idx = tb + k;
        if (idx < N) rp[idx] = toff + vals[k];
    }
    if (threadIdx.x == SCAN_BS - 1) ptot[blockIdx.x] = lds[SCAN_BS - 1];
}

__global__ __launch_bounds__(1024) void k_scan2(int* __restrict__ ptot,
                                                int* __restrict__ poff,
                                                int* __restrict__ rpN, int nb) {
    __shared__ int lds[1024];
    int tid = threadIdx.x;
    lds[tid] = (tid < nb) ? ptot[tid] : 0;
    __syncthreads();
    for (int d = 1; d < 1024; d <<= 1) {
        int v = (tid >= d) ? lds[tid - d] : 0;
        __syncthreads();
        lds[tid] += v;
        __syncthreads();
    }
    if (tid < nb) poff[tid] = (tid == 0) ? 0 : lds[tid - 1];
    if (tid == nb - 1) *rpN = lds[tid];
}

__global__ __launch_bounds__(SCAN_BS) void k_scan3(int* __restrict__ rp,
                                                   const int* __restrict__ poff, int N) {
    int off = poff[blockIdx.x];
    const int tb = blockIdx.x * SCAN_CHUNK + threadIdx.x * SCAN_ELEMS;
    #pragma unroll
    for (int k = 0; k < SCAN_ELEMS; ++k) {
        int idx = tb + k;
        if (idx < N) rp[idx] += off;
    }
}

// bucket cursors init: bcur[b] = rp[min(b*BIN_R, N)]
__global__ __launch_bounds__(256) void k_bcur(const int* __restrict__ rp,
                                              int* __restrict__ bcur, int KB, int N) {
    int b = blockIdx.x * 256 + threadIdx.x;
    if (b < KB) {
        int n = b << BIN_SHIFT;
        if (n > N) n = N;
        bcur[b] = rp[n];
    }
}

// Phase A: tile-reorder edges by bucket, flush coalesced runs into pairs[]
__global__ __launch_bounds__(256) void k_binA(const int* __restrict__ src,
                                              const int* __restrict__ dst,
                                              int* __restrict__ bcur,
                                              int2* __restrict__ pairs,
                                              int E, int N, int KB) {
    __shared__ int2 lbuf[BIN_TILE];              // 32 KB
    __shared__ unsigned short bkt[BIN_TILE];     // 8 KB
    __shared__ int lcnt[256];
    __shared__ int loff[256];
    __shared__ int lbase[256];
    __shared__ int tot;
    const int tid = threadIdx.x;
    const int base = blockIdx.x * BIN_TILE;

    lcnt[tid] = 0;
    __syncthreads();

    int mys[16], myd[16], myb[16];
    #pragma unroll
    for (int t = 0; t < 16; ++t) {
        int e = base + t * 256 + tid;            // coalesced
        int s = 0, d = -1;
        if (e < E) { s = src[e]; d = dst[e]; }
        if ((unsigned)d >= (unsigned)N) d = -1;  // same validity rule as k_hist
        if ((unsigned)s >= (unsigned)N) s = 0;   // clamp (keeps counts consistent)
        mys[t] = s; myd[t] = d;
        myb[t] = (d >= 0) ? (d >> BIN_SHIFT) : -1;
        if (myb[t] >= 0) atomicAdd(&lcnt[myb[t]], 1);
    }
    __syncthreads();

    // inclusive scan of lcnt into loff
    int v = lcnt[tid];
    loff[tid] = v;
    __syncthreads();
    for (int d = 1; d < 256; d <<= 1) {
        int t2 = (tid >= d) ? loff[tid - d] : 0;
        __syncthreads();
        loff[tid] += t2;
        __syncthreads();
    }
    if (tid == 255) tot = loff[255];
    int excl = loff[tid] - v;
    __syncthreads();                 // everyone done reading inclusive values
    loff[tid] = excl;
    lcnt[tid] = excl;                // running cursor
    if (tid < KB && v > 0) lbase[tid] = atomicAdd(&bcur[tid], v);
    __syncthreads();

    // scatter into LDS by bucket
    #pragma unroll
    for (int t = 0; t < 16; ++t) {
        if (myb[t] >= 0) {
            int pos = atomicAdd(&lcnt[myb[t]], 1);
            lbuf[pos] = make_int2(mys[t], myd[t]);
            bkt[pos] = (unsigned short)myb[t];
        }
    }
    __syncthreads();

    // flush: consecutive i within a bucket run -> consecutive global addrs
    const int T = tot;
    for (int i = tid; i < T; i += 256) {
        int b = bkt[i];
        pairs[lbase[b] + (i - loff[b])] = lbuf[i];
    }
}

// Phase B: one WG per bucket; LDS cursors from rp slice; dense col writes
__global__ __launch_bounds__(256) void k_binB(const int2* __restrict__ pairs,
                                              const int* __restrict__ rp,
                                              int* __restrict__ col, int N) {
    __shared__ int cur[BIN_R + 1];
    const int b = blockIdx.x;
    const int n0 = b << BIN_SHIFT;
    const int n1 = min(n0 + BIN_R, N);
    const int nn = n1 - n0;
    for (int i = threadIdx.x; i <= nn; i += 256) cur[i] = rp[n0 + i];
    __syncthreads();
    const int e0 = cur[0];
    const int e1 = cur[nn];
    __syncthreads();
    for (int i = e0 + threadIdx.x; i < e1; i += 256) {
        int2 p = pairs[i];                         // coalesced read
        int pos = atomicAdd(&cur[p.y - n0], 1);    // LDS atomic
        col[pos] = p.x;                            // dense within 25KB region
    }
}

// fallback fill (random scatter) for when KB > 256
__global__ __launch_bounds__(256) void k_fill(const int* __restrict__ src,
                                              const int* __restrict__ dst,
                                              const int* __restrict__ rp,
                                              int* __restrict__ tmp,
                                              int* __restrict__ col, int E, int N) {
    int e = blockIdx.x * 256 + threadIdx.x;
    if (e >= E) return;
    int s = src[e], d = dst[e];
    if ((unsigned)s >= (unsigned)N) s = 0;
    if ((unsigned)d >= (unsigned)N) return;
    int r = atomicAdd(&tmp[d], 1);
    col[rp[d] + r] = s;
}

// user-count histogram for scatter-mean denominator
__global__ __launch_bounds__(256) void k_ucnt(const int* __restrict__ uidx,
                                              float* __restrict__ cntf, int N) {
    int i = blockIdx.x * 256 + threadIdx.x;
    if (i < N) {
        int u = uidx[i];
        if ((unsigned)u < (unsigned)N) atomicAdd(&cntf[u], 1.0f);
    }
}

// ==================== GEMMs (LDS-staged, scalar FMA) ====================

__global__ __launch_bounds__(256) void k_gemm1(const float* __restrict__ x,
                                               const float* __restrict__ W,
                                               const float* __restrict__ scale,
                                               float* __restrict__ out, int N) {
    __shared__ float ws[INDIM * FEAT];   // 32 KB
    __shared__ float xs[16 * INDIM];     // 8 KB
    const int tid = threadIdx.x;
    for (int i = tid; i < INDIM * FEAT; i += 256) ws[i] = W[i];
    const int row0 = blockIdx.x * 16;
    for (int i = tid; i < 16 * INDIM; i += 256) {
        int r = i >> 7, k = i & (INDIM - 1);
        int gr = row0 + r;
        xs[i] = (gr < N) ? x[(long)gr * INDIM + k] : 0.0f;
    }
    __syncthreads();
    const int rb = tid >> 6;
    const int c  = tid & 63;
    float a0 = 0.f, a1 = 0.f, a2 = 0.f, a3 = 0.f;
    #pragma unroll 4
    for (int k = 0; k < INDIM; ++k) {
        float w = ws[k * FEAT + c];
        a0 += xs[(rb     ) * INDIM + k] * w;
        a1 += xs[(rb +  4) * INDIM + k] * w;
        a2 += xs[(rb +  8) * INDIM + k] * w;
        a3 += xs[(rb + 12) * INDIM + k] * w;
    }
    float acc[4] = {a0, a1, a2, a3};
    for (int j = 0; j < 4; ++j) {
        int gr = row0 + rb + j * 4;
        if (gr < N) {
            float sc = scale ? scale[gr] : 1.0f;
            out[(long)gr * FEAT + c] = acc[j] * sc;
        }
    }
}

__global__ __launch_bounds__(256) void k_gemm2(const float* __restrict__ h,
                                               const float* __restrict__ W,
                                               const float* __restrict__ scale,
                                               float* __restrict__ out, int N) {
    __shared__ float ws[FEAT * FEAT];    // 16 KB
    __shared__ float xs[16 * FEAT];      // 4 KB
    const int tid = threadIdx.x;
    for (int i = tid; i < FEAT * FEAT; i += 256) ws[i] = W[i];
    const int row0 = blockIdx.x * 16;
    for (int i = tid; i < 16 * FEAT; i += 256) {
        int r = i >> 6, k = i & 63;
        int gr = row0 + r;
        xs[i] = (gr < N) ? h[(long)gr * FEAT + k] : 0.0f;
    }
    __syncthreads();
    const int rb = tid >> 6;
    const int c  = tid & 63;
    float a0 = 0.f, a1 = 0.f, a2 = 0.f, a3 = 0.f;
    #pragma unroll 4
    for (int k = 0; k < FEAT; ++k) {
        float w = ws[k * FEAT + c];
        a0 += xs[(rb     ) * FEAT + k] * w;
        a1 += xs[(rb +  4) * FEAT + k] * w;
        a2 += xs[(rb +  8) * FEAT + k] * w;
        a3 += xs[(rb + 12) * FEAT + k] * w;
    }
    float acc[4] = {a0, a1, a2, a3};
    for (int j = 0; j < 4; ++j) {
        int gr = row0 + rb + j * 4;
        if (gr < N) {
            float sc = scale ? scale[gr] : 1.0f;
            out[(long)gr * FEAT + c] = acc[j] * sc;
        }
    }
}

// ==================== pull aggregation (atomic-free, col-only CSR) ====================
// A rows pre-scaled by dis[src]. agg[i] = dis[i]*(sum_j A[col_j] + A[i]) + bias

__global__ __launch_bounds__(256) void k_agg1(const float* __restrict__ A,
                                              const int* __restrict__ rp,
                                              const int* __restrict__ col,
                                              const float* __restrict__ dis,
                                              const float* __restrict__ bias,
                                              float* __restrict__ H, int N) {
    int i = blockIdx.x * 4 + (threadIdx.x >> 6);
    if (i >= N) return;
    int f = threadIdx.x & 63;
    int jb = rp[i], je = rp[i + 1];
    float acc = 0.f;
    int j = jb;
    for (; j + 3 < je; j += 4) {
        int c0 = col[j], c1 = col[j+1], c2 = col[j+2], c3 = col[j+3];
        acc += A[(long)c0 * FEAT + f];
        acc += A[(long)c1 * FEAT + f];
        acc += A[(long)c2 * FEAT + f];
        acc += A[(long)c3 * FEAT + f];
    }
    for (; j < je; ++j) acc += A[(long)col[j] * FEAT + f];
    float v = dis[i] * (acc + A[(long)i * FEAT + f]) + bias[f];
    H[(long)i * FEAT + f] = fmaxf(v, 0.f);              // relu
}

__global__ __launch_bounds__(256) void k_agg2s(const float* __restrict__ A,
                                               const int* __restrict__ rp,
                                               const int* __restrict__ col,
                                               const float* __restrict__ dis,
                                               const float* __restrict__ bias,
                                               const int* __restrict__ uidx,
                                               float* __restrict__ S, int N) {
    int i = blockIdx.x * 4 + (threadIdx.x >> 6);
    if (i >= N) return;
    int f = threadIdx.x & 63;
    int jb = rp[i], je = rp[i + 1];
    float acc = 0.f;
    int j = jb;
    for (; j + 3 < je; j += 4) {
        int c0 = col[j], c1 = col[j+1], c2 = col[j+2], c3 = col[j+3];
        acc += A[(long)c0 * FEAT + f];
        acc += A[(long)c1 * FEAT + f];
        acc += A[(long)c2 * FEAT + f];
        acc += A[(long)c3 * FEAT + f];
    }
    for (; j < je; ++j) acc += A[(long)col[j] * FEAT + f];
    float v = dis[i] * (acc + A[(long)i * FEAT + f]) + bias[f];
    int u = uidx[i];
    if ((unsigned)u < (unsigned)N) atomicAdd(&S[(long)u * FEAT + f], v);
}

// final: out = cnt>0 ? out/cnt : 0 (in place)
__global__ __launch_bounds__(256) void k_final(float* __restrict__ S,
                                               const float* __restrict__ cnt, int N) {
    long idx = (long)blockIdx.x * 256 + threadIdx.x;
    if (idx >= (long)N * FEAT) return;
    int i = (int)(idx >> 6);
    float c = cnt[i];
    S[idx] = (c > 0.f) ? S[idx] / c : 0.f;
}

extern "C" void kernel_launch(void* const* d_in, const int* in_sizes, int n_in,
                              void* d_out, int out_size, void* d_ws, size_t ws_size,
                              hipStream_t stream) {
    const float* x   = (const float*)d_in[0];
    const int* edge  = (const int*)d_in[1];
    const int* uidx  = (const int*)d_in[2];
    const float* W1  = (const float*)d_in[3];
    const float* b1  = (const float*)d_in[4];
    const float* W2  = (const float*)d_in[5];
    const float* b2  = (const float*)d_in[6];
    float* out       = (float*)d_out;

    const int N = in_sizes[2];       // 100000
    const int E = in_sizes[1] / 2;   // 1600000
    const int* src = edge;
    const int* dst = edge + E;

    const size_t fbuf = (size_t)N * FEAT * sizeof(float);   // 25.6 MB
    const long NF = (long)N * FEAT;
    const int gNF = (int)((NF + 255) / 256);
    const int gE  = (E + 255) / 256;
    const int gN  = (N + 255) / 256;
    const int gN4 = (N + 3) / 4;
    const int nbScan = (N + SCAN_CHUNK - 1) / SCAN_CHUNK;   // 49
    const int KB = (N + BIN_R - 1) >> BIN_SHIFT;            // 196

    auto align256 = [](size_t v) { return (v + 255) & ~(size_t)255; };

    // layout: dis, cntf, rowptr, cntE, ptot, poff(=bcur), col, A(=pairs)
    char* w = (char*)d_ws;
    size_t o = 0;
    float* dis  = (float*)(w + o); o = align256(o + (size_t)N * 4);
    float* cntf = (float*)(w + o); o = align256(o + (size_t)N * 4);
    int*   rp   = (int*)  (w + o); o = align256(o + (size_t)(N + 1) * 4);
    int*   cntE = (int*)  (w + o); o = align256(o + (size_t)N * 4);
    int*   ptot = (int*)  (w + o); o = align256(o + (size_t)1024 * 4);
    int*   poff = (int*)  (w + o); o = align256(o + (size_t)1024 * 4);
    int*   col  = (int*)  (w + o); o = align256(o + (size_t)E * 4);
    float* A    = (float*)(w + o); o = align256(o + fbuf);
    const size_t need_csr = o;   // ~33.7 MB
    int* bcur = ptot;            // free after scan2
    int2* pairs = (int2*)A;      // A dead until gemm1; E*8B <= fbuf

    if (ws_size >= need_csr && nbScan <= 1024 && (size_t)E * sizeof(int2) <= fbuf) {
        // --- CSR build ---
        hipMemsetAsync(cntE, 0, (size_t)N * 4, stream);
        k_hist <<<gE, 256, 0, stream>>>(dst, cntE, E, N);
        k_dis  <<<gN, 256, 0, stream>>>(cntE, dis, N);
        k_scan1<<<nbScan, SCAN_BS, 0, stream>>>(cntE, rp, ptot, N);
        k_scan2<<<1, 1024, 0, stream>>>(ptot, poff, rp + N, nbScan);
        k_scan3<<<nbScan, SCAN_BS, 0, stream>>>(rp, poff, N);
        if (KB <= 256) {
            k_bcur <<<1, 256, 0, stream>>>(rp, bcur, KB, N);
            k_binA <<<(E + BIN_TILE - 1) / BIN_TILE, 256, 0, stream>>>(src, dst, bcur, pairs, E, N, KB);
            k_binB <<<KB, 256, 0, stream>>>(pairs, rp, col, N);
        } else {
            hipMemsetAsync(cntE, 0, (size_t)N * 4, stream);
            k_fill <<<gE, 256, 0, stream>>>(src, dst, rp, cntE, col, E, N);
        }
        hipMemsetAsync(cntf, 0, (size_t)N * 4, stream);
        k_ucnt <<<gN, 256, 0, stream>>>(uidx, cntf, N);

        // --- layer 1: A = (x@W1)*dis[row]; H(=out) = relu(dis*(agg+self) + b1) ---
        k_gemm1<<<(N + 15) / 16, 256, 0, stream>>>(x, W1, dis, A, N);
        k_agg1 <<<gN4, 256, 0, stream>>>(A, rp, col, dis, b1, out, N);

        // --- layer 2: A = (H@W2)*dis[row]; scatter(dis*(agg+self) + b2) into out ---
        k_gemm2<<<(N + 15) / 16, 256, 0, stream>>>(out, W2, dis, A, N);
        hipMemsetAsync(out, 0, fbuf, stream);
        k_agg2s<<<gN4, 256, 0, stream>>>(A, rp, col, dis, b2, uidx, out, N);
        k_final<<<gNF, 256, 0, stream>>>(out, cntf, N);
    } else {
        // minimal-ws fallback: same CSR path but pairs/fill via k_fill in-place
        hipMemsetAsync(cntE, 0, (size_t)N * 4, stream);
        k_hist <<<gE, 256, 0, stream>>>(dst, cntE, E, N);
        k_dis  <<<gN, 256, 0, stream>>>(cntE, dis, N);
        k_scan1<<<nbScan, SCAN_BS, 0, stream>>>(cntE, rp, ptot, N);
        k_scan2<<<1, 1024, 0, stream>>>(ptot, poff, rp + N, nbScan);
        k_scan3<<<nbScan, SCAN_BS, 0, stream>>>(rp, poff, N);
        hipMemsetAsync(cntE, 0, (size_t)N * 4, stream);
        k_fill <<<gE, 256, 0, stream>>>(src, dst, rp, cntE, col, E, N);
        hipMemsetAsync(cntf, 0, (size_t)N * 4, stream);
        k_ucnt <<<gN, 256, 0, stream>>>(uidx, cntf, N);
        k_gemm1<<<(N + 15) / 16, 256, 0, stream>>>(x, W1, dis, A, N);
        k_agg1 <<<gN4, 256, 0, stream>>>(A, rp, col, dis, b1, out, N);
        k_gemm2<<<(N + 15) / 16, 256, 0, stream>>>(out, W2, dis, A, N);
        hipMemsetAsync(out, 0, fbuf, stream);
        k_agg2s<<<gN4, 256, 0, stream>>>(A, rp, col, dis, b2, uidx, out, N);
        k_final<<<gNF, 256, 0, stream>>>(out, cntf, N);
    }
}

// Round 8
// 466.230 us; speedup vs baseline: 2.2815x; 1.0393x over previous
//
#include <hip/hip_runtime.h>
#include <hip/hip_bf16.h>

// GCN: h1 = relu(GCNConv(x, W1, b1)); out = scatter_mean(GCNConv(h1, W2, b2), user_idx)
// N=100000, E=1600000, dims 128 -> 64 -> 64. fp32 I/O, int32 indices.
//
// R7 profile: k_agg1/k_agg2s gather-bound: FETCH=190MB (E*256B row gathers miss
// the 4MB/XCD L2; A=25.6MB), VALUBusy 27%, WRITE=exact payload.
// R8: A (message matrix) stored in bf16 -> 128B rows. Halves gather bytes and
// GEMM writes; all accumulation stays fp32. pairs(int2,12.8MB) still aliases
// A (bf16, 12.8MB) exactly.

#define FEAT 64
#define INDIM 128

#define SCAN_BS 256
#define SCAN_ELEMS 8
#define SCAN_CHUNK (SCAN_BS * SCAN_ELEMS)   // 2048 elems/block

#define BIN_SHIFT 9
#define BIN_R 512                 // nodes per bucket
#define BIN_TILE 4096             // edges per k_binA block (16/thread)

typedef __hip_bfloat16 bf16;

// ==================== CSR build ====================

__global__ __launch_bounds__(256) void k_hist(const int* __restrict__ dst,
                                              int* __restrict__ cntE, int E, int N) {
    int e = blockIdx.x * 256 + threadIdx.x;
    if (e < E) {
        int d = dst[e];
        if ((unsigned)d < (unsigned)N) atomicAdd(&cntE[d], 1);
    }
}

// dis[i] = rsqrt(deg_in[i] + 1)   (+1 = self loop)
__global__ __launch_bounds__(256) void k_dis(const int* __restrict__ cntE,
                                             float* __restrict__ dis, int N) {
    int i = blockIdx.x * 256 + threadIdx.x;
    if (i < N) dis[i] = rsqrtf((float)cntE[i] + 1.0f);
}

// --- 3-phase exclusive scan of cntE[0..N) -> rp[0..N] ---
__global__ __launch_bounds__(SCAN_BS) void k_scan1(const int* __restrict__ c,
                                                   int* __restrict__ rp,
                                                   int* __restrict__ ptot, int N) {
    __shared__ int lds[SCAN_BS];
    const int base = blockIdx.x * SCAN_CHUNK;
    const int tb = base + threadIdx.x * SCAN_ELEMS;
    int vals[SCAN_ELEMS];
    int s = 0;
    #pragma unroll
    for (int k = 0; k < SCAN_ELEMS; ++k) {
        int idx = tb + k;
        int v = (idx < N) ? c[idx] : 0;
        vals[k] = s;
        s += v;
    }
    lds[threadIdx.x] = s;
    __syncthreads();
    for (int d = 1; d < SCAN_BS; d <<= 1) {
        int v = (threadIdx.x >= d) ? lds[threadIdx.x - d] : 0;
        __syncthreads();
        lds[threadIdx.x] += v;
        __syncthreads();
    }
    int toff = (threadIdx.x == 0) ? 0 : lds[threadIdx.x - 1];
    #pragma unroll
    for (int k = 0; k < SCAN_ELEMS; ++k) {
        int idx = tb + k;
        if (idx < N) rp[idx] = toff + vals[k];
    }
    if (threadIdx.x == SCAN_BS - 1) ptot[blockIdx.x] = lds[SCAN_BS - 1];
}

__global__ __launch_bounds__(1024) void k_scan2(int* __restrict__ ptot,
                                                int* __restrict__ poff,
                                                int* __restrict__ rpN, int nb) {
    __shared__ int lds[1024];
    int tid = threadIdx.x;
    lds[tid] = (tid < nb) ? ptot[tid] : 0;
    __syncthreads();
    for (int d = 1; d < 1024; d <<= 1) {
        int v = (tid >= d) ? lds[tid - d] : 0;
        __syncthreads();
        lds[tid] += v;
        __syncthreads();
    }
    if (tid < nb) poff[tid] = (tid == 0) ? 0 : lds[tid - 1];
    if (tid == nb - 1) *rpN = lds[tid];
}

__global__ __launch_bounds__(SCAN_BS) void k_scan3(int* __restrict__ rp,
                                                   const int* __restrict__ poff, int N) {
    int off = poff[blockIdx.x];
    const int tb = blockIdx.x * SCAN_CHUNK + threadIdx.x * SCAN_ELEMS;
    #pragma unroll
    for (int k = 0; k < SCAN_ELEMS; ++k) {
        int idx = tb + k;
        if (idx < N) rp[idx] += off;
    }
}

// bucket cursors init: bcur[b] = rp[min(b*BIN_R, N)]
__global__ __launch_bounds__(256) void k_bcur(const int* __restrict__ rp,
                                              int* __restrict__ bcur, int KB, int N) {
    int b = blockIdx.x * 256 + threadIdx.x;
    if (b < KB) {
        int n = b << BIN_SHIFT;
        if (n > N) n = N;
        bcur[b] = rp[n];
    }
}

// Phase A: tile-reorder edges by bucket, flush coalesced runs into pairs[]
__global__ __launch_bounds__(256) void k_binA(const int* __restrict__ src,
                                              const int* __restrict__ dst,
                                              int* __restrict__ bcur,
                                              int2* __restrict__ pairs,
                                              int E, int N, int KB) {
    __shared__ int2 lbuf[BIN_TILE];              // 32 KB
    __shared__ unsigned short bkt[BIN_TILE];     // 8 KB
    __shared__ int lcnt[256];
    __shared__ int loff[256];
    __shared__ int lbase[256];
    __shared__ int tot;
    const int tid = threadIdx.x;
    const int base = blockIdx.x * BIN_TILE;

    lcnt[tid] = 0;
    __syncthreads();

    int mys[16], myd[16], myb[16];
    #pragma unroll
    for (int t = 0; t < 16; ++t) {
        int e = base + t * 256 + tid;            // coalesced
        int s = 0, d = -1;
        if (e < E) { s = src[e]; d = dst[e]; }
        if ((unsigned)d >= (unsigned)N) d = -1;
        if ((unsigned)s >= (unsigned)N) s = 0;
        mys[t] = s; myd[t] = d;
        myb[t] = (d >= 0) ? (d >> BIN_SHIFT) : -1;
        if (myb[t] >= 0) atomicAdd(&lcnt[myb[t]], 1);
    }
    __syncthreads();

    int v = lcnt[tid];
    loff[tid] = v;
    __syncthreads();
    for (int d = 1; d < 256; d <<= 1) {
        int t2 = (tid >= d) ? loff[tid - d] : 0;
        __syncthreads();
        loff[tid] += t2;
        __syncthreads();
    }
    if (tid == 255) tot = loff[255];
    int excl = loff[tid] - v;
    __syncthreads();
    loff[tid] = excl;
    lcnt[tid] = excl;
    if (tid < KB && v > 0) lbase[tid] = atomicAdd(&bcur[tid], v);
    __syncthreads();

    #pragma unroll
    for (int t = 0; t < 16; ++t) {
        if (myb[t] >= 0) {
            int pos = atomicAdd(&lcnt[myb[t]], 1);
            lbuf[pos] = make_int2(mys[t], myd[t]);
            bkt[pos] = (unsigned short)myb[t];
        }
    }
    __syncthreads();

    const int T = tot;
    for (int i = tid; i < T; i += 256) {
        int b = bkt[i];
        pairs[lbase[b] + (i - loff[b])] = lbuf[i];
    }
}

// Phase B: one WG per bucket; LDS cursors from rp slice; dense col writes
__global__ __launch_bounds__(256) void k_binB(const int2* __restrict__ pairs,
                                              const int* __restrict__ rp,
                                              int* __restrict__ col, int N) {
    __shared__ int cur[BIN_R + 1];
    const int b = blockIdx.x;
    const int n0 = b << BIN_SHIFT;
    const int n1 = min(n0 + BIN_R, N);
    const int nn = n1 - n0;
    for (int i = threadIdx.x; i <= nn; i += 256) cur[i] = rp[n0 + i];
    __syncthreads();
    const int e0 = cur[0];
    const int e1 = cur[nn];
    __syncthreads();
    for (int i = e0 + threadIdx.x; i < e1; i += 256) {
        int2 p = pairs[i];
        int pos = atomicAdd(&cur[p.y - n0], 1);
        col[pos] = p.x;
    }
}

// fallback fill (random scatter) for when binning is unusable
__global__ __launch_bounds__(256) void k_fill(const int* __restrict__ src,
                                              const int* __restrict__ dst,
                                              const int* __restrict__ rp,
                                              int* __restrict__ tmp,
                                              int* __restrict__ col, int E, int N) {
    int e = blockIdx.x * 256 + threadIdx.x;
    if (e >= E) return;
    int s = src[e], d = dst[e];
    if ((unsigned)s >= (unsigned)N) s = 0;
    if ((unsigned)d >= (unsigned)N) return;
    int r = atomicAdd(&tmp[d], 1);
    col[rp[d] + r] = s;
}

// user-count histogram for scatter-mean denominator
__global__ __launch_bounds__(256) void k_ucnt(const int* __restrict__ uidx,
                                              float* __restrict__ cntf, int N) {
    int i = blockIdx.x * 256 + threadIdx.x;
    if (i < N) {
        int u = uidx[i];
        if ((unsigned)u < (unsigned)N) atomicAdd(&cntf[u], 1.0f);
    }
}

// ==================== GEMMs (LDS-staged, scalar FMA; bf16 output) ====================

__global__ __launch_bounds__(256) void k_gemm1(const float* __restrict__ x,
                                               const float* __restrict__ W,
                                               const float* __restrict__ scale,
                                               bf16* __restrict__ out, int N) {
    __shared__ float ws[INDIM * FEAT];   // 32 KB
    __shared__ float xs[16 * INDIM];     // 8 KB
    const int tid = threadIdx.x;
    for (int i = tid; i < INDIM * FEAT; i += 256) ws[i] = W[i];
    const int row0 = blockIdx.x * 16;
    for (int i = tid; i < 16 * INDIM; i += 256) {
        int r = i >> 7, k = i & (INDIM - 1);
        int gr = row0 + r;
        xs[i] = (gr < N) ? x[(long)gr * INDIM + k] : 0.0f;
    }
    __syncthreads();
    const int rb = tid >> 6;
    const int c  = tid & 63;
    float a0 = 0.f, a1 = 0.f, a2 = 0.f, a3 = 0.f;
    #pragma unroll 4
    for (int k = 0; k < INDIM; ++k) {
        float w = ws[k * FEAT + c];
        a0 += xs[(rb     ) * INDIM + k] * w;
        a1 += xs[(rb +  4) * INDIM + k] * w;
        a2 += xs[(rb +  8) * INDIM + k] * w;
        a3 += xs[(rb + 12) * INDIM + k] * w;
    }
    float acc[4] = {a0, a1, a2, a3};
    for (int j = 0; j < 4; ++j) {
        int gr = row0 + rb + j * 4;
        if (gr < N) out[(long)gr * FEAT + c] = __float2bfloat16(acc[j] * scale[gr]);
    }
}

__global__ __launch_bounds__(256) void k_gemm2(const float* __restrict__ h,
                                               const float* __restrict__ W,
                                               const float* __restrict__ scale,
                                               bf16* __restrict__ out, int N) {
    __shared__ float ws[FEAT * FEAT];    // 16 KB
    __shared__ float xs[16 * FEAT];      // 4 KB
    const int tid = threadIdx.x;
    for (int i = tid; i < FEAT * FEAT; i += 256) ws[i] = W[i];
    const int row0 = blockIdx.x * 16;
    for (int i = tid; i < 16 * FEAT; i += 256) {
        int r = i >> 6, k = i & 63;
        int gr = row0 + r;
        xs[i] = (gr < N) ? h[(long)gr * FEAT + k] : 0.0f;
    }
    __syncthreads();
    const int rb = tid >> 6;
    const int c  = tid & 63;
    float a0 = 0.f, a1 = 0.f, a2 = 0.f, a3 = 0.f;
    #pragma unroll 4
    for (int k = 0; k < FEAT; ++k) {
        float w = ws[k * FEAT + c];
        a0 += xs[(rb     ) * FEAT + k] * w;
        a1 += xs[(rb +  4) * FEAT + k] * w;
        a2 += xs[(rb +  8) * FEAT + k] * w;
        a3 += xs[(rb + 12) * FEAT + k] * w;
    }
    float acc[4] = {a0, a1, a2, a3};
    for (int j = 0; j < 4; ++j) {
        int gr = row0 + rb + j * 4;
        if (gr < N) out[(long)gr * FEAT + c] = __float2bfloat16(acc[j] * scale[gr]);
    }
}

// ==================== pull aggregation (atomic-free, col-only CSR, bf16 A) ====================
// A rows pre-scaled by dis[src]. agg[i] = dis[i]*(sum_j A[col_j] + A[i]) + bias

__global__ __launch_bounds__(256) void k_agg1(const bf16* __restrict__ A,
                                              const int* __restrict__ rp,
                                              const int* __restrict__ col,
                                              const float* __restrict__ dis,
                                              const float* __restrict__ bias,
                                              float* __restrict__ H, int N) {
    int i = blockIdx.x * 4 + (threadIdx.x >> 6);
    if (i >= N) return;
    int f = threadIdx.x & 63;
    int jb = rp[i], je = rp[i + 1];
    float acc = 0.f;
    int j = jb;
    for (; j + 3 < je; j += 4) {
        int c0 = col[j], c1 = col[j+1], c2 = col[j+2], c3 = col[j+3];
        acc += __bfloat162float(A[(long)c0 * FEAT + f]);
        acc += __bfloat162float(A[(long)c1 * FEAT + f]);
        acc += __bfloat162float(A[(long)c2 * FEAT + f]);
        acc += __bfloat162float(A[(long)c3 * FEAT + f]);
    }
    for (; j < je; ++j) acc += __bfloat162float(A[(long)col[j] * FEAT + f]);
    float v = dis[i] * (acc + __bfloat162float(A[(long)i * FEAT + f])) + bias[f];
    H[(long)i * FEAT + f] = fmaxf(v, 0.f);              // relu
}

__global__ __launch_bounds__(256) void k_agg2s(const bf16* __restrict__ A,
                                               const int* __restrict__ rp,
                                               const int* __restrict__ col,
                                               const float* __restrict__ dis,
                                               const float* __restrict__ bias,
                                               const int* __restrict__ uidx,
                                               float* __restrict__ S, int N) {
    int i = blockIdx.x * 4 + (threadIdx.x >> 6);
    if (i >= N) return;
    int f = threadIdx.x & 63;
    int jb = rp[i], je = rp[i + 1];
    float acc = 0.f;
    int j = jb;
    for (; j + 3 < je; j += 4) {
        int c0 = col[j], c1 = col[j+1], c2 = col[j+2], c3 = col[j+3];
        acc += __bfloat162float(A[(long)c0 * FEAT + f]);
        acc += __bfloat162float(A[(long)c1 * FEAT + f]);
        acc += __bfloat162float(A[(long)c2 * FEAT + f]);
        acc += __bfloat162float(A[(long)c3 * FEAT + f]);
    }
    for (; j < je; ++j) acc += __bfloat162float(A[(long)col[j] * FEAT + f]);
    float v = dis[i] * (acc + __bfloat162float(A[(long)i * FEAT + f])) + bias[f];
    int u = uidx[i];
    if ((unsigned)u < (unsigned)N) atomicAdd(&S[(long)u * FEAT + f], v);
}

// final: out = cnt>0 ? out/cnt : 0 (in place)
__global__ __launch_bounds__(256) void k_final(float* __restrict__ S,
                                               const float* __restrict__ cnt, int N) {
    long idx = (long)blockIdx.x * 256 + threadIdx.x;
    if (idx >= (long)N * FEAT) return;
    int i = (int)(idx >> 6);
    float c = cnt[i];
    S[idx] = (c > 0.f) ? S[idx] / c : 0.f;
}

extern "C" void kernel_launch(void* const* d_in, const int* in_sizes, int n_in,
                              void* d_out, int out_size, void* d_ws, size_t ws_size,
                              hipStream_t stream) {
    const float* x   = (const float*)d_in[0];
    const int* edge  = (const int*)d_in[1];
    const int* uidx  = (const int*)d_in[2];
    const float* W1  = (const float*)d_in[3];
    const float* b1  = (const float*)d_in[4];
    const float* W2  = (const float*)d_in[5];
    const float* b2  = (const float*)d_in[6];
    float* out       = (float*)d_out;

    const int N = in_sizes[2];       // 100000
    const int E = in_sizes[1] / 2;   // 1600000
    const int* src = edge;
    const int* dst = edge + E;

    const size_t fbuf = (size_t)N * FEAT * sizeof(float);    // 25.6 MB
    const size_t abuf = (size_t)N * FEAT * sizeof(bf16);     // 12.8 MB
    const long NF = (long)N * FEAT;
    const int gNF = (int)((NF + 255) / 256);
    const int gE  = (E + 255) / 256;
    const int gN  = (N + 255) / 256;
    const int gN4 = (N + 3) / 4;
    const int nbScan = (N + SCAN_CHUNK - 1) / SCAN_CHUNK;   // 49
    const int KB = (N + BIN_R - 1) >> BIN_SHIFT;            // 196

    auto align256 = [](size_t v) { return (v + 255) & ~(size_t)255; };

    // layout: dis, cntf, rowptr, cntE, ptot, poff, col, A/pairs (max of the two)
    char* w = (char*)d_ws;
    size_t o = 0;
    float* dis  = (float*)(w + o); o = align256(o + (size_t)N * 4);
    float* cntf = (float*)(w + o); o = align256(o + (size_t)N * 4);
    int*   rp   = (int*)  (w + o); o = align256(o + (size_t)(N + 1) * 4);
    int*   cntE = (int*)  (w + o); o = align256(o + (size_t)N * 4);
    int*   ptot = (int*)  (w + o); o = align256(o + (size_t)1024 * 4);
    int*   poff = (int*)  (w + o); o = align256(o + (size_t)1024 * 4);
    int*   col  = (int*)  (w + o); o = align256(o + (size_t)E * 4);
    size_t apsz = (size_t)E * sizeof(int2) > abuf ? (size_t)E * sizeof(int2) : abuf;
    char*  Ap   = w + o;           o = align256(o + apsz);
    const size_t need = o;         // ~21 MB + col ... ~27.5 MB total
    int* bcur = ptot;              // free after scan2
    int2* pairs = (int2*)Ap;       // dead once gemm1 writes A
    bf16* A = (bf16*)Ap;

    if (ws_size >= need && nbScan <= 1024 && KB <= 256) {
        // --- CSR build ---
        hipMemsetAsync(cntE, 0, (size_t)N * 4, stream);
        k_hist <<<gE, 256, 0, stream>>>(dst, cntE, E, N);
        k_dis  <<<gN, 256, 0, stream>>>(cntE, dis, N);
        k_scan1<<<nbScan, SCAN_BS, 0, stream>>>(cntE, rp, ptot, N);
        k_scan2<<<1, 1024, 0, stream>>>(ptot, poff, rp + N, nbScan);
        k_scan3<<<nbScan, SCAN_BS, 0, stream>>>(rp, poff, N);
        k_bcur <<<1, 256, 0, stream>>>(rp, bcur, KB, N);
        k_binA <<<(E + BIN_TILE - 1) / BIN_TILE, 256, 0, stream>>>(src, dst, bcur, pairs, E, N, KB);
        k_binB <<<KB, 256, 0, stream>>>(pairs, rp, col, N);
        hipMemsetAsync(cntf, 0, (size_t)N * 4, stream);
        k_ucnt <<<gN, 256, 0, stream>>>(uidx, cntf, N);

        // --- layer 1: A = bf16((x@W1)*dis[row]); H(=out) = relu(dis*(agg+self)+b1) ---
        k_gemm1<<<(N + 15) / 16, 256, 0, stream>>>(x, W1, dis, A, N);
        k_agg1 <<<gN4, 256, 0, stream>>>(A, rp, col, dis, b1, out, N);

        // --- layer 2: A = bf16((H@W2)*dis[row]); scatter(dis*(agg+self)+b2) into out ---
        k_gemm2<<<(N + 15) / 16, 256, 0, stream>>>(out, W2, dis, A, N);
        hipMemsetAsync(out, 0, fbuf, stream);
        k_agg2s<<<gN4, 256, 0, stream>>>(A, rp, col, dis, b2, uidx, out, N);
        k_final<<<gNF, 256, 0, stream>>>(out, cntf, N);
    } else {
        // fallback: same pipeline, random-scatter fill
        hipMemsetAsync(cntE, 0, (size_t)N * 4, stream);
        k_hist <<<gE, 256, 0, stream>>>(dst, cntE, E, N);
        k_dis  <<<gN, 256, 0, stream>>>(cntE, dis, N);
        k_scan1<<<nbScan, SCAN_BS, 0, stream>>>(cntE, rp, ptot, N);
        k_scan2<<<1, 1024, 0, stream>>>(ptot, poff, rp + N, nbScan);
        k_scan3<<<nbScan, SCAN_BS, 0, stream>>>(rp, poff, N);
        hipMemsetAsync(cntE, 0, (size_t)N * 4, stream);
        k_fill <<<gE, 256, 0, stream>>>(src, dst, rp, cntE, col, E, N);
        hipMemsetAsync(cntf, 0, (size_t)N * 4, stream);
        k_ucnt <<<gN, 256, 0, stream>>>(uidx, cntf, N);
        k_gemm1<<<(N + 15) / 16, 256, 0, stream>>>(x, W1, dis, A, N);
        k_agg1 <<<gN4, 256, 0, stream>>>(A, rp, col, dis, b1, out, N);
        k_gemm2<<<(N + 15) / 16, 256, 0, stream>>>(out, W2, dis, A, N);
        hipMemsetAsync(out, 0, fbuf, stream);
        k_agg2s<<<gN4, 256, 0, stream>>>(A, rp, col, dis, b2, uidx, out, N);
        k_final<<<gNF, 256, 0, stream>>>(out, cntf, N);
    }
}

// Round 9
// 419.249 us; speedup vs baseline: 2.5372x; 1.1121x over previous
//
#include <hip/hip_runtime.h>
#include <hip/hip_bf16.h>

// GCN: h1 = relu(GCNConv(x, W1, b1)); out = scatter_mean(GCNConv(h1, W2, b2), user_idx)
// N=100000, E=1600000, dims 128 -> 64 -> 64. fp32 I/O, int32 indices.
//
// R8 profile: k_gemm1 77us (scalar FMA, VALUBusy 51%, 3 issue slots/FMA on LDS
// reads); k_agg* 75us latency-bound (33% VALU, 1.5TB/s). R9: (1) MFMA bf16
// GEMMs -- W staged frag-ordered in LDS (aligned b128, conflict-free), A frags
// direct from global (32B/lane contiguous); (2) agg gather unroll 4->8 for MLP.

#define FEAT 64
#define INDIM 128

#define SCAN_BS 256
#define SCAN_ELEMS 8
#define SCAN_CHUNK (SCAN_BS * SCAN_ELEMS)

#define BIN_SHIFT 9
#define BIN_R 512
#define BIN_TILE 4096

typedef __attribute__((ext_vector_type(8))) short short8;   // 8 bf16 = 4 VGPRs
typedef __attribute__((ext_vector_type(4))) float f32x4;

__device__ __forceinline__ unsigned short f2bf(float f) {   // RNE fp32->bf16
    unsigned u = __float_as_uint(f);
    unsigned r = u + 0x7FFFu + ((u >> 16) & 1u);
    return (unsigned short)(r >> 16);
}
__device__ __forceinline__ float bf2f(unsigned short v) {
    return __uint_as_float(((unsigned)v) << 16);
}

// ==================== CSR build ====================

__global__ __launch_bounds__(256) void k_hist(const int* __restrict__ dst,
                                              int* __restrict__ cntE, int E, int N) {
    int e = blockIdx.x * 256 + threadIdx.x;
    if (e < E) {
        int d = dst[e];
        if ((unsigned)d < (unsigned)N) atomicAdd(&cntE[d], 1);
    }
}

__global__ __launch_bounds__(256) void k_dis(const int* __restrict__ cntE,
                                             float* __restrict__ dis, int N) {
    int i = blockIdx.x * 256 + threadIdx.x;
    if (i < N) dis[i] = rsqrtf((float)cntE[i] + 1.0f);
}

__global__ __launch_bounds__(SCAN_BS) void k_scan1(const int* __restrict__ c,
                                                   int* __restrict__ rp,
                                                   int* __restrict__ ptot, int N) {
    __shared__ int lds[SCAN_BS];
    const int base = blockIdx.x * SCAN_CHUNK;
    const int tb = base + threadIdx.x * SCAN_ELEMS;
    int vals[SCAN_ELEMS];
    int s = 0;
    #pragma unroll
    for (int k = 0; k < SCAN_ELEMS; ++k) {
        int idx = tb + k;
        int v = (idx < N) ? c[idx] : 0;
        vals[k] = s;
        s += v;
    }
    lds[threadIdx.x] = s;
    __syncthreads();
    for (int d = 1; d < SCAN_BS; d <<= 1) {
        int v = (threadIdx.x >= d) ? lds[threadIdx.x - d] : 0;
        __syncthreads();
        lds[threadIdx.x] += v;
        __syncthreads();
    }
    int toff = (threadIdx.x == 0) ? 0 : lds[threadIdx.x - 1];
    #pragma unroll
    for (int k = 0; k < SCAN_ELEMS; ++k) {
        int idx = tb + k;
        if (idx < N) rp[idx] = toff + vals[k];
    }
    if (threadIdx.x == SCAN_BS - 1) ptot[blockIdx.x] = lds[SCAN_BS - 1];
}

__global__ __launch_bounds__(1024) void k_scan2(int* __restrict__ ptot,
                                                int* __restrict__ poff,
                                                int* __restrict__ rpN, int nb) {
    __shared__ int lds[1024];
    int tid = threadIdx.x;
    lds[tid] = (tid < nb) ? ptot[tid] : 0;
    __syncthreads();
    for (int d = 1; d < 1024; d <<= 1) {
        int v = (tid >= d) ? lds[tid - d] : 0;
        __syncthreads();
        lds[tid] += v;
        __syncthreads();
    }
    if (tid < nb) poff[tid] = (tid == 0) ? 0 : lds[tid - 1];
    if (tid == nb - 1) *rpN = lds[tid];
}

__global__ __launch_bounds__(SCAN_BS) void k_scan3(int* __restrict__ rp,
                                                   const int* __restrict__ poff, int N) {
    int off = poff[blockIdx.x];
    const int tb = blockIdx.x * SCAN_CHUNK + threadIdx.x * SCAN_ELEMS;
    #pragma unroll
    for (int k = 0; k < SCAN_ELEMS; ++k) {
        int idx = tb + k;
        if (idx < N) rp[idx] += off;
    }
}

__global__ __launch_bounds__(256) void k_bcur(const int* __restrict__ rp,
                                              int* __restrict__ bcur, int KB, int N) {
    int b = blockIdx.x * 256 + threadIdx.x;
    if (b < KB) {
        int n = b << BIN_SHIFT;
        if (n > N) n = N;
        bcur[b] = rp[n];
    }
}

__global__ __launch_bounds__(256) void k_binA(const int* __restrict__ src,
                                              const int* __restrict__ dst,
                                              int* __restrict__ bcur,
                                              int2* __restrict__ pairs,
                                              int E, int N, int KB) {
    __shared__ int2 lbuf[BIN_TILE];
    __shared__ unsigned short bkt[BIN_TILE];
    __shared__ int lcnt[256];
    __shared__ int loff[256];
    __shared__ int lbase[256];
    __shared__ int tot;
    const int tid = threadIdx.x;
    const int base = blockIdx.x * BIN_TILE;

    lcnt[tid] = 0;
    __syncthreads();

    int mys[16], myd[16], myb[16];
    #pragma unroll
    for (int t = 0; t < 16; ++t) {
        int e = base + t * 256 + tid;
        int s = 0, d = -1;
        if (e < E) { s = src[e]; d = dst[e]; }
        if ((unsigned)d >= (unsigned)N) d = -1;
        if ((unsigned)s >= (unsigned)N) s = 0;
        mys[t] = s; myd[t] = d;
        myb[t] = (d >= 0) ? (d >> BIN_SHIFT) : -1;
        if (myb[t] >= 0) atomicAdd(&lcnt[myb[t]], 1);
    }
    __syncthreads();

    int v = lcnt[tid];
    loff[tid] = v;
    __syncthreads();
    for (int d = 1; d < 256; d <<= 1) {
        int t2 = (tid >= d) ? loff[tid - d] : 0;
        __syncthreads();
        loff[tid] += t2;
        __syncthreads();
    }
    if (tid == 255) tot = loff[255];
    int excl = loff[tid] - v;
    __syncthreads();
    loff[tid] = excl;
    lcnt[tid] = excl;
    if (tid < KB && v > 0) lbase[tid] = atomicAdd(&bcur[tid], v);
    __syncthreads();

    #pragma unroll
    for (int t = 0; t < 16; ++t) {
        if (myb[t] >= 0) {
            int pos = atomicAdd(&lcnt[myb[t]], 1);
            lbuf[pos] = make_int2(mys[t], myd[t]);
            bkt[pos] = (unsigned short)myb[t];
        }
    }
    __syncthreads();

    const int T = tot;
    for (int i = tid; i < T; i += 256) {
        int b = bkt[i];
        pairs[lbase[b] + (i - loff[b])] = lbuf[i];
    }
}

__global__ __launch_bounds__(256) void k_binB(const int2* __restrict__ pairs,
                                              const int* __restrict__ rp,
                                              int* __restrict__ col, int N) {
    __shared__ int cur[BIN_R + 1];
    const int b = blockIdx.x;
    const int n0 = b << BIN_SHIFT;
    const int n1 = min(n0 + BIN_R, N);
    const int nn = n1 - n0;
    for (int i = threadIdx.x; i <= nn; i += 256) cur[i] = rp[n0 + i];
    __syncthreads();
    const int e0 = cur[0];
    const int e1 = cur[nn];
    __syncthreads();
    for (int i = e0 + threadIdx.x; i < e1; i += 256) {
        int2 p = pairs[i];
        int pos = atomicAdd(&cur[p.y - n0], 1);
        col[pos] = p.x;
    }
}

__global__ __launch_bounds__(256) void k_fill(const int* __restrict__ src,
                                              const int* __restrict__ dst,
                                              const int* __restrict__ rp,
                                              int* __restrict__ tmp,
                                              int* __restrict__ col, int E, int N) {
    int e = blockIdx.x * 256 + threadIdx.x;
    if (e >= E) return;
    int s = src[e], d = dst[e];
    if ((unsigned)s >= (unsigned)N) s = 0;
    if ((unsigned)d >= (unsigned)N) return;
    int r = atomicAdd(&tmp[d], 1);
    col[rp[d] + r] = s;
}

__global__ __launch_bounds__(256) void k_ucnt(const int* __restrict__ uidx,
                                              float* __restrict__ cntf, int N) {
    int i = blockIdx.x * 256 + threadIdx.x;
    if (i < N) {
        int u = uidx[i];
        if ((unsigned)u < (unsigned)N) atomicAdd(&cntf[u], 1.0f);
    }
}

// ==================== MFMA GEMMs ====================
// mfma_f32_16x16x32_bf16 layouts (verified, learn_hip m89/m91/m120):
//   A: lane holds A[m=lane&15][k=(lane>>4)*8+j], j=0..7
//   B: lane holds B[k=(lane>>4)*8+j][n=lane&15]
//   C: lane reg r -> C[row=(lane>>4)*4+r][col=lane&15]
// W staged in LDS frag-ordered: wf[(ct*KC+kc)*64+lane][j] -> aligned b128 reads.

// GEMM1: A_out[N x 64](bf16) = (x[N x 128] @ W[128 x 64]) * dis[row]
__global__ __launch_bounds__(256) void k_gemm1(const float* __restrict__ x,
                                               const float* __restrict__ W,
                                               const float* __restrict__ scale,
                                               unsigned short* __restrict__ out, int N) {
    __shared__ short wf[4 * 4 * 64 * 8];   // 16 KB, frag-ordered
    const int tid = threadIdx.x;
    for (int i = tid; i < INDIM * FEAT; i += 256) {
        int k = i >> 6, n = i & 63;
        int ct = n >> 4, kc = k >> 5, r = k & 31;
        int owner = ((r >> 3) << 4) | (n & 15);
        wf[(((ct << 2) | kc) * 64 + owner) * 8 + (r & 7)] = (short)f2bf(W[i]);
    }
    __syncthreads();

    const int lane = tid & 63;
    const int m = lane & 15, q = lane >> 4;
    const int row0 = blockIdx.x * 64 + (tid >> 6) * 16;

    short8 bfr[4][4];
    #pragma unroll
    for (int ct = 0; ct < 4; ++ct)
        #pragma unroll
        for (int kc = 0; kc < 4; ++kc)
            bfr[ct][kc] = *reinterpret_cast<const short8*>(&wf[(((ct << 2) | kc) * 64 + lane) * 8]);

    int gr = row0 + m;
    int rl = gr < N ? gr : (N - 1);
    const float* xp = x + (long)rl * INDIM + q * 8;

    f32x4 acc[4] = {{0,0,0,0},{0,0,0,0},{0,0,0,0},{0,0,0,0}};
    #pragma unroll
    for (int kc = 0; kc < 4; ++kc) {
        float4 v0 = *reinterpret_cast<const float4*>(xp + kc * 32);
        float4 v1 = *reinterpret_cast<const float4*>(xp + kc * 32 + 4);
        short8 a;
        a[0]=(short)f2bf(v0.x); a[1]=(short)f2bf(v0.y); a[2]=(short)f2bf(v0.z); a[3]=(short)f2bf(v0.w);
        a[4]=(short)f2bf(v1.x); a[5]=(short)f2bf(v1.y); a[6]=(short)f2bf(v1.z); a[7]=(short)f2bf(v1.w);
        #pragma unroll
        for (int ct = 0; ct < 4; ++ct)
            acc[ct] = __builtin_amdgcn_mfma_f32_16x16x32_bf16(a, bfr[ct][kc], acc[ct], 0, 0, 0);
    }

    #pragma unroll
    for (int reg = 0; reg < 4; ++reg) {
        int row = row0 + q * 4 + reg;
        if (row < N) {
            float sc = scale[row];
            #pragma unroll
            for (int ct = 0; ct < 4; ++ct)
                out[(long)row * FEAT + ct * 16 + m] = f2bf(acc[ct][reg] * sc);
        }
    }
}

// GEMM2: A_out[N x 64](bf16) = (h[N x 64] @ W[64 x 64]) * dis[row]
__global__ __launch_bounds__(256) void k_gemm2(const float* __restrict__ h,
                                               const float* __restrict__ W,
                                               const float* __restrict__ scale,
                                               unsigned short* __restrict__ out, int N) {
    __shared__ short wf[4 * 2 * 64 * 8];   // 8 KB
    const int tid = threadIdx.x;
    for (int i = tid; i < FEAT * FEAT; i += 256) {
        int k = i >> 6, n = i & 63;
        int ct = n >> 4, kc = k >> 5, r = k & 31;
        int owner = ((r >> 3) << 4) | (n & 15);
        wf[(((ct << 1) | kc) * 64 + owner) * 8 + (r & 7)] = (short)f2bf(W[i]);
    }
    __syncthreads();

    const int lane = tid & 63;
    const int m = lane & 15, q = lane >> 4;
    const int row0 = blockIdx.x * 64 + (tid >> 6) * 16;

    short8 bfr[4][2];
    #pragma unroll
    for (int ct = 0; ct < 4; ++ct)
        #pragma unroll
        for (int kc = 0; kc < 2; ++kc)
            bfr[ct][kc] = *reinterpret_cast<const short8*>(&wf[(((ct << 1) | kc) * 64 + lane) * 8]);

    int gr = row0 + m;
    int rl = gr < N ? gr : (N - 1);
    const float* hp = h + (long)rl * FEAT + q * 8;

    f32x4 acc[4] = {{0,0,0,0},{0,0,0,0},{0,0,0,0},{0,0,0,0}};
    #pragma unroll
    for (int kc = 0; kc < 2; ++kc) {
        float4 v0 = *reinterpret_cast<const float4*>(hp + kc * 32);
        float4 v1 = *reinterpret_cast<const float4*>(hp + kc * 32 + 4);
        short8 a;
        a[0]=(short)f2bf(v0.x); a[1]=(short)f2bf(v0.y); a[2]=(short)f2bf(v0.z); a[3]=(short)f2bf(v0.w);
        a[4]=(short)f2bf(v1.x); a[5]=(short)f2bf(v1.y); a[6]=(short)f2bf(v1.z); a[7]=(short)f2bf(v1.w);
        #pragma unroll
        for (int ct = 0; ct < 4; ++ct)
            acc[ct] = __builtin_amdgcn_mfma_f32_16x16x32_bf16(a, bfr[ct][kc], acc[ct], 0, 0, 0);
    }

    #pragma unroll
    for (int reg = 0; reg < 4; ++reg) {
        int row = row0 + q * 4 + reg;
        if (row < N) {
            float sc = scale[row];
            #pragma unroll
            for (int ct = 0; ct < 4; ++ct)
                out[(long)row * FEAT + ct * 16 + m] = f2bf(acc[ct][reg] * sc);
        }
    }
}

// ==================== pull aggregation (atomic-free, bf16 A, unroll 8) ====================

__global__ __launch_bounds__(256) void k_agg1(const unsigned short* __restrict__ A,
                                              const int* __restrict__ rp,
                                              const int* __restrict__ col,
                                              const float* __restrict__ dis,
                                              const float* __restrict__ bias,
                                              float* __restrict__ H, int N) {
    int i = blockIdx.x * 4 + (threadIdx.x >> 6);
    if (i >= N) return;
    int f = threadIdx.x & 63;
    int jb = rp[i], je = rp[i + 1];
    float acc = 0.f;
    int j = jb;
    for (; j + 7 < je; j += 8) {
        int c0=col[j],c1=col[j+1],c2=col[j+2],c3=col[j+3];
        int c4=col[j+4],c5=col[j+5],c6=col[j+6],c7=col[j+7];
        float t0=bf2f(A[(long)c0*FEAT+f]), t1=bf2f(A[(long)c1*FEAT+f]);
        float t2=bf2f(A[(long)c2*FEAT+f]), t3=bf2f(A[(long)c3*FEAT+f]);
        float t4=bf2f(A[(long)c4*FEAT+f]), t5=bf2f(A[(long)c5*FEAT+f]);
        float t6=bf2f(A[(long)c6*FEAT+f]), t7=bf2f(A[(long)c7*FEAT+f]);
        acc += ((t0+t1)+(t2+t3)) + ((t4+t5)+(t6+t7));
    }
    for (; j < je; ++j) acc += bf2f(A[(long)col[j]*FEAT+f]);
    float v = dis[i] * (acc + bf2f(A[(long)i*FEAT+f])) + bias[f];
    H[(long)i * FEAT + f] = fmaxf(v, 0.f);
}

__global__ __launch_bounds__(256) void k_agg2s(const unsigned short* __restrict__ A,
                                               const int* __restrict__ rp,
                                               const int* __restrict__ col,
                                               const float* __restrict__ dis,
                                               const float* __restrict__ bias,
                                               const int* __restrict__ uidx,
                                               float* __restrict__ S, int N) {
    int i = blockIdx.x * 4 + (threadIdx.x >> 6);
    if (i >= N) return;
    int f = threadIdx.x & 63;
    int jb = rp[i], je = rp[i + 1];
    float acc = 0.f;
    int j = jb;
    for (; j + 7 < je; j += 8) {
        int c0=col[j],c1=col[j+1],c2=col[j+2],c3=col[j+3];
        int c4=col[j+4],c5=col[j+5],c6=col[j+6],c7=col[j+7];
        float t0=bf2f(A[(long)c0*FEAT+f]), t1=bf2f(A[(long)c1*FEAT+f]);
        float t2=bf2f(A[(long)c2*FEAT+f]), t3=bf2f(A[(long)c3*FEAT+f]);
        float t4=bf2f(A[(long)c4*FEAT+f]), t5=bf2f(A[(long)c5*FEAT+f]);
        float t6=bf2f(A[(long)c6*FEAT+f]), t7=bf2f(A[(long)c7*FEAT+f]);
        acc += ((t0+t1)+(t2+t3)) + ((t4+t5)+(t6+t7));
    }
    for (; j < je; ++j) acc += bf2f(A[(long)col[j]*FEAT+f]);
    float v = dis[i] * (acc + bf2f(A[(long)i*FEAT+f])) + bias[f];
    int u = uidx[i];
    if ((unsigned)u < (unsigned)N) atomicAdd(&S[(long)u * FEAT + f], v);
}

__global__ __launch_bounds__(256) void k_final(float* __restrict__ S,
                                               const float* __restrict__ cnt, int N) {
    long idx = (long)blockIdx.x * 256 + threadIdx.x;
    if (idx >= (long)N * FEAT) return;
    int i = (int)(idx >> 6);
    float c = cnt[i];
    S[idx] = (c > 0.f) ? S[idx] / c : 0.f;
}

extern "C" void kernel_launch(void* const* d_in, const int* in_sizes, int n_in,
                              void* d_out, int out_size, void* d_ws, size_t ws_size,
                              hipStream_t stream) {
    const float* x   = (const float*)d_in[0];
    const int* edge  = (const int*)d_in[1];
    const int* uidx  = (const int*)d_in[2];
    const float* W1  = (const float*)d_in[3];
    const float* b1  = (const float*)d_in[4];
    const float* W2  = (const float*)d_in[5];
    const float* b2  = (const float*)d_in[6];
    float* out       = (float*)d_out;

    const int N = in_sizes[2];       // 100000
    const int E = in_sizes[1] / 2;   // 1600000
    const int* src = edge;
    const int* dst = edge + E;

    const size_t fbuf = (size_t)N * FEAT * sizeof(float);          // 25.6 MB
    const size_t abuf = (size_t)N * FEAT * sizeof(unsigned short); // 12.8 MB
    const long NF = (long)N * FEAT;
    const int gNF = (int)((NF + 255) / 256);
    const int gE  = (E + 255) / 256;
    const int gN  = (N + 255) / 256;
    const int gN4 = (N + 3) / 4;
    const int gG  = (N + 63) / 64;                                 // MFMA gemm grid
    const int nbScan = (N + SCAN_CHUNK - 1) / SCAN_CHUNK;
    const int KB = (N + BIN_R - 1) >> BIN_SHIFT;

    auto align256 = [](size_t v) { return (v + 255) & ~(size_t)255; };

    char* w = (char*)d_ws;
    size_t o = 0;
    float* dis  = (float*)(w + o); o = align256(o + (size_t)N * 4);
    float* cntf = (float*)(w + o); o = align256(o + (size_t)N * 4);
    int*   rp   = (int*)  (w + o); o = align256(o + (size_t)(N + 1) * 4);
    int*   cntE = (int*)  (w + o); o = align256(o + (size_t)N * 4);
    int*   ptot = (int*)  (w + o); o = align256(o + (size_t)1024 * 4);
    int*   poff = (int*)  (w + o); o = align256(o + (size_t)1024 * 4);
    int*   col  = (int*)  (w + o); o = align256(o + (size_t)E * 4);
    size_t apsz = (size_t)E * sizeof(int2) > abuf ? (size_t)E * sizeof(int2) : abuf;
    char*  Ap   = w + o;           o = align256(o + apsz);
    const size_t need = o;
    int* bcur = ptot;
    int2* pairs = (int2*)Ap;
    unsigned short* A = (unsigned short*)Ap;

    if (ws_size >= need && nbScan <= 1024 && KB <= 256) {
        hipMemsetAsync(cntE, 0, (size_t)N * 4, stream);
        k_hist <<<gE, 256, 0, stream>>>(dst, cntE, E, N);
        k_dis  <<<gN, 256, 0, stream>>>(cntE, dis, N);
        k_scan1<<<nbScan, SCAN_BS, 0, stream>>>(cntE, rp, ptot, N);
        k_scan2<<<1, 1024, 0, stream>>>(ptot, poff, rp + N, nbScan);
        k_scan3<<<nbScan, SCAN_BS, 0, stream>>>(rp, poff, N);
        k_bcur <<<1, 256, 0, stream>>>(rp, bcur, KB, N);
        k_binA <<<(E + BIN_TILE - 1) / BIN_TILE, 256, 0, stream>>>(src, dst, bcur, pairs, E, N, KB);
        k_binB <<<KB, 256, 0, stream>>>(pairs, rp, col, N);
        hipMemsetAsync(cntf, 0, (size_t)N * 4, stream);
        k_ucnt <<<gN, 256, 0, stream>>>(uidx, cntf, N);

        k_gemm1<<<gG, 256, 0, stream>>>(x, W1, dis, A, N);
        k_agg1 <<<gN4, 256, 0, stream>>>(A, rp, col, dis, b1, out, N);

        k_gemm2<<<gG, 256, 0, stream>>>(out, W2, dis, A, N);
        hipMemsetAsync(out, 0, fbuf, stream);
        k_agg2s<<<gN4, 256, 0, stream>>>(A, rp, col, dis, b2, uidx, out, N);
        k_final<<<gNF, 256, 0, stream>>>(out, cntf, N);
    } else {
        hipMemsetAsync(cntE, 0, (size_t)N * 4, stream);
        k_hist <<<gE, 256, 0, stream>>>(dst, cntE, E, N);
        k_dis  <<<gN, 256, 0, stream>>>(cntE, dis, N);
        k_scan1<<<nbScan, SCAN_BS, 0, stream>>>(cntE, rp, ptot, N);
        k_scan2<<<1, 1024, 0, stream>>>(ptot, poff, rp + N, nbScan);
        k_scan3<<<nbScan, SCAN_BS, 0, stream>>>(rp, poff, N);
        hipMemsetAsync(cntE, 0, (size_t)N * 4, stream);
        k_fill <<<gE, 256, 0, stream>>>(src, dst, rp, cntE, col, E, N);
        hipMemsetAsync(cntf, 0, (size_t)N * 4, stream);
        k_ucnt <<<gN, 256, 0, stream>>>(uidx, cntf, N);
        k_gemm1<<<gG, 256, 0, stream>>>(x, W1, dis, A, N);
        k_agg1 <<<gN4, 256, 0, stream>>>(A, rp, col, dis, b1, out, N);
        k_gemm2<<<gG, 256, 0, stream>>>(out, W2, dis, A, N);
        hipMemsetAsync(out, 0, fbuf, stream);
        k_agg2s<<<gN4, 256, 0, stream>>>(A, rp, col, dis, b2, uidx, out, N);
        k_final<<<gNF, 256, 0, stream>>>(out, cntf, N);
    }
}

// Round 10
// 378.702 us; speedup vs baseline: 2.8088x; 1.1071x over previous
//
#include <hip/hip_runtime.h>
#include <hip/hip_bf16.h>

// GCN: h1 = relu(GCNConv(x, W1, b1)); out = scatter_mean(GCNConv(h1, W2, b2), user_idx)
// N=100000, E=1600000, dims 128 -> 64 -> 64. fp32 I/O, int32 indices.
//
// R9 profile: k_agg* stuck at 75us, FETCH=87MB == predicted L2-miss traffic of
// the random row gather (A=12.8MB vs 4MB/XCD L2), VALUBusy 30% -> VMEM-issue/
// latency bound, not BW bound. R10: widened gather -- 8B/lane (bf16x4), 16
// lanes/row, 4 edges per wave-instruction (512B), float4 quarter-accumulators
// combined via shfl_xor(16,32). 4x fewer VMEM instructions per edge.

#define FEAT 64
#define INDIM 128

#define SCAN_BS 256
#define SCAN_ELEMS 8
#define SCAN_CHUNK (SCAN_BS * SCAN_ELEMS)

#define BIN_SHIFT 9
#define BIN_R 512
#define BIN_TILE 4096

typedef __attribute__((ext_vector_type(8))) short short8;   // 8 bf16 = 4 VGPRs
typedef __attribute__((ext_vector_type(4))) float f32x4;

__device__ __forceinline__ unsigned short f2bf(float f) {   // RNE fp32->bf16
    unsigned u = __float_as_uint(f);
    unsigned r = u + 0x7FFFu + ((u >> 16) & 1u);
    return (unsigned short)(r >> 16);
}
__device__ __forceinline__ float bf2f(unsigned short v) {
    return __uint_as_float(((unsigned)v) << 16);
}

// ==================== CSR build ====================

__global__ __launch_bounds__(256) void k_hist(const int* __restrict__ dst,
                                              int* __restrict__ cntE, int E, int N) {
    int e = blockIdx.x * 256 + threadIdx.x;
    if (e < E) {
        int d = dst[e];
        if ((unsigned)d < (unsigned)N) atomicAdd(&cntE[d], 1);
    }
}

__global__ __launch_bounds__(256) void k_dis(const int* __restrict__ cntE,
                                             float* __restrict__ dis, int N) {
    int i = blockIdx.x * 256 + threadIdx.x;
    if (i < N) dis[i] = rsqrtf((float)cntE[i] + 1.0f);
}

__global__ __launch_bounds__(SCAN_BS) void k_scan1(const int* __restrict__ c,
                                                   int* __restrict__ rp,
                                                   int* __restrict__ ptot, int N) {
    __shared__ int lds[SCAN_BS];
    const int base = blockIdx.x * SCAN_CHUNK;
    const int tb = base + threadIdx.x * SCAN_ELEMS;
    int vals[SCAN_ELEMS];
    int s = 0;
    #pragma unroll
    for (int k = 0; k < SCAN_ELEMS; ++k) {
        int idx = tb + k;
        int v = (idx < N) ? c[idx] : 0;
        vals[k] = s;
        s += v;
    }
    lds[threadIdx.x] = s;
    __syncthreads();
    for (int d = 1; d < SCAN_BS; d <<= 1) {
        int v = (threadIdx.x >= d) ? lds[threadIdx.x - d] : 0;
        __syncthreads();
        lds[threadIdx.x] += v;
        __syncthreads();
    }
    int toff = (threadIdx.x == 0) ? 0 : lds[threadIdx.x - 1];
    #pragma unroll
    for (int k = 0; k < SCAN_ELEMS; ++k) {
        int idx = tb + k;
        if (idx < N) rp[idx] = toff + vals[k];
    }
    if (threadIdx.x == SCAN_BS - 1) ptot[blockIdx.x] = lds[SCAN_BS - 1];
}

__global__ __launch_bounds__(1024) void k_scan2(int* __restrict__ ptot,
                                                int* __restrict__ poff,
                                                int* __restrict__ rpN, int nb) {
    __shared__ int lds[1024];
    int tid = threadIdx.x;
    lds[tid] = (tid < nb) ? ptot[tid] : 0;
    __syncthreads();
    for (int d = 1; d < 1024; d <<= 1) {
        int v = (tid >= d) ? lds[tid - d] : 0;
        __syncthreads();
        lds[tid] += v;
        __syncthreads();
    }
    if (tid < nb) poff[tid] = (tid == 0) ? 0 : lds[tid - 1];
    if (tid == nb - 1) *rpN = lds[tid];
}

__global__ __launch_bounds__(SCAN_BS) void k_scan3(int* __restrict__ rp,
                                                   const int* __restrict__ poff, int N) {
    int off = poff[blockIdx.x];
    const int tb = blockIdx.x * SCAN_CHUNK + threadIdx.x * SCAN_ELEMS;
    #pragma unroll
    for (int k = 0; k < SCAN_ELEMS; ++k) {
        int idx = tb + k;
        if (idx < N) rp[idx] += off;
    }
}

__global__ __launch_bounds__(256) void k_bcur(const int* __restrict__ rp,
                                              int* __restrict__ bcur, int KB, int N) {
    int b = blockIdx.x * 256 + threadIdx.x;
    if (b < KB) {
        int n = b << BIN_SHIFT;
        if (n > N) n = N;
        bcur[b] = rp[n];
    }
}

__global__ __launch_bounds__(256) void k_binA(const int* __restrict__ src,
                                              const int* __restrict__ dst,
                                              int* __restrict__ bcur,
                                              int2* __restrict__ pairs,
                                              int E, int N, int KB) {
    __shared__ int2 lbuf[BIN_TILE];
    __shared__ unsigned short bkt[BIN_TILE];
    __shared__ int lcnt[256];
    __shared__ int loff[256];
    __shared__ int lbase[256];
    __shared__ int tot;
    const int tid = threadIdx.x;
    const int base = blockIdx.x * BIN_TILE;

    lcnt[tid] = 0;
    __syncthreads();

    int mys[16], myd[16], myb[16];
    #pragma unroll
    for (int t = 0; t < 16; ++t) {
        int e = base + t * 256 + tid;
        int s = 0, d = -1;
        if (e < E) { s = src[e]; d = dst[e]; }
        if ((unsigned)d >= (unsigned)N) d = -1;
        if ((unsigned)s >= (unsigned)N) s = 0;
        mys[t] = s; myd[t] = d;
        myb[t] = (d >= 0) ? (d >> BIN_SHIFT) : -1;
        if (myb[t] >= 0) atomicAdd(&lcnt[myb[t]], 1);
    }
    __syncthreads();

    int v = lcnt[tid];
    loff[tid] = v;
    __syncthreads();
    for (int d = 1; d < 256; d <<= 1) {
        int t2 = (tid >= d) ? loff[tid - d] : 0;
        __syncthreads();
        loff[tid] += t2;
        __syncthreads();
    }
    if (tid == 255) tot = loff[255];
    int excl = loff[tid] - v;
    __syncthreads();
    loff[tid] = excl;
    lcnt[tid] = excl;
    if (tid < KB && v > 0) lbase[tid] = atomicAdd(&bcur[tid], v);
    __syncthreads();

    #pragma unroll
    for (int t = 0; t < 16; ++t) {
        if (myb[t] >= 0) {
            int pos = atomicAdd(&lcnt[myb[t]], 1);
            lbuf[pos] = make_int2(mys[t], myd[t]);
            bkt[pos] = (unsigned short)myb[t];
        }
    }
    __syncthreads();

    const int T = tot;
    for (int i = tid; i < T; i += 256) {
        int b = bkt[i];
        pairs[lbase[b] + (i - loff[b])] = lbuf[i];
    }
}

__global__ __launch_bounds__(256) void k_binB(const int2* __restrict__ pairs,
                                              const int* __restrict__ rp,
                                              int* __restrict__ col, int N) {
    __shared__ int cur[BIN_R + 1];
    const int b = blockIdx.x;
    const int n0 = b << BIN_SHIFT;
    const int n1 = min(n0 + BIN_R, N);
    const int nn = n1 - n0;
    for (int i = threadIdx.x; i <= nn; i += 256) cur[i] = rp[n0 + i];
    __syncthreads();
    const int e0 = cur[0];
    const int e1 = cur[nn];
    __syncthreads();
    for (int i = e0 + threadIdx.x; i < e1; i += 256) {
        int2 p = pairs[i];
        int pos = atomicAdd(&cur[p.y - n0], 1);
        col[pos] = p.x;
    }
}

__global__ __launch_bounds__(256) void k_fill(const int* __restrict__ src,
                                              const int* __restrict__ dst,
                                              const int* __restrict__ rp,
                                              int* __restrict__ tmp,
                                              int* __restrict__ col, int E, int N) {
    int e = blockIdx.x * 256 + threadIdx.x;
    if (e >= E) return;
    int s = src[e], d = dst[e];
    if ((unsigned)s >= (unsigned)N) s = 0;
    if ((unsigned)d >= (unsigned)N) return;
    int r = atomicAdd(&tmp[d], 1);
    col[rp[d] + r] = s;
}

__global__ __launch_bounds__(256) void k_ucnt(const int* __restrict__ uidx,
                                              float* __restrict__ cntf, int N) {
    int i = blockIdx.x * 256 + threadIdx.x;
    if (i < N) {
        int u = uidx[i];
        if ((unsigned)u < (unsigned)N) atomicAdd(&cntf[u], 1.0f);
    }
}

// ==================== MFMA GEMMs (16x16x32 bf16, verified layouts) ====================

__global__ __launch_bounds__(256) void k_gemm1(const float* __restrict__ x,
                                               const float* __restrict__ W,
                                               const float* __restrict__ scale,
                                               unsigned short* __restrict__ out, int N) {
    __shared__ short wf[4 * 4 * 64 * 8];   // 16 KB, frag-ordered
    const int tid = threadIdx.x;
    for (int i = tid; i < INDIM * FEAT; i += 256) {
        int k = i >> 6, n = i & 63;
        int ct = n >> 4, kc = k >> 5, r = k & 31;
        int owner = ((r >> 3) << 4) | (n & 15);
        wf[(((ct << 2) | kc) * 64 + owner) * 8 + (r & 7)] = (short)f2bf(W[i]);
    }
    __syncthreads();

    const int lane = tid & 63;
    const int m = lane & 15, q = lane >> 4;
    const int row0 = blockIdx.x * 64 + (tid >> 6) * 16;

    short8 bfr[4][4];
    #pragma unroll
    for (int ct = 0; ct < 4; ++ct)
        #pragma unroll
        for (int kc = 0; kc < 4; ++kc)
            bfr[ct][kc] = *reinterpret_cast<const short8*>(&wf[(((ct << 2) | kc) * 64 + lane) * 8]);

    int gr = row0 + m;
    int rl = gr < N ? gr : (N - 1);
    const float* xp = x + (long)rl * INDIM + q * 8;

    f32x4 acc[4] = {{0,0,0,0},{0,0,0,0},{0,0,0,0},{0,0,0,0}};
    #pragma unroll
    for (int kc = 0; kc < 4; ++kc) {
        float4 v0 = *reinterpret_cast<const float4*>(xp + kc * 32);
        float4 v1 = *reinterpret_cast<const float4*>(xp + kc * 32 + 4);
        short8 a;
        a[0]=(short)f2bf(v0.x); a[1]=(short)f2bf(v0.y); a[2]=(short)f2bf(v0.z); a[3]=(short)f2bf(v0.w);
        a[4]=(short)f2bf(v1.x); a[5]=(short)f2bf(v1.y); a[6]=(short)f2bf(v1.z); a[7]=(short)f2bf(v1.w);
        #pragma unroll
        for (int ct = 0; ct < 4; ++ct)
            acc[ct] = __builtin_amdgcn_mfma_f32_16x16x32_bf16(a, bfr[ct][kc], acc[ct], 0, 0, 0);
    }

    #pragma unroll
    for (int reg = 0; reg < 4; ++reg) {
        int row = row0 + q * 4 + reg;
        if (row < N) {
            float sc = scale[row];
            #pragma unroll
            for (int ct = 0; ct < 4; ++ct)
                out[(long)row * FEAT + ct * 16 + m] = f2bf(acc[ct][reg] * sc);
        }
    }
}

__global__ __launch_bounds__(256) void k_gemm2(const float* __restrict__ h,
                                               const float* __restrict__ W,
                                               const float* __restrict__ scale,
                                               unsigned short* __restrict__ out, int N) {
    __shared__ short wf[4 * 2 * 64 * 8];   // 8 KB
    const int tid = threadIdx.x;
    for (int i = tid; i < FEAT * FEAT; i += 256) {
        int k = i >> 6, n = i & 63;
        int ct = n >> 4, kc = k >> 5, r = k & 31;
        int owner = ((r >> 3) << 4) | (n & 15);
        wf[(((ct << 1) | kc) * 64 + owner) * 8 + (r & 7)] = (short)f2bf(W[i]);
    }
    __syncthreads();

    const int lane = tid & 63;
    const int m = lane & 15, q = lane >> 4;
    const int row0 = blockIdx.x * 64 + (tid >> 6) * 16;

    short8 bfr[4][2];
    #pragma unroll
    for (int ct = 0; ct < 4; ++ct)
        #pragma unroll
        for (int kc = 0; kc < 2; ++kc)
            bfr[ct][kc] = *reinterpret_cast<const short8*>(&wf[(((ct << 1) | kc) * 64 + lane) * 8]);

    int gr = row0 + m;
    int rl = gr < N ? gr : (N - 1);
    const float* hp = h + (long)rl * FEAT + q * 8;

    f32x4 acc[4] = {{0,0,0,0},{0,0,0,0},{0,0,0,0},{0,0,0,0}};
    #pragma unroll
    for (int kc = 0; kc < 2; ++kc) {
        float4 v0 = *reinterpret_cast<const float4*>(hp + kc * 32);
        float4 v1 = *reinterpret_cast<const float4*>(hp + kc * 32 + 4);
        short8 a;
        a[0]=(short)f2bf(v0.x); a[1]=(short)f2bf(v0.y); a[2]=(short)f2bf(v0.z); a[3]=(short)f2bf(v0.w);
        a[4]=(short)f2bf(v1.x); a[5]=(short)f2bf(v1.y); a[6]=(short)f2bf(v1.z); a[7]=(short)f2bf(v1.w);
        #pragma unroll
        for (int ct = 0; ct < 4; ++ct)
            acc[ct] = __builtin_amdgcn_mfma_f32_16x16x32_bf16(a, bfr[ct][kc], acc[ct], 0, 0, 0);
    }

    #pragma unroll
    for (int reg = 0; reg < 4; ++reg) {
        int row = row0 + q * 4 + reg;
        if (row < N) {
            float sc = scale[row];
            #pragma unroll
            for (int ct = 0; ct < 4; ++ct)
                out[(long)row * FEAT + ct * 16 + m] = f2bf(acc[ct][reg] * sc);
        }
    }
}

// ==================== pull aggregation: widened gather ====================
// lane = 16*q + fl; lane loads 8B (features 4fl..4fl+3) of quarter q's edge.
// One wave-instruction gathers 4 edges (512B). Quarters hold independent
// partial sums (float4); combined via shfl_xor(16), shfl_xor(32). Self row
// initialized by quarter 0 only. 8 edges in flight per iteration.

__global__ __launch_bounds__(256) void k_agg1(const unsigned short* __restrict__ A,
                                              const int* __restrict__ rp,
                                              const int* __restrict__ col,
                                              const float* __restrict__ dis,
                                              const float* __restrict__ bias,
                                              float* __restrict__ H, int N) {
    int i = blockIdx.x * 4 + (threadIdx.x >> 6);
    if (i >= N) return;
    const int lane = threadIdx.x & 63;
    const int q  = lane >> 4;
    const int fl = lane & 15;
    const int jb = rp[i], je = rp[i + 1];

    float a0 = 0.f, a1 = 0.f, a2 = 0.f, a3 = 0.f;
    if (q == 0) {
        uint2 rv = *reinterpret_cast<const uint2*>(A + (long)i * FEAT + 4 * fl);
        a0 = bf2f((unsigned short)rv.x); a1 = bf2f((unsigned short)(rv.x >> 16));
        a2 = bf2f((unsigned short)rv.y); a3 = bf2f((unsigned short)(rv.y >> 16));
    }
    for (int j0 = jb; j0 < je; j0 += 8) {
        int ja = j0 + q, jb2 = j0 + 4 + q;
        int ca = (ja  < je) ? col[ja]  : i;  float ma = (ja  < je) ? 1.f : 0.f;
        int cb = (jb2 < je) ? col[jb2] : i;  float mb = (jb2 < je) ? 1.f : 0.f;
        uint2 ra = *reinterpret_cast<const uint2*>(A + (long)ca * FEAT + 4 * fl);
        uint2 rb = *reinterpret_cast<const uint2*>(A + (long)cb * FEAT + 4 * fl);
        a0 = fmaf(ma, bf2f((unsigned short)ra.x),         a0);
        a1 = fmaf(ma, bf2f((unsigned short)(ra.x >> 16)), a1);
        a2 = fmaf(ma, bf2f((unsigned short)ra.y),         a2);
        a3 = fmaf(ma, bf2f((unsigned short)(ra.y >> 16)), a3);
        a0 = fmaf(mb, bf2f((unsigned short)rb.x),         a0);
        a1 = fmaf(mb, bf2f((unsigned short)(rb.x >> 16)), a1);
        a2 = fmaf(mb, bf2f((unsigned short)rb.y),         a2);
        a3 = fmaf(mb, bf2f((unsigned short)(rb.y >> 16)), a3);
    }
    a0 += __shfl_xor(a0, 16); a1 += __shfl_xor(a1, 16);
    a2 += __shfl_xor(a2, 16); a3 += __shfl_xor(a3, 16);
    a0 += __shfl_xor(a0, 32); a1 += __shfl_xor(a1, 32);
    a2 += __shfl_xor(a2, 32); a3 += __shfl_xor(a3, 32);

    if (q == 0) {
        float di = dis[i];
        float4 b4 = *reinterpret_cast<const float4*>(bias + 4 * fl);
        float4 o;
        o.x = fmaxf(fmaf(di, a0, b4.x), 0.f);
        o.y = fmaxf(fmaf(di, a1, b4.y), 0.f);
        o.z = fmaxf(fmaf(di, a2, b4.z), 0.f);
        o.w = fmaxf(fmaf(di, a3, b4.w), 0.f);
        *reinterpret_cast<float4*>(H + (long)i * FEAT + 4 * fl) = o;
    }
}

__global__ __launch_bounds__(256) void k_agg2s(const unsigned short* __restrict__ A,
                                               const int* __restrict__ rp,
                                               const int* __restrict__ col,
                                               const float* __restrict__ dis,
                                               const float* __restrict__ bias,
                                               const int* __restrict__ uidx,
                                               float* __restrict__ S, int N) {
    int i = blockIdx.x * 4 + (threadIdx.x >> 6);
    if (i >= N) return;
    const int lane = threadIdx.x & 63;
    const int q  = lane >> 4;
    const int fl = lane & 15;
    const int jb = rp[i], je = rp[i + 1];
    const float bv = bias[4 * fl + q];      // hoisted

    float a0 = 0.f, a1 = 0.f, a2 = 0.f, a3 = 0.f;
    if (q == 0) {
        uint2 rv = *reinterpret_cast<const uint2*>(A + (long)i * FEAT + 4 * fl);
        a0 = bf2f((unsigned short)rv.x); a1 = bf2f((unsigned short)(rv.x >> 16));
        a2 = bf2f((unsigned short)rv.y); a3 = bf2f((unsigned short)(rv.y >> 16));
    }
    for (int j0 = jb; j0 < je; j0 += 8) {
        int ja = j0 + q, jb2 = j0 + 4 + q;
        int ca = (ja  < je) ? col[ja]  : i;  float ma = (ja  < je) ? 1.f : 0.f;
        int cb = (jb2 < je) ? col[jb2] : i;  float mb = (jb2 < je) ? 1.f : 0.f;
        uint2 ra = *reinterpret_cast<const uint2*>(A + (long)ca * FEAT + 4 * fl);
        uint2 rb = *reinterpret_cast<const uint2*>(A + (long)cb * FEAT + 4 * fl);
        a0 = fmaf(ma, bf2f((unsigned short)ra.x),         a0);
        a1 = fmaf(ma, bf2f((unsigned short)(ra.x >> 16)), a1);
        a2 = fmaf(ma, bf2f((unsigned short)ra.y),         a2);
        a3 = fmaf(ma, bf2f((unsigned short)(ra.y >> 16)), a3);
        a0 = fmaf(mb, bf2f((unsigned short)rb.x),         a0);
        a1 = fmaf(mb, bf2f((unsigned short)(rb.x >> 16)), a1);
        a2 = fmaf(mb, bf2f((unsigned short)rb.y),         a2);
        a3 = fmaf(mb, bf2f((unsigned short)(rb.y >> 16)), a3);
    }
    a0 += __shfl_xor(a0, 16); a1 += __shfl_xor(a1, 16);
    a2 += __shfl_xor(a2, 16); a3 += __shfl_xor(a3, 16);
    a0 += __shfl_xor(a0, 32); a1 += __shfl_xor(a1, 32);
    a2 += __shfl_xor(a2, 32); a3 += __shfl_xor(a3, 32);

    int u = uidx[i];
    if ((unsigned)u < (unsigned)N) {
        float di = dis[i];
        float v = (q == 0) ? a0 : (q == 1) ? a1 : (q == 2) ? a2 : a3;
        atomicAdd(&S[(long)u * FEAT + 4 * fl + q], fmaf(di, v, bv));
    }
}

__global__ __launch_bounds__(256) void k_final(float* __restrict__ S,
                                               const float* __restrict__ cnt, int N) {
    long idx = (long)blockIdx.x * 256 + threadIdx.x;
    if (idx >= (long)N * FEAT) return;
    int i = (int)(idx >> 6);
    float c = cnt[i];
    S[idx] = (c > 0.f) ? S[idx] / c : 0.f;
}

extern "C" void kernel_launch(void* const* d_in, const int* in_sizes, int n_in,
                              void* d_out, int out_size, void* d_ws, size_t ws_size,
                              hipStream_t stream) {
    const float* x   = (const float*)d_in[0];
    const int* edge  = (const int*)d_in[1];
    const int* uidx  = (const int*)d_in[2];
    const float* W1  = (const float*)d_in[3];
    const float* b1  = (const float*)d_in[4];
    const float* W2  = (const float*)d_in[5];
    const float* b2  = (const float*)d_in[6];
    float* out       = (float*)d_out;

    const int N = in_sizes[2];       // 100000
    const int E = in_sizes[1] / 2;   // 1600000
    const int* src = edge;
    const int* dst = edge + E;

    const size_t fbuf = (size_t)N * FEAT * sizeof(float);          // 25.6 MB
    const size_t abuf = (size_t)N * FEAT * sizeof(unsigned short); // 12.8 MB
    const long NF = (long)N * FEAT;
    const int gNF = (int)((NF + 255) / 256);
    const int gE  = (E + 255) / 256;
    const int gN  = (N + 255) / 256;
    const int gN4 = (N + 3) / 4;
    const int gG  = (N + 63) / 64;
    const int nbScan = (N + SCAN_CHUNK - 1) / SCAN_CHUNK;
    const int KB = (N + BIN_R - 1) >> BIN_SHIFT;

    auto align256 = [](size_t v) { return (v + 255) & ~(size_t)255; };

    char* w = (char*)d_ws;
    size_t o = 0;
    float* dis  = (float*)(w + o); o = align256(o + (size_t)N * 4);
    float* cntf = (float*)(w + o); o = align256(o + (size_t)N * 4);
    int*   rp   = (int*)  (w + o); o = align256(o + (size_t)(N + 1) * 4);
    int*   cntE = (int*)  (w + o); o = align256(o + (size_t)N * 4);
    int*   ptot = (int*)  (w + o); o = align256(o + (size_t)1024 * 4);
    int*   poff = (int*)  (w + o); o = align256(o + (size_t)1024 * 4);
    int*   col  = (int*)  (w + o); o = align256(o + (size_t)E * 4);
    size_t apsz = (size_t)E * sizeof(int2) > abuf ? (size_t)E * sizeof(int2) : abuf;
    char*  Ap   = w + o;           o = align256(o + apsz);
    const size_t need = o;
    int* bcur = ptot;
    int2* pairs = (int2*)Ap;
    unsigned short* A = (unsigned short*)Ap;

    if (ws_size >= need && nbScan <= 1024 && KB <= 256) {
        hipMemsetAsync(cntE, 0, (size_t)N * 4, stream);
        k_hist <<<gE, 256, 0, stream>>>(dst, cntE, E, N);
        k_dis  <<<gN, 256, 0, stream>>>(cntE, dis, N);
        k_scan1<<<nbScan, SCAN_BS, 0, stream>>>(cntE, rp, ptot, N);
        k_scan2<<<1, 1024, 0, stream>>>(ptot, poff, rp + N, nbScan);
        k_scan3<<<nbScan, SCAN_BS, 0, stream>>>(rp, poff, N);
        k_bcur <<<1, 256, 0, stream>>>(rp, bcur, KB, N);
        k_binA <<<(E + BIN_TILE - 1) / BIN_TILE, 256, 0, stream>>>(src, dst, bcur, pairs, E, N, KB);
        k_binB <<<KB, 256, 0, stream>>>(pairs, rp, col, N);
        hipMemsetAsync(cntf, 0, (size_t)N * 4, stream);
        k_ucnt <<<gN, 256, 0, stream>>>(uidx, cntf, N);

        k_gemm1<<<gG, 256, 0, stream>>>(x, W1, dis, A, N);
        k_agg1 <<<gN4, 256, 0, stream>>>(A, rp, col, dis, b1, out, N);

        k_gemm2<<<gG, 256, 0, stream>>>(out, W2, dis, A, N);
        hipMemsetAsync(out, 0, fbuf, stream);
        k_agg2s<<<gN4, 256, 0, stream>>>(A, rp, col, dis, b2, uidx, out, N);
        k_final<<<gNF, 256, 0, stream>>>(out, cntf, N);
    } else {
        hipMemsetAsync(cntE, 0, (size_t)N * 4, stream);
        k_hist <<<gE, 256, 0, stream>>>(dst, cntE, E, N);
        k_dis  <<<gN, 256, 0, stream>>>(cntE, dis, N);
        k_scan1<<<nbScan, SCAN_BS, 0, stream>>>(cntE, rp, ptot, N);
        k_scan2<<<1, 1024, 0, stream>>>(ptot, poff, rp + N, nbScan);
        k_scan3<<<nbScan, SCAN_BS, 0, stream>>>(rp, poff, N);
        hipMemsetAsync(cntE, 0, (size_t)N * 4, stream);
        k_fill <<<gE, 256, 0, stream>>>(src, dst, rp, cntE, col, E, N);
        hipMemsetAsync(cntf, 0, (size_t)N * 4, stream);
        k_ucnt <<<gN, 256, 0, stream>>>(uidx, cntf, N);
        k_gemm1<<<gG, 256, 0, stream>>>(x, W1, dis, A, N);
        k_agg1 <<<gN4, 256, 0, stream>>>(A, rp, col, dis, b1, out, N);
        k_gemm2<<<gG, 256, 0, stream>>>(out, W2, dis, A, N);
        hipMemsetAsync(out, 0, fbuf, stream);
        k_agg2s<<<gN4, 256, 0, stream>>>(A, rp, col, dis, b2, uidx, out, N);
        k_final<<<gNF, 256, 0, stream>>>(out, cntf, N);
    }
}

// Round 11
// 319.747 us; speedup vs baseline: 3.3267x; 1.1844x over previous
//
#include <hip/hip_runtime.h>
#include <hip/hip_bf16.h>

// GCN: h1 = relu(GCNConv(x, W1, b1)); out = scatter_mean(GCNConv(h1, W2, b2), user_idx)
// N=100000, E=1600000, dims 128 -> 64 -> 64. fp32 I/O, int32 indices.
//
// R10 profile: k_hist 66us -- 1.6M random int atomics, WRITE=E*32B, VALU 0.4%.
// R11: eliminate the N-wide histogram. k_bhist does a 196-bucket LDS histogram
// (77K global atomics total); k_bscan scans buckets; k_binA unchanged (cursors
// from bucket bases); k_binB2 counts per-node degrees in LDS from the bucket's
// dense pairs run, block-scans to emit rp+dis, then rank-scatters col.
// Deletes k_hist/k_dis/k_scan1/2/3/k_bcur.

#define FEAT 64
#define INDIM 128

#define SCAN_BS 256
#define SCAN_ELEMS 8
#define SCAN_CHUNK (SCAN_BS * SCAN_ELEMS)

#define BIN_SHIFT 9
#define BIN_R 512
#define BIN_TILE 4096
#define BH_TILE 8192

typedef __attribute__((ext_vector_type(8))) short short8;
typedef __attribute__((ext_vector_type(4))) float f32x4;

__device__ __forceinline__ unsigned short f2bf(float f) {
    unsigned u = __float_as_uint(f);
    unsigned r = u + 0x7FFFu + ((u >> 16) & 1u);
    return (unsigned short)(r >> 16);
}
__device__ __forceinline__ float bf2f(unsigned short v) {
    return __uint_as_float(((unsigned)v) << 16);
}

// ==================== bucket-level CSR build ====================

// per-block LDS histogram over KB (<=256) buckets
__global__ __launch_bounds__(256) void k_bhist(const int* __restrict__ dst,
                                               int* __restrict__ gbc, int E, int N, int KB) {
    __shared__ int h[256];
    const int tid = threadIdx.x;
    h[tid] = 0;
    __syncthreads();
    const int base = blockIdx.x * BH_TILE;
    #pragma unroll
    for (int t = 0; t < BH_TILE / 256; ++t) {
        int e = base + t * 256 + tid;
        if (e < E) {
            int d = dst[e];
            if ((unsigned)d < (unsigned)N) atomicAdd(&h[d >> BIN_SHIFT], 1);
        }
    }
    __syncthreads();
    if (tid < KB && h[tid]) atomicAdd(&gbc[tid], h[tid]);
}

// single block: exclusive scan of gbc[KB] -> bb[0..KB]; init bcur; rp[N]=total
__global__ __launch_bounds__(256) void k_bscan(const int* __restrict__ gbc,
                                               int* __restrict__ bb,
                                               int* __restrict__ bcur,
                                               int* __restrict__ rpN, int KB) {
    __shared__ int lds[256];
    const int tid = threadIdx.x;
    int v = (tid < KB) ? gbc[tid] : 0;
    lds[tid] = v;
    __syncthreads();
    for (int d = 1; d < 256; d <<= 1) {
        int t = (tid >= d) ? lds[tid - d] : 0;
        __syncthreads();
        lds[tid] += t;
        __syncthreads();
    }
    int excl = lds[tid] - v;
    if (tid < KB) { bb[tid] = excl; bcur[tid] = excl; }
    if (tid == 255) { bb[KB] = lds[255]; *rpN = lds[255]; }
}

// tile-reorder edges by bucket, flush coalesced runs into pairs[] (cursor-based)
__global__ __launch_bounds__(256) void k_binA(const int* __restrict__ src,
                                              const int* __restrict__ dst,
                                              int* __restrict__ bcur,
                                              int2* __restrict__ pairs,
                                              int E, int N, int KB) {
    __shared__ int2 lbuf[BIN_TILE];
    __shared__ unsigned short bkt[BIN_TILE];
    __shared__ int lcnt[256];
    __shared__ int loff[256];
    __shared__ int lbase[256];
    __shared__ int tot;
    const int tid = threadIdx.x;
    const int base = blockIdx.x * BIN_TILE;

    lcnt[tid] = 0;
    __syncthreads();

    int mys[16], myd[16], myb[16];
    #pragma unroll
    for (int t = 0; t < 16; ++t) {
        int e = base + t * 256 + tid;
        int s = 0, d = -1;
        if (e < E) { s = src[e]; d = dst[e]; }
        if ((unsigned)d >= (unsigned)N) d = -1;
        if ((unsigned)s >= (unsigned)N) s = 0;
        mys[t] = s; myd[t] = d;
        myb[t] = (d >= 0) ? (d >> BIN_SHIFT) : -1;
        if (myb[t] >= 0) atomicAdd(&lcnt[myb[t]], 1);
    }
    __syncthreads();

    int v = lcnt[tid];
    loff[tid] = v;
    __syncthreads();
    for (int d = 1; d < 256; d <<= 1) {
        int t2 = (tid >= d) ? loff[tid - d] : 0;
        __syncthreads();
        loff[tid] += t2;
        __syncthreads();
    }
    if (tid == 255) tot = loff[255];
    int excl = loff[tid] - v;
    __syncthreads();
    loff[tid] = excl;
    lcnt[tid] = excl;
    if (tid < KB && v > 0) lbase[tid] = atomicAdd(&bcur[tid], v);
    __syncthreads();

    #pragma unroll
    for (int t = 0; t < 16; ++t) {
        if (myb[t] >= 0) {
            int pos = atomicAdd(&lcnt[myb[t]], 1);
            lbuf[pos] = make_int2(mys[t], myd[t]);
            bkt[pos] = (unsigned short)myb[t];
        }
    }
    __syncthreads();

    const int T = tot;
    for (int i = tid; i < T; i += 256) {
        int b = bkt[i];
        pairs[lbase[b] + (i - loff[b])] = lbuf[i];
    }
}

// one WG per bucket: count degrees in LDS, scan -> rp + dis, then rank -> col
__global__ __launch_bounds__(256) void k_binB2(const int2* __restrict__ pairs,
                                               const int* __restrict__ bb,
                                               int* __restrict__ rp,
                                               int* __restrict__ col,
                                               float* __restrict__ dis, int N) {
    __shared__ int cnt[BIN_R];
    __shared__ int cur[BIN_R];
    __shared__ int ssum[256];
    const int tid = threadIdx.x;
    const int b = blockIdx.x;
    const int n0 = b << BIN_SHIFT;
    const int n1 = min(n0 + BIN_R, N);
    const int nn = n1 - n0;
    const int e0 = bb[b];
    const int e1 = bb[b + 1];

    for (int i = tid; i < nn; i += 256) cnt[i] = 0;
    __syncthreads();
    for (int i = e0 + tid; i < e1; i += 256) {
        int2 p = pairs[i];
        atomicAdd(&cnt[p.y - n0], 1);
    }
    __syncthreads();

    // exclusive scan over nn (<=512) counters: 2 elems/thread + block scan
    const int i0 = 2 * tid;
    int c0 = (i0     < nn) ? cnt[i0]     : 0;
    int c1 = (i0 + 1 < nn) ? cnt[i0 + 1] : 0;
    ssum[tid] = c0 + c1;
    __syncthreads();
    for (int d = 1; d < 256; d <<= 1) {
        int t = (tid >= d) ? ssum[tid - d] : 0;
        __syncthreads();
        ssum[tid] += t;
        __syncthreads();
    }
    int excl = ssum[tid] - (c0 + c1);
    if (i0 < nn) {
        cur[i0] = e0 + excl;
        rp[n0 + i0] = e0 + excl;
        dis[n0 + i0] = rsqrtf((float)c0 + 1.0f);
    }
    if (i0 + 1 < nn) {
        cur[i0 + 1] = e0 + excl + c0;
        rp[n0 + i0 + 1] = e0 + excl + c0;
        dis[n0 + i0 + 1] = rsqrtf((float)c1 + 1.0f);
    }
    __syncthreads();

    for (int i = e0 + tid; i < e1; i += 256) {
        int2 p = pairs[i];
        int pos = atomicAdd(&cur[p.y - n0], 1);
        col[pos] = p.x;     // dense within bucket region
    }
}

// ==================== fallback CSR build (proven path) ====================

__global__ __launch_bounds__(256) void k_hist(const int* __restrict__ dst,
                                              int* __restrict__ cntE, int E, int N) {
    int e = blockIdx.x * 256 + threadIdx.x;
    if (e < E) {
        int d = dst[e];
        if ((unsigned)d < (unsigned)N) atomicAdd(&cntE[d], 1);
    }
}
__global__ __launch_bounds__(256) void k_dis(const int* __restrict__ cntE,
                                             float* __restrict__ dis, int N) {
    int i = blockIdx.x * 256 + threadIdx.x;
    if (i < N) dis[i] = rsqrtf((float)cntE[i] + 1.0f);
}
__global__ __launch_bounds__(SCAN_BS) void k_scan1(const int* __restrict__ c,
                                                   int* __restrict__ rp,
                                                   int* __restrict__ ptot, int N) {
    __shared__ int lds[SCAN_BS];
    const int base = blockIdx.x * SCAN_CHUNK;
    const int tb = base + threadIdx.x * SCAN_ELEMS;
    int vals[SCAN_ELEMS];
    int s = 0;
    #pragma unroll
    for (int k = 0; k < SCAN_ELEMS; ++k) {
        int idx = tb + k;
        int v = (idx < N) ? c[idx] : 0;
        vals[k] = s;
        s += v;
    }
    lds[threadIdx.x] = s;
    __syncthreads();
    for (int d = 1; d < SCAN_BS; d <<= 1) {
        int v = (threadIdx.x >= d) ? lds[threadIdx.x - d] : 0;
        __syncthreads();
        lds[threadIdx.x] += v;
        __syncthreads();
    }
    int toff = (threadIdx.x == 0) ? 0 : lds[threadIdx.x - 1];
    #pragma unroll
    for (int k = 0; k < SCAN_ELEMS; ++k) {
        int idx = tb + k;
        if (idx < N) rp[idx] = toff + vals[k];
    }
    if (threadIdx.x == SCAN_BS - 1) ptot[blockIdx.x] = lds[SCAN_BS - 1];
}
__global__ __launch_bounds__(1024) void k_scan2(int* __restrict__ ptot,
                                                int* __restrict__ poff,
                                                int* __restrict__ rpN, int nb) {
    __shared__ int lds[1024];
    int tid = threadIdx.x;
    lds[tid] = (tid < nb) ? ptot[tid] : 0;
    __syncthreads();
    for (int d = 1; d < 1024; d <<= 1) {
        int v = (tid >= d) ? lds[tid - d] : 0;
        __syncthreads();
        lds[tid] += v;
        __syncthreads();
    }
    if (tid < nb) poff[tid] = (tid == 0) ? 0 : lds[tid - 1];
    if (tid == nb - 1) *rpN = lds[tid];
}
__global__ __launch_bounds__(SCAN_BS) void k_scan3(int* __restrict__ rp,
                                                   const int* __restrict__ poff, int N) {
    int off = poff[blockIdx.x];
    const int tb = blockIdx.x * SCAN_CHUNK + threadIdx.x * SCAN_ELEMS;
    #pragma unroll
    for (int k = 0; k < SCAN_ELEMS; ++k) {
        int idx = tb + k;
        if (idx < N) rp[idx] += off;
    }
}
__global__ __launch_bounds__(256) void k_fill(const int* __restrict__ src,
                                              const int* __restrict__ dst,
                                              const int* __restrict__ rp,
                                              int* __restrict__ tmp,
                                              int* __restrict__ col, int E, int N) {
    int e = blockIdx.x * 256 + threadIdx.x;
    if (e >= E) return;
    int s = src[e], d = dst[e];
    if ((unsigned)s >= (unsigned)N) s = 0;
    if ((unsigned)d >= (unsigned)N) return;
    int r = atomicAdd(&tmp[d], 1);
    col[rp[d] + r] = s;
}

__global__ __launch_bounds__(256) void k_ucnt(const int* __restrict__ uidx,
                                              float* __restrict__ cntf, int N) {
    int i = blockIdx.x * 256 + threadIdx.x;
    if (i < N) {
        int u = uidx[i];
        if ((unsigned)u < (unsigned)N) atomicAdd(&cntf[u], 1.0f);
    }
}

// ==================== MFMA GEMMs (16x16x32 bf16, verified layouts) ====================

__global__ __launch_bounds__(256) void k_gemm1(const float* __restrict__ x,
                                               const float* __restrict__ W,
                                               const float* __restrict__ scale,
                                               unsigned short* __restrict__ out, int N) {
    __shared__ short wf[4 * 4 * 64 * 8];
    const int tid = threadIdx.x;
    for (int i = tid; i < INDIM * FEAT; i += 256) {
        int k = i >> 6, n = i & 63;
        int ct = n >> 4, kc = k >> 5, r = k & 31;
        int owner = ((r >> 3) << 4) | (n & 15);
        wf[(((ct << 2) | kc) * 64 + owner) * 8 + (r & 7)] = (short)f2bf(W[i]);
    }
    __syncthreads();

    const int lane = tid & 63;
    const int m = lane & 15, q = lane >> 4;
    const int row0 = blockIdx.x * 64 + (tid >> 6) * 16;

    short8 bfr[4][4];
    #pragma unroll
    for (int ct = 0; ct < 4; ++ct)
        #pragma unroll
        for (int kc = 0; kc < 4; ++kc)
            bfr[ct][kc] = *reinterpret_cast<const short8*>(&wf[(((ct << 2) | kc) * 64 + lane) * 8]);

    int gr = row0 + m;
    int rl = gr < N ? gr : (N - 1);
    const float* xp = x + (long)rl * INDIM + q * 8;

    f32x4 acc[4] = {{0,0,0,0},{0,0,0,0},{0,0,0,0},{0,0,0,0}};
    #pragma unroll
    for (int kc = 0; kc < 4; ++kc) {
        float4 v0 = *reinterpret_cast<const float4*>(xp + kc * 32);
        float4 v1 = *reinterpret_cast<const float4*>(xp + kc * 32 + 4);
        short8 a;
        a[0]=(short)f2bf(v0.x); a[1]=(short)f2bf(v0.y); a[2]=(short)f2bf(v0.z); a[3]=(short)f2bf(v0.w);
        a[4]=(short)f2bf(v1.x); a[5]=(short)f2bf(v1.y); a[6]=(short)f2bf(v1.z); a[7]=(short)f2bf(v1.w);
        #pragma unroll
        for (int ct = 0; ct < 4; ++ct)
            acc[ct] = __builtin_amdgcn_mfma_f32_16x16x32_bf16(a, bfr[ct][kc], acc[ct], 0, 0, 0);
    }

    #pragma unroll
    for (int reg = 0; reg < 4; ++reg) {
        int row = row0 + q * 4 + reg;
        if (row < N) {
            float sc = scale[row];
            #pragma unroll
            for (int ct = 0; ct < 4; ++ct)
                out[(long)row * FEAT + ct * 16 + m] = f2bf(acc[ct][reg] * sc);
        }
    }
}

__global__ __launch_bounds__(256) void k_gemm2(const float* __restrict__ h,
                                               const float* __restrict__ W,
                                               const float* __restrict__ scale,
                                               unsigned short* __restrict__ out, int N) {
    __shared__ short wf[4 * 2 * 64 * 8];
    const int tid = threadIdx.x;
    for (int i = tid; i < FEAT * FEAT; i += 256) {
        int k = i >> 6, n = i & 63;
        int ct = n >> 4, kc = k >> 5, r = k & 31;
        int owner = ((r >> 3) << 4) | (n & 15);
        wf[(((ct << 1) | kc) * 64 + owner) * 8 + (r & 7)] = (short)f2bf(W[i]);
    }
    __syncthreads();

    const int lane = tid & 63;
    const int m = lane & 15, q = lane >> 4;
    const int row0 = blockIdx.x * 64 + (tid >> 6) * 16;

    short8 bfr[4][2];
    #pragma unroll
    for (int ct = 0; ct < 4; ++ct)
        #pragma unroll
        for (int kc = 0; kc < 2; ++kc)
            bfr[ct][kc] = *reinterpret_cast<const short8*>(&wf[(((ct << 1) | kc) * 64 + lane) * 8]);

    int gr = row0 + m;
    int rl = gr < N ? gr : (N - 1);
    const float* hp = h + (long)rl * FEAT + q * 8;

    f32x4 acc[4] = {{0,0,0,0},{0,0,0,0},{0,0,0,0},{0,0,0,0}};
    #pragma unroll
    for (int kc = 0; kc < 2; ++kc) {
        float4 v0 = *reinterpret_cast<const float4*>(hp + kc * 32);
        float4 v1 = *reinterpret_cast<const float4*>(hp + kc * 32 + 4);
        short8 a;
        a[0]=(short)f2bf(v0.x); a[1]=(short)f2bf(v0.y); a[2]=(short)f2bf(v0.z); a[3]=(short)f2bf(v0.w);
        a[4]=(short)f2bf(v1.x); a[5]=(short)f2bf(v1.y); a[6]=(short)f2bf(v1.z); a[7]=(short)f2bf(v1.w);
        #pragma unroll
        for (int ct = 0; ct < 4; ++ct)
            acc[ct] = __builtin_amdgcn_mfma_f32_16x16x32_bf16(a, bfr[ct][kc], acc[ct], 0, 0, 0);
    }

    #pragma unroll
    for (int reg = 0; reg < 4; ++reg) {
        int row = row0 + q * 4 + reg;
        if (row < N) {
            float sc = scale[row];
            #pragma unroll
            for (int ct = 0; ct < 4; ++ct)
                out[(long)row * FEAT + ct * 16 + m] = f2bf(acc[ct][reg] * sc);
        }
    }
}

// ==================== pull aggregation: widened gather ====================

__global__ __launch_bounds__(256) void k_agg1(const unsigned short* __restrict__ A,
                                              const int* __restrict__ rp,
                                              const int* __restrict__ col,
                                              const float* __restrict__ dis,
                                              const float* __restrict__ bias,
                                              float* __restrict__ H, int N) {
    int i = blockIdx.x * 4 + (threadIdx.x >> 6);
    if (i >= N) return;
    const int lane = threadIdx.x & 63;
    const int q  = lane >> 4;
    const int fl = lane & 15;
    const int jb = rp[i], je = rp[i + 1];

    float a0 = 0.f, a1 = 0.f, a2 = 0.f, a3 = 0.f;
    if (q == 0) {
        uint2 rv = *reinterpret_cast<const uint2*>(A + (long)i * FEAT + 4 * fl);
        a0 = bf2f((unsigned short)rv.x); a1 = bf2f((unsigned short)(rv.x >> 16));
        a2 = bf2f((unsigned short)rv.y); a3 = bf2f((unsigned short)(rv.y >> 16));
    }
    for (int j0 = jb; j0 < je; j0 += 8) {
        int ja = j0 + q, jb2 = j0 + 4 + q;
        int ca = (ja  < je) ? col[ja]  : i;  float ma = (ja  < je) ? 1.f : 0.f;
        int cb = (jb2 < je) ? col[jb2] : i;  float mb = (jb2 < je) ? 1.f : 0.f;
        uint2 ra = *reinterpret_cast<const uint2*>(A + (long)ca * FEAT + 4 * fl);
        uint2 rb = *reinterpret_cast<const uint2*>(A + (long)cb * FEAT + 4 * fl);
        a0 = fmaf(ma, bf2f((unsigned short)ra.x),         a0);
        a1 = fmaf(ma, bf2f((unsigned short)(ra.x >> 16)), a1);
        a2 = fmaf(ma, bf2f((unsigned short)ra.y),         a2);
        a3 = fmaf(ma, bf2f((unsigned short)(ra.y >> 16)), a3);
        a0 = fmaf(mb, bf2f((unsigned short)rb.x),         a0);
        a1 = fmaf(mb, bf2f((unsigned short)(rb.x >> 16)), a1);
        a2 = fmaf(mb, bf2f((unsigned short)rb.y),         a2);
        a3 = fmaf(mb, bf2f((unsigned short)(rb.y >> 16)), a3);
    }
    a0 += __shfl_xor(a0, 16); a1 += __shfl_xor(a1, 16);
    a2 += __shfl_xor(a2, 16); a3 += __shfl_xor(a3, 16);
    a0 += __shfl_xor(a0, 32); a1 += __shfl_xor(a1, 32);
    a2 += __shfl_xor(a2, 32); a3 += __shfl_xor(a3, 32);

    if (q == 0) {
        float di = dis[i];
        float4 b4 = *reinterpret_cast<const float4*>(bias + 4 * fl);
        float4 o;
        o.x = fmaxf(fmaf(di, a0, b4.x), 0.f);
        o.y = fmaxf(fmaf(di, a1, b4.y), 0.f);
        o.z = fmaxf(fmaf(di, a2, b4.z), 0.f);
        o.w = fmaxf(fmaf(di, a3, b4.w), 0.f);
        *reinterpret_cast<float4*>(H + (long)i * FEAT + 4 * fl) = o;
    }
}

__global__ __launch_bounds__(256) void k_agg2s(const unsigned short* __restrict__ A,
                                               const int* __restrict__ rp,
                                               const int* __restrict__ col,
                                               const float* __restrict__ dis,
                                               const float* __restrict__ bias,
                                               const int* __restrict__ uidx,
                                               float* __restrict__ S, int N) {
    int i = blockIdx.x * 4 + (threadIdx.x >> 6);
    if (i >= N) return;
    const int lane = threadIdx.x & 63;
    const int q  = lane >> 4;
    const int fl = lane & 15;
    const int jb = rp[i], je = rp[i + 1];
    const float bv = bias[4 * fl + q];

    float a0 = 0.f, a1 = 0.f, a2 = 0.f, a3 = 0.f;
    if (q == 0) {
        uint2 rv = *reinterpret_cast<const uint2*>(A + (long)i * FEAT + 4 * fl);
        a0 = bf2f((unsigned short)rv.x); a1 = bf2f((unsigned short)(rv.x >> 16));
        a2 = bf2f((unsigned short)rv.y); a3 = bf2f((unsigned short)(rv.y >> 16));
    }
    for (int j0 = jb; j0 < je; j0 += 8) {
        int ja = j0 + q, jb2 = j0 + 4 + q;
        int ca = (ja  < je) ? col[ja]  : i;  float ma = (ja  < je) ? 1.f : 0.f;
        int cb = (jb2 < je) ? col[jb2] : i;  float mb = (jb2 < je) ? 1.f : 0.f;
        uint2 ra = *reinterpret_cast<const uint2*>(A + (long)ca * FEAT + 4 * fl);
        uint2 rb = *reinterpret_cast<const uint2*>(A + (long)cb * FEAT + 4 * fl);
        a0 = fmaf(ma, bf2f((unsigned short)ra.x),         a0);
        a1 = fmaf(ma, bf2f((unsigned short)(ra.x >> 16)), a1);
        a2 = fmaf(ma, bf2f((unsigned short)ra.y),         a2);
        a3 = fmaf(ma, bf2f((unsigned short)(ra.y >> 16)), a3);
        a0 = fmaf(mb, bf2f((unsigned short)rb.x),         a0);
        a1 = fmaf(mb, bf2f((unsigned short)(rb.x >> 16)), a1);
        a2 = fmaf(mb, bf2f((unsigned short)rb.y),         a2);
        a3 = fmaf(mb, bf2f((unsigned short)(rb.y >> 16)), a3);
    }
    a0 += __shfl_xor(a0, 16); a1 += __shfl_xor(a1, 16);
    a2 += __shfl_xor(a2, 16); a3 += __shfl_xor(a3, 16);
    a0 += __shfl_xor(a0, 32); a1 += __shfl_xor(a1, 32);
    a2 += __shfl_xor(a2, 32); a3 += __shfl_xor(a3, 32);

    int u = uidx[i];
    if ((unsigned)u < (unsigned)N) {
        float di = dis[i];
        float v = (q == 0) ? a0 : (q == 1) ? a1 : (q == 2) ? a2 : a3;
        atomicAdd(&S[(long)u * FEAT + 4 * fl + q], fmaf(di, v, bv));
    }
}

__global__ __launch_bounds__(256) void k_final(float* __restrict__ S,
                                               const float* __restrict__ cnt, int N) {
    long idx = (long)blockIdx.x * 256 + threadIdx.x;
    if (idx >= (long)N * FEAT) return;
    int i = (int)(idx >> 6);
    float c = cnt[i];
    S[idx] = (c > 0.f) ? S[idx] / c : 0.f;
}

extern "C" void kernel_launch(void* const* d_in, const int* in_sizes, int n_in,
                              void* d_out, int out_size, void* d_ws, size_t ws_size,
                              hipStream_t stream) {
    const float* x   = (const float*)d_in[0];
    const int* edge  = (const int*)d_in[1];
    const int* uidx  = (const int*)d_in[2];
    const float* W1  = (const float*)d_in[3];
    const float* b1  = (const float*)d_in[4];
    const float* W2  = (const float*)d_in[5];
    const float* b2  = (const float*)d_in[6];
    float* out       = (float*)d_out;

    const int N = in_sizes[2];       // 100000
    const int E = in_sizes[1] / 2;   // 1600000
    const int* src = edge;
    const int* dst = edge + E;

    const size_t fbuf = (size_t)N * FEAT * sizeof(float);
    const size_t abuf = (size_t)N * FEAT * sizeof(unsigned short);
    const long NF = (long)N * FEAT;
    const int gNF = (int)((NF + 255) / 256);
    const int gE  = (E + 255) / 256;
    const int gN  = (N + 255) / 256;
    const int gN4 = (N + 3) / 4;
    const int gG  = (N + 63) / 64;
    const int nbScan = (N + SCAN_CHUNK - 1) / SCAN_CHUNK;
    const int KB = (N + BIN_R - 1) >> BIN_SHIFT;            // 196

    auto align256 = [](size_t v) { return (v + 255) & ~(size_t)255; };

    char* w = (char*)d_ws;
    size_t o = 0;
    float* dis  = (float*)(w + o); o = align256(o + (size_t)N * 4);
    float* cntf = (float*)(w + o); o = align256(o + (size_t)N * 4);
    int*   rp   = (int*)  (w + o); o = align256(o + (size_t)(N + 1) * 4);
    int*   cntE = (int*)  (w + o); o = align256(o + (size_t)N * 4);   // gbc aliases
    int*   ptot = (int*)  (w + o); o = align256(o + (size_t)1024 * 4); // bb aliases
    int*   poff = (int*)  (w + o); o = align256(o + (size_t)1024 * 4); // bcur aliases
    int*   col  = (int*)  (w + o); o = align256(o + (size_t)E * 4);
    size_t apsz = (size_t)E * sizeof(int2) > abuf ? (size_t)E * sizeof(int2) : abuf;
    char*  Ap   = w + o;           o = align256(o + apsz);
    const size_t need = o;
    int* gbc  = cntE;
    int* bb   = ptot;      // KB+1 ints
    int* bcur = poff;
    int2* pairs = (int2*)Ap;
    unsigned short* A = (unsigned short*)Ap;

    if (ws_size >= need && KB <= 256) {
        // --- bucket-level CSR build (no N-wide atomics) ---
        hipMemsetAsync(gbc, 0, (size_t)KB * 4, stream);
        k_bhist<<<(E + BH_TILE - 1) / BH_TILE, 256, 0, stream>>>(dst, gbc, E, N, KB);
        k_bscan<<<1, 256, 0, stream>>>(gbc, bb, bcur, rp + N, KB);
        k_binA <<<(E + BIN_TILE - 1) / BIN_TILE, 256, 0, stream>>>(src, dst, bcur, pairs, E, N, KB);
        k_binB2<<<KB, 256, 0, stream>>>(pairs, bb, rp, col, dis, N);
        hipMemsetAsync(cntf, 0, (size_t)N * 4, stream);
        k_ucnt <<<gN, 256, 0, stream>>>(uidx, cntf, N);

        k_gemm1<<<gG, 256, 0, stream>>>(x, W1, dis, A, N);
        k_agg1 <<<gN4, 256, 0, stream>>>(A, rp, col, dis, b1, out, N);

        k_gemm2<<<gG, 256, 0, stream>>>(out, W2, dis, A, N);
        hipMemsetAsync(out, 0, fbuf, stream);
        k_agg2s<<<gN4, 256, 0, stream>>>(A, rp, col, dis, b2, uidx, out, N);
        k_final<<<gNF, 256, 0, stream>>>(out, cntf, N);
    } else {
        // --- fallback: proven atomic-histogram CSR build ---
        hipMemsetAsync(cntE, 0, (size_t)N * 4, stream);
        k_hist <<<gE, 256, 0, stream>>>(dst, cntE, E, N);
        k_dis  <<<gN, 256, 0, stream>>>(cntE, dis, N);
        k_scan1<<<nbScan, SCAN_BS, 0, stream>>>(cntE, rp, ptot, N);
        k_scan2<<<1, 1024, 0, stream>>>(ptot, poff, rp + N, nbScan);
        k_scan3<<<nbScan, SCAN_BS, 0, stream>>>(rp, poff, N);
        hipMemsetAsync(cntE, 0, (size_t)N * 4, stream);
        k_fill <<<gE, 256, 0, stream>>>(src, dst, rp, cntE, col, E, N);
        hipMemsetAsync(cntf, 0, (size_t)N * 4, stream);
        k_ucnt <<<gN, 256, 0, stream>>>(uidx, cntf, N);
        k_gemm1<<<gG, 256, 0, stream>>>(x, W1, dis, A, N);
        k_agg1 <<<gN4, 256, 0, stream>>>(A, rp, col, dis, b1, out, N);
        k_gemm2<<<gG, 256, 0, stream>>>(out, W2, dis, A, N);
        hipMemsetAsync(out, 0, fbuf, stream);
        k_agg2s<<<gN4, 256, 0, stream>>>(A, rp, col, dis, b2, uidx, out, N);
        k_final<<<gNF, 256, 0, stream>>>(out, cntf, N);
    }
}

// Round 12
// 304.209 us; speedup vs baseline: 3.4966x; 1.0511x over previous
//
#include <hip/hip_runtime.h>
#include <hip/hip_bf16.h>

// GCN: h1 = relu(GCNConv(x, W1, b1)); out = scatter_mean(GCNConv(h1, W2, b2), user_idx)
// N=100000, E=1600000, dims 128 -> 64 -> 64. fp32 I/O, int32 indices.
//
// R11 profile: k_agg* 56us, FETCH=87MB @2TB/s, VALU 38% -- still VMEM-instr
// bound at 8B/lane. R12: (1) gather at 16B/lane (uint4, 8 lanes/row, 8 edges
// per wave-instruction, octant accumulators + shfl_xor 8/16/32); (2) pairs
// packed to one int ((src<<9)|(dst&511)) -- halves binA write + binB2 read,
// binA LDS 43->27KB.

#define FEAT 64
#define INDIM 128

#define SCAN_BS 256
#define SCAN_ELEMS 8
#define SCAN_CHUNK (SCAN_BS * SCAN_ELEMS)

#define BIN_SHIFT 9
#define BIN_R 512
#define BIN_TILE 4096
#define BH_TILE 8192

typedef __attribute__((ext_vector_type(8))) short short8;
typedef __attribute__((ext_vector_type(4))) float f32x4;

__device__ __forceinline__ unsigned short f2bf(float f) {
    unsigned u = __float_as_uint(f);
    unsigned r = u + 0x7FFFu + ((u >> 16) & 1u);
    return (unsigned short)(r >> 16);
}
__device__ __forceinline__ float bf2f(unsigned short v) {
    return __uint_as_float(((unsigned)v) << 16);
}

// ==================== bucket-level CSR build ====================

__global__ __launch_bounds__(256) void k_bhist(const int* __restrict__ dst,
                                               int* __restrict__ gbc, int E, int N, int KB) {
    __shared__ int h[256];
    const int tid = threadIdx.x;
    h[tid] = 0;
    __syncthreads();
    const int base = blockIdx.x * BH_TILE;
    #pragma unroll
    for (int t = 0; t < BH_TILE / 256; ++t) {
        int e = base + t * 256 + tid;
        if (e < E) {
            int d = dst[e];
            if ((unsigned)d < (unsigned)N) atomicAdd(&h[d >> BIN_SHIFT], 1);
        }
    }
    __syncthreads();
    if (tid < KB && h[tid]) atomicAdd(&gbc[tid], h[tid]);
}

__global__ __launch_bounds__(256) void k_bscan(const int* __restrict__ gbc,
                                               int* __restrict__ bb,
                                               int* __restrict__ bcur,
                                               int* __restrict__ rpN, int KB) {
    __shared__ int lds[256];
    const int tid = threadIdx.x;
    int v = (tid < KB) ? gbc[tid] : 0;
    lds[tid] = v;
    __syncthreads();
    for (int d = 1; d < 256; d <<= 1) {
        int t = (tid >= d) ? lds[tid - d] : 0;
        __syncthreads();
        lds[tid] += t;
        __syncthreads();
    }
    int excl = lds[tid] - v;
    if (tid < KB) { bb[tid] = excl; bcur[tid] = excl; }
    if (tid == 255) { bb[KB] = lds[255]; *rpN = lds[255]; }
}

// tile-reorder edges by bucket; packed (src<<BIN_SHIFT)|local_dst
__global__ __launch_bounds__(256) void k_binA(const int* __restrict__ src,
                                              const int* __restrict__ dst,
                                              int* __restrict__ bcur,
                                              unsigned* __restrict__ pairs,
                                              int E, int N, int KB) {
    __shared__ unsigned lbuf[BIN_TILE];          // 16 KB
    __shared__ unsigned short bkt[BIN_TILE];     // 8 KB
    __shared__ int lcnt[256];
    __shared__ int loff[256];
    __shared__ int lbase[256];
    __shared__ int tot;
    const int tid = threadIdx.x;
    const int base = blockIdx.x * BIN_TILE;

    lcnt[tid] = 0;
    __syncthreads();

    int mys[16], myd[16], myb[16];
    #pragma unroll
    for (int t = 0; t < 16; ++t) {
        int e = base + t * 256 + tid;
        int s = 0, d = -1;
        if (e < E) { s = src[e]; d = dst[e]; }
        if ((unsigned)d >= (unsigned)N) d = -1;
        if ((unsigned)s >= (unsigned)N) s = 0;
        mys[t] = s; myd[t] = d;
        myb[t] = (d >= 0) ? (d >> BIN_SHIFT) : -1;
        if (myb[t] >= 0) atomicAdd(&lcnt[myb[t]], 1);
    }
    __syncthreads();

    int v = lcnt[tid];
    loff[tid] = v;
    __syncthreads();
    for (int d = 1; d < 256; d <<= 1) {
        int t2 = (tid >= d) ? loff[tid - d] : 0;
        __syncthreads();
        loff[tid] += t2;
        __syncthreads();
    }
    if (tid == 255) tot = loff[255];
    int excl = loff[tid] - v;
    __syncthreads();
    loff[tid] = excl;
    lcnt[tid] = excl;
    if (tid < KB && v > 0) lbase[tid] = atomicAdd(&bcur[tid], v);
    __syncthreads();

    #pragma unroll
    for (int t = 0; t < 16; ++t) {
        if (myb[t] >= 0) {
            int pos = atomicAdd(&lcnt[myb[t]], 1);
            lbuf[pos] = ((unsigned)mys[t] << BIN_SHIFT) | (unsigned)(myd[t] & (BIN_R - 1));
            bkt[pos] = (unsigned short)myb[t];
        }
    }
    __syncthreads();

    const int T = tot;
    for (int i = tid; i < T; i += 256) {
        int b = bkt[i];
        pairs[lbase[b] + (i - loff[b])] = lbuf[i];
    }
}

// one WG per bucket: degrees in LDS -> rp + dis, then rank -> col
__global__ __launch_bounds__(256) void k_binB2(const unsigned* __restrict__ pairs,
                                               const int* __restrict__ bb,
                                               int* __restrict__ rp,
                                               int* __restrict__ col,
                                               float* __restrict__ dis, int N) {
    __shared__ int cnt[BIN_R];
    __shared__ int cur[BIN_R];
    __shared__ int ssum[256];
    const int tid = threadIdx.x;
    const int b = blockIdx.x;
    const int n0 = b << BIN_SHIFT;
    const int n1 = min(n0 + BIN_R, N);
    const int nn = n1 - n0;
    const int e0 = bb[b];
    const int e1 = bb[b + 1];

    for (int i = tid; i < nn; i += 256) cnt[i] = 0;
    __syncthreads();
    for (int i = e0 + tid; i < e1; i += 256) {
        atomicAdd(&cnt[pairs[i] & (BIN_R - 1)], 1);
    }
    __syncthreads();

    const int i0 = 2 * tid;
    int c0 = (i0     < nn) ? cnt[i0]     : 0;
    int c1 = (i0 + 1 < nn) ? cnt[i0 + 1] : 0;
    ssum[tid] = c0 + c1;
    __syncthreads();
    for (int d = 1; d < 256; d <<= 1) {
        int t = (tid >= d) ? ssum[tid - d] : 0;
        __syncthreads();
        ssum[tid] += t;
        __syncthreads();
    }
    int excl = ssum[tid] - (c0 + c1);
    if (i0 < nn) {
        cur[i0] = e0 + excl;
        rp[n0 + i0] = e0 + excl;
        dis[n0 + i0] = rsqrtf((float)c0 + 1.0f);
    }
    if (i0 + 1 < nn) {
        cur[i0 + 1] = e0 + excl + c0;
        rp[n0 + i0 + 1] = e0 + excl + c0;
        dis[n0 + i0 + 1] = rsqrtf((float)c1 + 1.0f);
    }
    __syncthreads();

    for (int i = e0 + tid; i < e1; i += 256) {
        unsigned p = pairs[i];
        int pos = atomicAdd(&cur[p & (BIN_R - 1)], 1);
        col[pos] = (int)(p >> BIN_SHIFT);
    }
}

// ==================== fallback CSR build (proven path) ====================

__global__ __launch_bounds__(256) void k_hist(const int* __restrict__ dst,
                                              int* __restrict__ cntE, int E, int N) {
    int e = blockIdx.x * 256 + threadIdx.x;
    if (e < E) {
        int d = dst[e];
        if ((unsigned)d < (unsigned)N) atomicAdd(&cntE[d], 1);
    }
}
__global__ __launch_bounds__(256) void k_dis(const int* __restrict__ cntE,
                                             float* __restrict__ dis, int N) {
    int i = blockIdx.x * 256 + threadIdx.x;
    if (i < N) dis[i] = rsqrtf((float)cntE[i] + 1.0f);
}
__global__ __launch_bounds__(SCAN_BS) void k_scan1(const int* __restrict__ c,
                                                   int* __restrict__ rp,
                                                   int* __restrict__ ptot, int N) {
    __shared__ int lds[SCAN_BS];
    const int base = blockIdx.x * SCAN_CHUNK;
    const int tb = base + threadIdx.x * SCAN_ELEMS;
    int vals[SCAN_ELEMS];
    int s = 0;
    #pragma unroll
    for (int k = 0; k < SCAN_ELEMS; ++k) {
        int idx = tb + k;
        int v = (idx < N) ? c[idx] : 0;
        vals[k] = s;
        s += v;
    }
    lds[threadIdx.x] = s;
    __syncthreads();
    for (int d = 1; d < SCAN_BS; d <<= 1) {
        int v = (threadIdx.x >= d) ? lds[threadIdx.x - d] : 0;
        __syncthreads();
        lds[threadIdx.x] += v;
        __syncthreads();
    }
    int toff = (threadIdx.x == 0) ? 0 : lds[threadIdx.x - 1];
    #pragma unroll
    for (int k = 0; k < SCAN_ELEMS; ++k) {
        int idx = tb + k;
        if (idx < N) rp[idx] = toff + vals[k];
    }
    if (threadIdx.x == SCAN_BS - 1) ptot[blockIdx.x] = lds[SCAN_BS - 1];
}
__global__ __launch_bounds__(1024) void k_scan2(int* __restrict__ ptot,
                                                int* __restrict__ poff,
                                                int* __restrict__ rpN, int nb) {
    __shared__ int lds[1024];
    int tid = threadIdx.x;
    lds[tid] = (tid < nb) ? ptot[tid] : 0;
    __syncthreads();
    for (int d = 1; d < 1024; d <<= 1) {
        int v = (tid >= d) ? lds[tid - d] : 0;
        __syncthreads();
        lds[tid] += v;
        __syncthreads();
    }
    if (tid < nb) poff[tid] = (tid == 0) ? 0 : lds[tid - 1];
    if (tid == nb - 1) *rpN = lds[tid];
}
__global__ __launch_bounds__(SCAN_BS) void k_scan3(int* __restrict__ rp,
                                                   const int* __restrict__ poff, int N) {
    int off = poff[blockIdx.x];
    const int tb = blockIdx.x * SCAN_CHUNK + threadIdx.x * SCAN_ELEMS;
    #pragma unroll
    for (int k = 0; k < SCAN_ELEMS; ++k) {
        int idx = tb + k;
        if (idx < N) rp[idx] += off;
    }
}
__global__ __launch_bounds__(256) void k_fill(const int* __restrict__ src,
                                              const int* __restrict__ dst,
                                              const int* __restrict__ rp,
                                              int* __restrict__ tmp,
                                              int* __restrict__ col, int E, int N) {
    int e = blockIdx.x * 256 + threadIdx.x;
    if (e >= E) return;
    int s = src[e], d = dst[e];
    if ((unsigned)s >= (unsigned)N) s = 0;
    if ((unsigned)d >= (unsigned)N) return;
    int r = atomicAdd(&tmp[d], 1);
    col[rp[d] + r] = s;
}

__global__ __launch_bounds__(256) void k_ucnt(const int* __restrict__ uidx,
                                              float* __restrict__ cntf, int N) {
    int i = blockIdx.x * 256 + threadIdx.x;
    if (i < N) {
        int u = uidx[i];
        if ((unsigned)u < (unsigned)N) atomicAdd(&cntf[u], 1.0f);
    }
}

// ==================== MFMA GEMMs (16x16x32 bf16, verified layouts) ====================

__global__ __launch_bounds__(256) void k_gemm1(const float* __restrict__ x,
                                               const float* __restrict__ W,
                                               const float* __restrict__ scale,
                                               unsigned short* __restrict__ out, int N) {
    __shared__ short wf[4 * 4 * 64 * 8];
    const int tid = threadIdx.x;
    for (int i = tid; i < INDIM * FEAT; i += 256) {
        int k = i >> 6, n = i & 63;
        int ct = n >> 4, kc = k >> 5, r = k & 31;
        int owner = ((r >> 3) << 4) | (n & 15);
        wf[(((ct << 2) | kc) * 64 + owner) * 8 + (r & 7)] = (short)f2bf(W[i]);
    }
    __syncthreads();

    const int lane = tid & 63;
    const int m = lane & 15, q = lane >> 4;
    const int row0 = blockIdx.x * 64 + (tid >> 6) * 16;

    short8 bfr[4][4];
    #pragma unroll
    for (int ct = 0; ct < 4; ++ct)
        #pragma unroll
        for (int kc = 0; kc < 4; ++kc)
            bfr[ct][kc] = *reinterpret_cast<const short8*>(&wf[(((ct << 2) | kc) * 64 + lane) * 8]);

    int gr = row0 + m;
    int rl = gr < N ? gr : (N - 1);
    const float* xp = x + (long)rl * INDIM + q * 8;

    f32x4 acc[4] = {{0,0,0,0},{0,0,0,0},{0,0,0,0},{0,0,0,0}};
    #pragma unroll
    for (int kc = 0; kc < 4; ++kc) {
        float4 v0 = *reinterpret_cast<const float4*>(xp + kc * 32);
        float4 v1 = *reinterpret_cast<const float4*>(xp + kc * 32 + 4);
        short8 a;
        a[0]=(short)f2bf(v0.x); a[1]=(short)f2bf(v0.y); a[2]=(short)f2bf(v0.z); a[3]=(short)f2bf(v0.w);
        a[4]=(short)f2bf(v1.x); a[5]=(short)f2bf(v1.y); a[6]=(short)f2bf(v1.z); a[7]=(short)f2bf(v1.w);
        #pragma unroll
        for (int ct = 0; ct < 4; ++ct)
            acc[ct] = __builtin_amdgcn_mfma_f32_16x16x32_bf16(a, bfr[ct][kc], acc[ct], 0, 0, 0);
    }

    #pragma unroll
    for (int reg = 0; reg < 4; ++reg) {
        int row = row0 + q * 4 + reg;
        if (row < N) {
            float sc = scale[row];
            #pragma unroll
            for (int ct = 0; ct < 4; ++ct)
                out[(long)row * FEAT + ct * 16 + m] = f2bf(acc[ct][reg] * sc);
        }
    }
}

__global__ __launch_bounds__(256) void k_gemm2(const float* __restrict__ h,
                                               const float* __restrict__ W,
                                               const float* __restrict__ scale,
                                               unsigned short* __restrict__ out, int N) {
    __shared__ short wf[4 * 2 * 64 * 8];
    const int tid = threadIdx.x;
    for (int i = tid; i < FEAT * FEAT; i += 256) {
        int k = i >> 6, n = i & 63;
        int ct = n >> 4, kc = k >> 5, r = k & 31;
        int owner = ((r >> 3) << 4) | (n & 15);
        wf[(((ct << 1) | kc) * 64 + owner) * 8 + (r & 7)] = (short)f2bf(W[i]);
    }
    __syncthreads();

    const int lane = tid & 63;
    const int m = lane & 15, q = lane >> 4;
    const int row0 = blockIdx.x * 64 + (tid >> 6) * 16;

    short8 bfr[4][2];
    #pragma unroll
    for (int ct = 0; ct < 4; ++ct)
        #pragma unroll
        for (int kc = 0; kc < 2; ++kc)
            bfr[ct][kc] = *reinterpret_cast<const short8*>(&wf[(((ct << 1) | kc) * 64 + lane) * 8]);

    int gr = row0 + m;
    int rl = gr < N ? gr : (N - 1);
    const float* hp = h + (long)rl * FEAT + q * 8;

    f32x4 acc[4] = {{0,0,0,0},{0,0,0,0},{0,0,0,0},{0,0,0,0}};
    #pragma unroll
    for (int kc = 0; kc < 2; ++kc) {
        float4 v0 = *reinterpret_cast<const float4*>(hp + kc * 32);
        float4 v1 = *reinterpret_cast<const float4*>(hp + kc * 32 + 4);
        short8 a;
        a[0]=(short)f2bf(v0.x); a[1]=(short)f2bf(v0.y); a[2]=(short)f2bf(v0.z); a[3]=(short)f2bf(v0.w);
        a[4]=(short)f2bf(v1.x); a[5]=(short)f2bf(v1.y); a[6]=(short)f2bf(v1.z); a[7]=(short)f2bf(v1.w);
        #pragma unroll
        for (int ct = 0; ct < 4; ++ct)
            acc[ct] = __builtin_amdgcn_mfma_f32_16x16x32_bf16(a, bfr[ct][kc], acc[ct], 0, 0, 0);
    }

    #pragma unroll
    for (int reg = 0; reg < 4; ++reg) {
        int row = row0 + q * 4 + reg;
        if (row < N) {
            float sc = scale[row];
            #pragma unroll
            for (int ct = 0; ct < 4; ++ct)
                out[(long)row * FEAT + ct * 16 + m] = f2bf(acc[ct][reg] * sc);
        }
    }
}

// ==================== pull aggregation: 16B/lane gather ====================
// lane = 8*q2 + ol (q2 = edge slot 0..7, ol = feature-octet 0..7).
// lane loads uint4 (8 bf16 feats) of slot q2's edge: 8 edges per instruction,
// 2 loads in flight (16 edges/iter). Octant partials merged via shfl_xor 8/16/32.

#define AGG_BODY(SELF_INIT)                                                      \
    const int lane = threadIdx.x & 63;                                           \
    const int q2 = lane >> 3;                                                    \
    const int ol = lane & 7;                                                     \
    const int jb = rp[i], je = rp[i + 1];                                        \
    float a0=0.f,a1=0.f,a2=0.f,a3=0.f,a4=0.f,a5=0.f,a6=0.f,a7=0.f;               \
    if (q2 == 0) { SELF_INIT }                                                   \
    for (int j0 = jb; j0 < je; j0 += 16) {                                       \
        int ja = j0 + q2, jb2 = j0 + 8 + q2;                                     \
        int ca = (ja  < je) ? col[ja]  : i;  float ma = (ja  < je) ? 1.f : 0.f;  \
        int cb = (jb2 < je) ? col[jb2] : i;  float mb = (jb2 < je) ? 1.f : 0.f;  \
        uint4 ra = *reinterpret_cast<const uint4*>(A + (long)ca * FEAT + 8 * ol);\
        uint4 rb = *reinterpret_cast<const uint4*>(A + (long)cb * FEAT + 8 * ol);\
        a0 = fmaf(ma, bf2f((unsigned short)ra.x),         a0);                   \
        a1 = fmaf(ma, bf2f((unsigned short)(ra.x >> 16)), a1);                   \
        a2 = fmaf(ma, bf2f((unsigned short)ra.y),         a2);                   \
        a3 = fmaf(ma, bf2f((unsigned short)(ra.y >> 16)), a3);                   \
        a4 = fmaf(ma, bf2f((unsigned short)ra.z),         a4);                   \
        a5 = fmaf(ma, bf2f((unsigned short)(ra.z >> 16)), a5);                   \
        a6 = fmaf(ma, bf2f((unsigned short)ra.w),         a6);                   \
        a7 = fmaf(ma, bf2f((unsigned short)(ra.w >> 16)), a7);                   \
        a0 = fmaf(mb, bf2f((unsigned short)rb.x),         a0);                   \
        a1 = fmaf(mb, bf2f((unsigned short)(rb.x >> 16)), a1);                   \
        a2 = fmaf(mb, bf2f((unsigned short)rb.y),         a2);                   \
        a3 = fmaf(mb, bf2f((unsigned short)(rb.y >> 16)), a3);                   \
        a4 = fmaf(mb, bf2f((unsigned short)rb.z),         a4);                   \
        a5 = fmaf(mb, bf2f((unsigned short)(rb.z >> 16)), a5);                   \
        a6 = fmaf(mb, bf2f((unsigned short)rb.w),         a6);                   \
        a7 = fmaf(mb, bf2f((unsigned short)(rb.w >> 16)), a7);                   \
    }                                                                            \
    a0 += __shfl_xor(a0, 8);  a1 += __shfl_xor(a1, 8);                           \
    a2 += __shfl_xor(a2, 8);  a3 += __shfl_xor(a3, 8);                           \
    a4 += __shfl_xor(a4, 8);  a5 += __shfl_xor(a5, 8);                           \
    a6 += __shfl_xor(a6, 8);  a7 += __shfl_xor(a7, 8);                           \
    a0 += __shfl_xor(a0, 16); a1 += __shfl_xor(a1, 16);                          \
    a2 += __shfl_xor(a2, 16); a3 += __shfl_xor(a3, 16);                          \
    a4 += __shfl_xor(a4, 16); a5 += __shfl_xor(a5, 16);                          \
    a6 += __shfl_xor(a6, 16); a7 += __shfl_xor(a7, 16);                          \
    a0 += __shfl_xor(a0, 32); a1 += __shfl_xor(a1, 32);                          \
    a2 += __shfl_xor(a2, 32); a3 += __shfl_xor(a3, 32);                          \
    a4 += __shfl_xor(a4, 32); a5 += __shfl_xor(a5, 32);                          \
    a6 += __shfl_xor(a6, 32); a7 += __shfl_xor(a7, 32);

__global__ __launch_bounds__(256) void k_agg1(const unsigned short* __restrict__ A,
                                              const int* __restrict__ rp,
                                              const int* __restrict__ col,
                                              const float* __restrict__ dis,
                                              const float* __restrict__ bias,
                                              float* __restrict__ H, int N) {
    int i = blockIdx.x * 4 + (threadIdx.x >> 6);
    if (i >= N) return;
    AGG_BODY(
        uint4 rv = *reinterpret_cast<const uint4*>(A + (long)i * FEAT + 8 * ol);
        a0 = bf2f((unsigned short)rv.x); a1 = bf2f((unsigned short)(rv.x >> 16));
        a2 = bf2f((unsigned short)rv.y); a3 = bf2f((unsigned short)(rv.y >> 16));
        a4 = bf2f((unsigned short)rv.z); a5 = bf2f((unsigned short)(rv.z >> 16));
        a6 = bf2f((unsigned short)rv.w); a7 = bf2f((unsigned short)(rv.w >> 16));
    )
    if (q2 == 0) {
        float di = dis[i];
        float4 b4a = *reinterpret_cast<const float4*>(bias + 8 * ol);
        float4 b4b = *reinterpret_cast<const float4*>(bias + 8 * ol + 4);
        float4 o0, o1;
        o0.x = fmaxf(fmaf(di, a0, b4a.x), 0.f);
        o0.y = fmaxf(fmaf(di, a1, b4a.y), 0.f);
        o0.z = fmaxf(fmaf(di, a2, b4a.z), 0.f);
        o0.w = fmaxf(fmaf(di, a3, b4a.w), 0.f);
        o1.x = fmaxf(fmaf(di, a4, b4b.x), 0.f);
        o1.y = fmaxf(fmaf(di, a5, b4b.y), 0.f);
        o1.z = fmaxf(fmaf(di, a6, b4b.z), 0.f);
        o1.w = fmaxf(fmaf(di, a7, b4b.w), 0.f);
        *reinterpret_cast<float4*>(H + (long)i * FEAT + 8 * ol)     = o0;
        *reinterpret_cast<float4*>(H + (long)i * FEAT + 8 * ol + 4) = o1;
    }
}

__global__ __launch_bounds__(256) void k_agg2s(const unsigned short* __restrict__ A,
                                               const int* __restrict__ rp,
                                               const int* __restrict__ col,
                                               const float* __restrict__ dis,
                                               const float* __restrict__ bias,
                                               const int* __restrict__ uidx,
                                               float* __restrict__ S, int N) {
    int i = blockIdx.x * 4 + (threadIdx.x >> 6);
    if (i >= N) return;
    AGG_BODY(
        uint4 rv = *reinterpret_cast<const uint4*>(A + (long)i * FEAT + 8 * ol);
        a0 = bf2f((unsigned short)rv.x); a1 = bf2f((unsigned short)(rv.x >> 16));
        a2 = bf2f((unsigned short)rv.y); a3 = bf2f((unsigned short)(rv.y >> 16));
        a4 = bf2f((unsigned short)rv.z); a5 = bf2f((unsigned short)(rv.z >> 16));
        a6 = bf2f((unsigned short)rv.w); a7 = bf2f((unsigned short)(rv.w >> 16));
    )
    int u = uidx[i];
    if ((unsigned)u < (unsigned)N) {
        float di = dis[i];
        float v = (q2 == 0) ? a0 : (q2 == 1) ? a1 : (q2 == 2) ? a2 : (q2 == 3) ? a3
                : (q2 == 4) ? a4 : (q2 == 5) ? a5 : (q2 == 6) ? a6 : a7;
        int f = 8 * ol + q2;
        atomicAdd(&S[(long)u * FEAT + f], fmaf(di, v, bias[f]));
    }
}

__global__ __launch_bounds__(256) void k_final(float* __restrict__ S,
                                               const float* __restrict__ cnt, int N) {
    long idx = (long)blockIdx.x * 256 + threadIdx.x;
    if (idx >= (long)N * FEAT) return;
    int i = (int)(idx >> 6);
    float c = cnt[i];
    S[idx] = (c > 0.f) ? S[idx] / c : 0.f;
}

extern "C" void kernel_launch(void* const* d_in, const int* in_sizes, int n_in,
                              void* d_out, int out_size, void* d_ws, size_t ws_size,
                              hipStream_t stream) {
    const float* x   = (const float*)d_in[0];
    const int* edge  = (const int*)d_in[1];
    const int* uidx  = (const int*)d_in[2];
    const float* W1  = (const float*)d_in[3];
    const float* b1  = (const float*)d_in[4];
    const float* W2  = (const float*)d_in[5];
    const float* b2  = (const float*)d_in[6];
    float* out       = (float*)d_out;

    const int N = in_sizes[2];       // 100000
    const int E = in_sizes[1] / 2;   // 1600000
    const int* src = edge;
    const int* dst = edge + E;

    const size_t fbuf = (size_t)N * FEAT * sizeof(float);
    const size_t abuf = (size_t)N * FEAT * sizeof(unsigned short);
    const long NF = (long)N * FEAT;
    const int gNF = (int)((NF + 255) / 256);
    const int gE  = (E + 255) / 256;
    const int gN  = (N + 255) / 256;
    const int gN4 = (N + 3) / 4;
    const int gG  = (N + 63) / 64;
    const int nbScan = (N + SCAN_CHUNK - 1) / SCAN_CHUNK;
    const int KB = (N + BIN_R - 1) >> BIN_SHIFT;            // 196

    auto align256 = [](size_t v) { return (v + 255) & ~(size_t)255; };

    char* w = (char*)d_ws;
    size_t o = 0;
    float* dis  = (float*)(w + o); o = align256(o + (size_t)N * 4);
    float* cntf = (float*)(w + o); o = align256(o + (size_t)N * 4);
    int*   rp   = (int*)  (w + o); o = align256(o + (size_t)(N + 1) * 4);
    int*   cntE = (int*)  (w + o); o = align256(o + (size_t)N * 4);   // gbc aliases
    int*   ptot = (int*)  (w + o); o = align256(o + (size_t)1024 * 4); // bb aliases
    int*   poff = (int*)  (w + o); o = align256(o + (size_t)1024 * 4); // bcur aliases
    int*   col  = (int*)  (w + o); o = align256(o + (size_t)E * 4);
    size_t apsz = (size_t)E * 4 > abuf ? (size_t)E * 4 : abuf;
    char*  Ap   = w + o;           o = align256(o + apsz);
    const size_t need = o;
    int* gbc  = cntE;
    int* bb   = ptot;
    int* bcur = poff;
    unsigned* pairs = (unsigned*)Ap;   // dead once gemm1 writes A
    unsigned short* A = (unsigned short*)Ap;

    // packed pairs need src < 2^(32-BIN_SHIFT)
    if (ws_size >= need && KB <= 256 && N <= (1 << (32 - BIN_SHIFT - 1))) {
        hipMemsetAsync(gbc, 0, (size_t)KB * 4, stream);
        k_bhist<<<(E + BH_TILE - 1) / BH_TILE, 256, 0, stream>>>(dst, gbc, E, N, KB);
        k_bscan<<<1, 256, 0, stream>>>(gbc, bb, bcur, rp + N, KB);
        k_binA <<<(E + BIN_TILE - 1) / BIN_TILE, 256, 0, stream>>>(src, dst, bcur, pairs, E, N, KB);
        k_binB2<<<KB, 256, 0, stream>>>(pairs, bb, rp, col, dis, N);
        hipMemsetAsync(cntf, 0, (size_t)N * 4, stream);
        k_ucnt <<<gN, 256, 0, stream>>>(uidx, cntf, N);

        k_gemm1<<<gG, 256, 0, stream>>>(x, W1, dis, A, N);
        k_agg1 <<<gN4, 256, 0, stream>>>(A, rp, col, dis, b1, out, N);

        k_gemm2<<<gG, 256, 0, stream>>>(out, W2, dis, A, N);
        hipMemsetAsync(out, 0, fbuf, stream);
        k_agg2s<<<gN4, 256, 0, stream>>>(A, rp, col, dis, b2, uidx, out, N);
        k_final<<<gNF, 256, 0, stream>>>(out, cntf, N);
    } else {
        hipMemsetAsync(cntE, 0, (size_t)N * 4, stream);
        k_hist <<<gE, 256, 0, stream>>>(dst, cntE, E, N);
        k_dis  <<<gN, 256, 0, stream>>>(cntE, dis, N);
        k_scan1<<<nbScan, SCAN_BS, 0, stream>>>(cntE, rp, ptot, N);
        k_scan2<<<1, 1024, 0, stream>>>(ptot, poff, rp + N, nbScan);
        k_scan3<<<nbScan, SCAN_BS, 0, stream>>>(rp, poff, N);
        hipMemsetAsync(cntE, 0, (size_t)N * 4, stream);
        k_fill <<<gE, 256, 0, stream>>>(src, dst, rp, cntE, col, E, N);
        hipMemsetAsync(cntf, 0, (size_t)N * 4, stream);
        k_ucnt <<<gN, 256, 0, stream>>>(uidx, cntf, N);
        k_gemm1<<<gG, 256, 0, stream>>>(x, W1, dis, A, N);
        k_agg1 <<<gN4, 256, 0, stream>>>(A, rp, col, dis, b1, out, N);
        k_gemm2<<<gG, 256, 0, stream>>>(out, W2, dis, A, N);
        hipMemsetAsync(out, 0, fbuf, stream);
        k_agg2s<<<gN4, 256, 0, stream>>>(A, rp, col, dis, b2, uidx, out, N);
        k_final<<<gNF, 256, 0, stream>>>(out, cntf, N);
    }
}